// Round 1
// baseline (6954.160 us; speedup 1.0000x reference)
//
#include <hip/hip_runtime.h>

// Problem constants (fixed by the reference).
#define NN 100000
#define EE 1600000
// D_IN=64, H=128, E_IN=64, C=8
constexpr float BN_EPS = 1e-5f;

// ---------------------------------------------------------------------------
// degree + inverse degree
// ---------------------------------------------------------------------------
__global__ void k_deg(const int* __restrict__ dst, float* __restrict__ deg) {
    int e = blockIdx.x * 256 + threadIdx.x;
    if (e < EE) atomicAdd(&deg[dst[e]], 1.0f);
}

__global__ void k_invdeg(const float* __restrict__ deg, float* __restrict__ invd) {
    int i = blockIdx.x * 256 + threadIdx.x;
    if (i < NN) {
        float d = deg[i];
        invd[i] = d > 0.f ? 1.f / d : 0.f;   // matches DGL mean: zero-degree -> 0
    }
}

// ---------------------------------------------------------------------------
// scatter-add aggregation: agg[dst] += x[src], F features per edge
// ---------------------------------------------------------------------------
template <int F>
__global__ void k_scatter(const float* __restrict__ x, const int* __restrict__ src,
                          const int* __restrict__ dst, float* __restrict__ agg) {
    constexpr int PER = F / 4;  // float4 chunks per edge
    int gid = blockIdx.x * 256 + threadIdx.x;
    int e = gid / PER, f4 = gid % PER;
    if (e >= EE) return;
    int s = src[e], d = dst[e];
    float4 xv = *reinterpret_cast<const float4*>(x + (size_t)s * F + f4 * 4);
    float* ap = agg + (size_t)d * F + f4 * 4;
    atomicAdd(ap + 0, xv.x);
    atomicAdd(ap + 1, xv.y);
    atomicAdd(ap + 2, xv.z);
    atomicAdd(ap + 3, xv.w);
}

// ---------------------------------------------------------------------------
// node GEMM: out[N,128] = [A1 | A2*invdeg] @ [W1 ; W2] + bias
// block = 256 threads, tile = 64 rows x 128 cols, per-thread 4x8 acc.
// cols per thread: cg + 16*j  (conflict-free LDS W reads)
// ---------------------------------------------------------------------------
template <int K1, int K2>
__global__ __launch_bounds__(256) void k_node_gemm(
    const float* __restrict__ A1, const float* __restrict__ A2,
    const float* __restrict__ invd,
    const float* __restrict__ W1, const float* __restrict__ W2,
    const float* __restrict__ bias, float* __restrict__ out) {
    __shared__ float As[64][17];    // +1 pad: conflict-free
    __shared__ float Ws[16][128];
    const int t = threadIdx.x;
    const int cg = t & 15;   // col group
    const int rg = t >> 4;   // row group: rows rg*4..+3
    const int rowbase = blockIdx.x * 64;

    float acc[4][8];
#pragma unroll
    for (int i = 0; i < 4; ++i)
#pragma unroll
        for (int j = 0; j < 8; ++j) acc[i][j] = 0.f;

    constexpr int KT = K1 + K2;
    const int lk = t & 15, lr0 = t >> 4;

    for (int kb = 0; kb < KT; kb += 16) {
        // stage A (gathered from x-part or agg-part, agg scaled by invdeg)
        {
            int g = kb + lk;  // uniform source per chunk (K1 % 16 == 0)
            const float* Asrc;
            int Kst, gg;
            bool scale;
            if (g < K1) { Asrc = A1; Kst = K1; gg = g; scale = false; }
            else        { Asrc = A2; Kst = K2; gg = g - K1; scale = true; }
#pragma unroll
            for (int p = 0; p < 4; ++p) {
                int r = lr0 + 16 * p;
                int row = rowbase + r;
                float v = 0.f;
                if (row < NN) {
                    v = Asrc[(size_t)row * Kst + gg];
                    if (scale) v *= invd[row];
                }
                As[r][lk] = v;
            }
        }
        // stage W chunk [16 x 128]
#pragma unroll
        for (int p = 0; p < 8; ++p) {
            int idx = t + 256 * p;
            int kr = idx >> 7, col = idx & 127;
            int gw = kb + kr;
            Ws[kr][col] = (gw < K1) ? W1[gw * 128 + col] : W2[(gw - K1) * 128 + col];
        }
        __syncthreads();
#pragma unroll
        for (int k = 0; k < 16; ++k) {
            float a0 = As[rg * 4 + 0][k], a1 = As[rg * 4 + 1][k];
            float a2 = As[rg * 4 + 2][k], a3 = As[rg * 4 + 3][k];
#pragma unroll
            for (int j = 0; j < 8; ++j) {
                float w = Ws[k][cg + 16 * j];
                acc[0][j] = fmaf(a0, w, acc[0][j]);
                acc[1][j] = fmaf(a1, w, acc[1][j]);
                acc[2][j] = fmaf(a2, w, acc[2][j]);
                acc[3][j] = fmaf(a3, w, acc[3][j]);
            }
        }
        __syncthreads();
    }
#pragma unroll
    for (int i = 0; i < 4; ++i) {
        int row = rowbase + rg * 4 + i;
        if (row < NN) {
#pragma unroll
            for (int j = 0; j < 8; ++j) {
                int c = cg + 16 * j;
                out[(size_t)row * 128 + c] = acc[i][j] + bias[c];
            }
        }
    }
}

// ---------------------------------------------------------------------------
// per-column sum / sumsq over [N,128]
// ---------------------------------------------------------------------------
__global__ void k_colstats(const float* __restrict__ h, float* __restrict__ stats) {
    const int t = threadIdx.x;
    const int col = t & 127, half = t >> 7;
    float s = 0.f, ss = 0.f;
    for (int row = blockIdx.x * 2 + half; row < NN; row += gridDim.x * 2) {
        float v = h[(size_t)row * 128 + col];
        s += v;
        ss += v * v;
    }
    __shared__ float red[256];
    red[t] = s;
    __syncthreads();
    if (t < 128) atomicAdd(&stats[col], red[t] + red[t + 128]);
    __syncthreads();
    red[t] = ss;
    __syncthreads();
    if (t < 128) atomicAdd(&stats[128 + col], red[t] + red[t + 128]);
}

// stats -> BN scale a, shift b:  y = a*x + b, a = g*rsqrt(var+eps), b = bt - mu*a
__global__ void k_bnfin(const float* __restrict__ stats, const float* __restrict__ g,
                        const float* __restrict__ bt, float* __restrict__ ab) {
    int c = threadIdx.x;  // 128 threads
    float mu = stats[c] * (1.f / NN);
    float ex2 = stats[128 + c] * (1.f / NN);
    float var = ex2 - mu * mu;  // biased variance (matches reference)
    float a = g[c] * rsqrtf(var + BN_EPS);
    ab[c] = a;
    ab[128 + c] = bt[c] - mu * a;
}

// in-place BN + ReLU over [N,128], float4-vectorized
__global__ void k_bnrelu(float* __restrict__ h, const float* __restrict__ ab) {
    int idx = blockIdx.x * 256 + threadIdx.x;  // over NN*32 float4s
    if (idx >= NN * 32) return;
    int c4 = idx & 31;
    float4 v = reinterpret_cast<float4*>(h)[idx];
    const float4 a = reinterpret_cast<const float4*>(ab)[c4];
    const float4 b = reinterpret_cast<const float4*>(ab)[32 + c4];
    v.x = fmaxf(fmaf(a.x, v.x, b.x), 0.f);
    v.y = fmaxf(fmaf(a.y, v.y, b.y), 0.f);
    v.z = fmaxf(fmaf(a.z, v.z, b.z), 0.f);
    v.w = fmaxf(fmaf(a.w, v.w, b.w), 0.f);
    reinterpret_cast<float4*>(h)[idx] = v;
}

// ---------------------------------------------------------------------------
// fused edge MLP: out = relu([h[u]|h[v]|ef] @ We1 + be1) @ We2 + be2
// block = 256 threads, 64 edges; K=320 staged in chunks of 32.
// phase-2 reuses the LDS union for hid[64][132].
// ---------------------------------------------------------------------------
__global__ __launch_bounds__(256) void k_edge_mlp(
    const float* __restrict__ h, const float* __restrict__ ef,
    const float* __restrict__ We1, const float* __restrict__ be1,
    const float* __restrict__ We2, const float* __restrict__ be2,
    const int* __restrict__ uu, const int* __restrict__ vv,
    float* __restrict__ out) {
    __shared__ __align__(16) float smem[8448];  // union: phase1 As+Wsh / phase2 Hid
    float* As = smem;                            // [64][36] (pad 36: float4-aligned, ~2-way max)
    float* Wsh = smem + 64 * 36;                 // [32][128]
    __shared__ int su[64], sv[64];
    const int t = threadIdx.x;
    const int eb = blockIdx.x * 64;
    if (t < 64) {
        su[t] = uu[eb + t];
        sv[t] = vv[eb + t];
    }
    __syncthreads();

    const int cg = t & 15;  // cols cg*8 .. cg*8+7
    const int rg = t >> 4;  // edges rg*4 .. +3
    float acc[4][8];
#pragma unroll
    for (int i = 0; i < 4; ++i)
#pragma unroll
        for (int j = 0; j < 8; ++j) acc[i][j] = 0.f;

    const int f4 = t & 7, e0 = t >> 3;

    for (int kc = 0; kc < 10; ++kc) {
        // stage gathered A rows: [h[u] (chunks 0-3) | h[v] (4-7) | ef (8-9)]
#pragma unroll
        for (int p = 0; p < 2; ++p) {
            int e = e0 + 32 * p;
            float4 val;
            if (kc < 4)
                val = *(const float4*)(h + (size_t)su[e] * 128 + kc * 32 + f4 * 4);
            else if (kc < 8)
                val = *(const float4*)(h + (size_t)sv[e] * 128 + (kc - 4) * 32 + f4 * 4);
            else
                val = *(const float4*)(ef + (size_t)(eb + e) * 64 + (kc - 8) * 32 + f4 * 4);
            *(float4*)(As + e * 36 + f4 * 4) = val;
        }
        // stage We1 chunk [32 x 128]
#pragma unroll
        for (int p = 0; p < 4; ++p) {
            int idx = t + 256 * p;  // 1024 float4s
            int kr = idx >> 5, c4 = idx & 31;
            *(float4*)(Wsh + kr * 128 + c4 * 4) =
                *(const float4*)(We1 + (size_t)(kc * 32 + kr) * 128 + c4 * 4);
        }
        __syncthreads();
#pragma unroll
        for (int k4 = 0; k4 < 32; k4 += 4) {
            float4 av[4];
#pragma unroll
            for (int i = 0; i < 4; ++i)
                av[i] = *(const float4*)(As + (rg * 4 + i) * 36 + k4);
            const float* avp = (const float*)av;
#pragma unroll
            for (int kk = 0; kk < 4; ++kk) {
                float4 w0 = *(const float4*)(Wsh + (k4 + kk) * 128 + cg * 8);
                float4 w1 = *(const float4*)(Wsh + (k4 + kk) * 128 + cg * 8 + 4);
#pragma unroll
                for (int i = 0; i < 4; ++i) {
                    float a = avp[i * 4 + kk];
                    acc[i][0] = fmaf(a, w0.x, acc[i][0]);
                    acc[i][1] = fmaf(a, w0.y, acc[i][1]);
                    acc[i][2] = fmaf(a, w0.z, acc[i][2]);
                    acc[i][3] = fmaf(a, w0.w, acc[i][3]);
                    acc[i][4] = fmaf(a, w1.x, acc[i][4]);
                    acc[i][5] = fmaf(a, w1.y, acc[i][5]);
                    acc[i][6] = fmaf(a, w1.z, acc[i][6]);
                    acc[i][7] = fmaf(a, w1.w, acc[i][7]);
                }
            }
        }
        __syncthreads();
    }

    // bias + relu -> Hid (reuse LDS; all As/Wsh reads done at last barrier)
    float* Hid = smem;  // [64][132]
#pragma unroll
    for (int i = 0; i < 4; ++i) {
        int e = rg * 4 + i;
#pragma unroll
        for (int j = 0; j < 8; ++j) {
            int c = cg * 8 + j;
            Hid[e * 132 + c] = fmaxf(acc[i][j] + be1[c], 0.f);
        }
    }
    __syncthreads();

    // second layer: out[e][0..7] = Hid[e] @ We2 + be2
    {
        int e = t >> 2, cq = t & 3;
        float s0 = be2[cq], s1 = be2[cq + 4];
#pragma unroll
        for (int k4 = 0; k4 < 32; ++k4) {
            float4 hv = *(const float4*)(Hid + e * 132 + k4 * 4);
            s0 = fmaf(hv.x, We2[(k4 * 4 + 0) * 8 + cq], s0);
            s1 = fmaf(hv.x, We2[(k4 * 4 + 0) * 8 + cq + 4], s1);
            s0 = fmaf(hv.y, We2[(k4 * 4 + 1) * 8 + cq], s0);
            s1 = fmaf(hv.y, We2[(k4 * 4 + 1) * 8 + cq + 4], s1);
            s0 = fmaf(hv.z, We2[(k4 * 4 + 2) * 8 + cq], s0);
            s1 = fmaf(hv.z, We2[(k4 * 4 + 2) * 8 + cq + 4], s1);
            s0 = fmaf(hv.w, We2[(k4 * 4 + 3) * 8 + cq], s0);
            s1 = fmaf(hv.w, We2[(k4 * 4 + 3) * 8 + cq + 4], s1);
        }
        out[(size_t)(eb + e) * 8 + cq] = s0;
        out[(size_t)(eb + e) * 8 + cq + 4] = s1;
    }
}

// ---------------------------------------------------------------------------
extern "C" void kernel_launch(void* const* d_in, const int* in_sizes, int n_in,
                              void* d_out, int out_size, void* d_ws, size_t ws_size,
                              hipStream_t stream) {
    const float* x   = (const float*)d_in[0];
    const float* ef  = (const float*)d_in[1];
    const float* Ws1 = (const float*)d_in[2];
    const float* Wn1 = (const float*)d_in[3];
    const float* b1  = (const float*)d_in[4];
    const float* g1  = (const float*)d_in[5];
    const float* bt1 = (const float*)d_in[6];
    const float* Ws2 = (const float*)d_in[7];
    const float* Wn2 = (const float*)d_in[8];
    const float* b2  = (const float*)d_in[9];
    const float* g2  = (const float*)d_in[10];
    const float* bt2 = (const float*)d_in[11];
    const float* We1 = (const float*)d_in[12];
    const float* be1 = (const float*)d_in[13];
    const float* We2 = (const float*)d_in[14];
    const float* be2 = (const float*)d_in[15];
    const int* src = (const int*)d_in[16];
    const int* dst = (const int*)d_in[17];
    const int* u   = (const int*)d_in[18];
    const int* v   = (const int*)d_in[19];
    float* out = (float*)d_out;

    // Workspace layout (floats). Total: 2N + 512 + 2*N*128 = ~25.8M floats (~103 MB).
    // h1 lives in d_out (N*128 == E*8 == out_size exactly); it is fully dead
    // before k_edge_mlp overwrites d_out with the final result.
    float* ws    = (float*)d_ws;
    float* deg   = ws;                       // N
    float* invd  = ws + NN;                  // N
    float* stats = ws + 2 * NN;              // 256
    float* ab    = ws + 2 * NN + 256;        // 256
    float* agg   = ws + 2 * NN + 512;        // N*128 (layer1 uses stride 64)
    float* h2    = agg + (size_t)NN * 128;   // N*128
    float* h1    = out;                      // N*128 scratch in d_out

    // degrees
    hipMemsetAsync(deg, 0, NN * sizeof(float), stream);
    k_deg<<<(EE + 255) / 256, 256, 0, stream>>>(dst, deg);
    k_invdeg<<<(NN + 255) / 256, 256, 0, stream>>>(deg, invd);

    // ---- layer 1 ----
    hipMemsetAsync(agg, 0, (size_t)NN * 64 * sizeof(float), stream);
    k_scatter<64><<<(EE * 16 + 255) / 256, 256, 0, stream>>>(x, src, dst, agg);
    k_node_gemm<64, 64><<<(NN + 63) / 64, 256, 0, stream>>>(x, agg, invd, Ws1, Wn1, b1, h1);
    hipMemsetAsync(stats, 0, 256 * sizeof(float), stream);
    k_colstats<<<256, 256, 0, stream>>>(h1, stats);
    k_bnfin<<<1, 128, 0, stream>>>(stats, g1, bt1, ab);
    k_bnrelu<<<(NN * 32 + 255) / 256, 256, 0, stream>>>(h1, ab);

    // ---- layer 2 ----
    hipMemsetAsync(agg, 0, (size_t)NN * 128 * sizeof(float), stream);
    k_scatter<128><<<(EE * 32 + 255) / 256, 256, 0, stream>>>(h1, src, dst, agg);
    k_node_gemm<128, 128><<<(NN + 63) / 64, 256, 0, stream>>>(h1, agg, invd, Ws2, Wn2, b2, h2);
    hipMemsetAsync(stats, 0, 256 * sizeof(float), stream);
    k_colstats<<<256, 256, 0, stream>>>(h2, stats);
    k_bnfin<<<1, 128, 0, stream>>>(stats, g2, bt2, ab);
    k_bnrelu<<<(NN * 32 + 255) / 256, 256, 0, stream>>>(h2, ab);

    // ---- edge head ----
    k_edge_mlp<<<EE / 64, 256, 0, stream>>>(h2, ef, We1, be1, We2, be2, u, v, out);
}

// Round 2
// 3107.553 us; speedup vs baseline: 2.2378x; 2.2378x over previous
//
#include <hip/hip_runtime.h>

// Problem constants (fixed by the reference).
#define NN 100000
#define EE 1600000
// D_IN=64, H=128, E_IN=64, C=8
constexpr float BN_EPS = 1e-5f;

// ---------------------------------------------------------------------------
// CSR build: count -> scan -> fill
// ---------------------------------------------------------------------------
__global__ void k_count(const int* __restrict__ dst, int* __restrict__ cnt) {
    int e = blockIdx.x * 256 + threadIdx.x;
    if (e < EE) atomicAdd(&cnt[dst[e]], 1);
}

// Single-block exclusive scan over cnt[N]; also emits cursor copy and inv_deg.
__global__ __launch_bounds__(1024) void k_scan(const int* __restrict__ cnt,
                                               int* __restrict__ offs,
                                               int* __restrict__ cursor,
                                               float* __restrict__ invd) {
    const int t = threadIdx.x, lane = t & 63, w = t >> 6;  // 16 waves
    __shared__ int wsum[16], wexcl[16];
    __shared__ int carry_sh;
    if (t == 0) carry_sh = 0;
    __syncthreads();
    int ss = 0;  // block total lives in t==15's copy
    for (int base = 0; base < NN; base += 1024) {
        int i = base + t;
        int v = (i < NN) ? cnt[i] : 0;
        int s = v;
#pragma unroll
        for (int d = 1; d < 64; d <<= 1) {
            int o = __shfl_up(s, d, 64);
            if (lane >= d) s += o;
        }
        if (lane == 63) wsum[w] = s;
        __syncthreads();
        if (t < 16) {
            int wv = wsum[t];
            ss = wv;
#pragma unroll
            for (int d = 1; d < 16; d <<= 1) {
                int o = __shfl_up(ss, d, 16);
                if (t >= d) ss += o;
            }
            wexcl[t] = ss - wv;
        }
        __syncthreads();
        int excl = (s - v) + wexcl[w];
        int c = carry_sh;
        if (i < NN) {
            int o = c + excl;
            offs[i] = o;
            cursor[i] = o;
            invd[i] = v > 0 ? 1.f / (float)v : 0.f;  // DGL mean: zero-degree -> 0
        }
        __syncthreads();  // all reads of carry_sh done
        if (t == 15) carry_sh = c + ss;
        __syncthreads();
    }
    if (t == 0) offs[NN] = carry_sh;
}

__global__ void k_fill(const int* __restrict__ src, const int* __restrict__ dst,
                       int* __restrict__ cursor, int* __restrict__ eidsrc) {
    int e = blockIdx.x * 256 + threadIdx.x;
    if (e < EE) {
        int pos = atomicAdd(&cursor[dst[e]], 1);
        eidsrc[pos] = src[e];
    }
}

// ---------------------------------------------------------------------------
// CSR mean-aggregation: one wave per dst node, coalesced row gathers.
// agg[n] = inv_deg[n] * sum_{s in N(n)} h[s]
// ---------------------------------------------------------------------------
template <int F>
__global__ __launch_bounds__(256) void k_gather_agg(
    const float* __restrict__ h, const int* __restrict__ offs,
    const int* __restrict__ eidsrc, const float* __restrict__ invd,
    float* __restrict__ agg) {
    int node = (blockIdx.x * 256 + threadIdx.x) >> 6;
    int lane = threadIdx.x & 63;
    if (node >= NN) return;
    int beg = offs[node], end = offs[node + 1];
    float iv = invd[node];
    if constexpr (F == 128) {
        float2 s = {0.f, 0.f};
        for (int p = beg; p < end; ++p) {
            int sn = eidsrc[p];
            float2 v = *(const float2*)(h + (size_t)sn * 128 + lane * 2);
            s.x += v.x;
            s.y += v.y;
        }
        s.x *= iv;
        s.y *= iv;
        *(float2*)(agg + (size_t)node * 128 + lane * 2) = s;
    } else {
        float s = 0.f;
        for (int p = beg; p < end; ++p) s += h[(size_t)eidsrc[p] * 64 + lane];
        agg[(size_t)node * 64 + lane] = s * iv;
    }
}

// ---------------------------------------------------------------------------
// node GEMM: out[N,128] = [A1 | A2] @ [W1 ; W2] + bias
// block = 256 threads, tile = 64 rows x 128 cols, per-thread 4x8 acc.
// NOTE: `out` may alias A2 (each block reads only its own 64 rows, then
// writes those same rows after the k-loop) -> no __restrict__ on A2/out.
// ---------------------------------------------------------------------------
template <int K1, int K2>
__global__ __launch_bounds__(256) void k_node_gemm(
    const float* __restrict__ A1, const float* A2,
    const float* __restrict__ W1, const float* __restrict__ W2,
    const float* __restrict__ bias, float* out) {
    __shared__ float As[64][17];  // +1 pad: conflict-free
    __shared__ float Ws[16][128];
    const int t = threadIdx.x;
    const int cg = t & 15;  // col group
    const int rg = t >> 4;  // row group: rows rg*4..+3
    const int rowbase = blockIdx.x * 64;

    float acc[4][8];
#pragma unroll
    for (int i = 0; i < 4; ++i)
#pragma unroll
        for (int j = 0; j < 8; ++j) acc[i][j] = 0.f;

    constexpr int KT = K1 + K2;
    const int lk = t & 15, lr0 = t >> 4;

    for (int kb = 0; kb < KT; kb += 16) {
        // stage A chunk (source is uniform per chunk since K1 % 16 == 0)
        {
            int g = kb + lk;
            const float* Asrc;
            int Kst, gg;
            if (g < K1) { Asrc = A1; Kst = K1; gg = g; }
            else        { Asrc = A2; Kst = K2; gg = g - K1; }
#pragma unroll
            for (int p = 0; p < 4; ++p) {
                int r = lr0 + 16 * p;
                int row = rowbase + r;
                As[r][lk] = (row < NN) ? Asrc[(size_t)row * Kst + gg] : 0.f;
            }
        }
        // stage W chunk [16 x 128]
#pragma unroll
        for (int p = 0; p < 8; ++p) {
            int idx = t + 256 * p;
            int kr = idx >> 7, col = idx & 127;
            int gw = kb + kr;
            Ws[kr][col] = (gw < K1) ? W1[gw * 128 + col] : W2[(gw - K1) * 128 + col];
        }
        __syncthreads();
#pragma unroll
        for (int k = 0; k < 16; ++k) {
            float a0 = As[rg * 4 + 0][k], a1 = As[rg * 4 + 1][k];
            float a2 = As[rg * 4 + 2][k], a3 = As[rg * 4 + 3][k];
#pragma unroll
            for (int j = 0; j < 8; ++j) {
                float w = Ws[k][cg + 16 * j];
                acc[0][j] = fmaf(a0, w, acc[0][j]);
                acc[1][j] = fmaf(a1, w, acc[1][j]);
                acc[2][j] = fmaf(a2, w, acc[2][j]);
                acc[3][j] = fmaf(a3, w, acc[3][j]);
            }
        }
        __syncthreads();
    }
#pragma unroll
    for (int i = 0; i < 4; ++i) {
        int row = rowbase + rg * 4 + i;
        if (row < NN) {
#pragma unroll
            for (int j = 0; j < 8; ++j) {
                int c = cg + 16 * j;
                out[(size_t)row * 128 + c] = acc[i][j] + bias[c];
            }
        }
    }
}

// ---------------------------------------------------------------------------
// per-column sum / sumsq over [N,128]
// ---------------------------------------------------------------------------
__global__ void k_colstats(const float* __restrict__ h, float* __restrict__ stats) {
    const int t = threadIdx.x;
    const int col = t & 127, half = t >> 7;
    float s = 0.f, ss = 0.f;
    for (int row = blockIdx.x * 2 + half; row < NN; row += gridDim.x * 2) {
        float v = h[(size_t)row * 128 + col];
        s += v;
        ss += v * v;
    }
    __shared__ float red[256];
    red[t] = s;
    __syncthreads();
    if (t < 128) atomicAdd(&stats[col], red[t] + red[t + 128]);
    __syncthreads();
    red[t] = ss;
    __syncthreads();
    if (t < 128) atomicAdd(&stats[128 + col], red[t] + red[t + 128]);
}

// stats -> BN scale a, shift b:  y = a*x + b, a = g*rsqrt(var+eps), b = bt - mu*a
__global__ void k_bnfin(const float* __restrict__ stats, const float* __restrict__ g,
                        const float* __restrict__ bt, float* __restrict__ ab) {
    int c = threadIdx.x;  // 128 threads
    float mu = stats[c] * (1.f / NN);
    float ex2 = stats[128 + c] * (1.f / NN);
    float var = ex2 - mu * mu;  // biased variance (matches reference)
    float a = g[c] * rsqrtf(var + BN_EPS);
    ab[c] = a;
    ab[128 + c] = bt[c] - mu * a;
}

// in-place BN + ReLU over [N,128], float4-vectorized
__global__ void k_bnrelu(float* __restrict__ h, const float* __restrict__ ab) {
    int idx = blockIdx.x * 256 + threadIdx.x;  // over NN*32 float4s
    if (idx >= NN * 32) return;
    int c4 = idx & 31;
    float4 v = reinterpret_cast<float4*>(h)[idx];
    const float4 a = reinterpret_cast<const float4*>(ab)[c4];
    const float4 b = reinterpret_cast<const float4*>(ab)[32 + c4];
    v.x = fmaxf(fmaf(a.x, v.x, b.x), 0.f);
    v.y = fmaxf(fmaf(a.y, v.y, b.y), 0.f);
    v.z = fmaxf(fmaf(a.z, v.z, b.z), 0.f);
    v.w = fmaxf(fmaf(a.w, v.w, b.w), 0.f);
    reinterpret_cast<float4*>(h)[idx] = v;
}

// ---------------------------------------------------------------------------
// fused edge MLP: out = relu([h[u]|h[v]|ef] @ We1 + be1) @ We2 + be2
// block = 256 threads, 64 edges; K=320 staged in chunks of 32.
// phase-2 reuses the LDS union for hid[64][132].
// ---------------------------------------------------------------------------
__global__ __launch_bounds__(256) void k_edge_mlp(
    const float* __restrict__ h, const float* __restrict__ ef,
    const float* __restrict__ We1, const float* __restrict__ be1,
    const float* __restrict__ We2, const float* __restrict__ be2,
    const int* __restrict__ uu, const int* __restrict__ vv,
    float* __restrict__ out) {
    __shared__ __align__(16) float smem[8448];  // union: phase1 As+Wsh / phase2 Hid
    float* As = smem;                            // [64][36]
    float* Wsh = smem + 64 * 36;                 // [32][128]
    __shared__ int su[64], sv[64];
    const int t = threadIdx.x;
    const int eb = blockIdx.x * 64;
    if (t < 64) {
        su[t] = uu[eb + t];
        sv[t] = vv[eb + t];
    }
    __syncthreads();

    const int cg = t & 15;  // cols cg*8 .. cg*8+7
    const int rg = t >> 4;  // edges rg*4 .. +3
    float acc[4][8];
#pragma unroll
    for (int i = 0; i < 4; ++i)
#pragma unroll
        for (int j = 0; j < 8; ++j) acc[i][j] = 0.f;

    const int f4 = t & 7, e0 = t >> 3;

    for (int kc = 0; kc < 10; ++kc) {
        // stage gathered A rows: [h[u] (chunks 0-3) | h[v] (4-7) | ef (8-9)]
#pragma unroll
        for (int p = 0; p < 2; ++p) {
            int e = e0 + 32 * p;
            float4 val;
            if (kc < 4)
                val = *(const float4*)(h + (size_t)su[e] * 128 + kc * 32 + f4 * 4);
            else if (kc < 8)
                val = *(const float4*)(h + (size_t)sv[e] * 128 + (kc - 4) * 32 + f4 * 4);
            else
                val = *(const float4*)(ef + (size_t)(eb + e) * 64 + (kc - 8) * 32 + f4 * 4);
            *(float4*)(As + e * 36 + f4 * 4) = val;
        }
        // stage We1 chunk [32 x 128]
#pragma unroll
        for (int p = 0; p < 4; ++p) {
            int idx = t + 256 * p;  // 1024 float4s
            int kr = idx >> 5, c4 = idx & 31;
            *(float4*)(Wsh + kr * 128 + c4 * 4) =
                *(const float4*)(We1 + (size_t)(kc * 32 + kr) * 128 + c4 * 4);
        }
        __syncthreads();
#pragma unroll
        for (int k4 = 0; k4 < 32; k4 += 4) {
            float4 av[4];
#pragma unroll
            for (int i = 0; i < 4; ++i)
                av[i] = *(const float4*)(As + (rg * 4 + i) * 36 + k4);
            const float* avp = (const float*)av;
#pragma unroll
            for (int kk = 0; kk < 4; ++kk) {
                float4 w0 = *(const float4*)(Wsh + (k4 + kk) * 128 + cg * 8);
                float4 w1 = *(const float4*)(Wsh + (k4 + kk) * 128 + cg * 8 + 4);
#pragma unroll
                for (int i = 0; i < 4; ++i) {
                    float a = avp[i * 4 + kk];
                    acc[i][0] = fmaf(a, w0.x, acc[i][0]);
                    acc[i][1] = fmaf(a, w0.y, acc[i][1]);
                    acc[i][2] = fmaf(a, w0.z, acc[i][2]);
                    acc[i][3] = fmaf(a, w0.w, acc[i][3]);
                    acc[i][4] = fmaf(a, w1.x, acc[i][4]);
                    acc[i][5] = fmaf(a, w1.y, acc[i][5]);
                    acc[i][6] = fmaf(a, w1.z, acc[i][6]);
                    acc[i][7] = fmaf(a, w1.w, acc[i][7]);
                }
            }
        }
        __syncthreads();
    }

    // bias + relu -> Hid (reuse LDS; all As/Wsh reads done at last barrier)
    float* Hid = smem;  // [64][132]
#pragma unroll
    for (int i = 0; i < 4; ++i) {
        int e = rg * 4 + i;
#pragma unroll
        for (int j = 0; j < 8; ++j) {
            int c = cg * 8 + j;
            Hid[e * 132 + c] = fmaxf(acc[i][j] + be1[c], 0.f);
        }
    }
    __syncthreads();

    // second layer: out[e][0..7] = Hid[e] @ We2 + be2
    {
        int e = t >> 2, cq = t & 3;
        float s0 = be2[cq], s1 = be2[cq + 4];
#pragma unroll
        for (int k4 = 0; k4 < 32; ++k4) {
            float4 hv = *(const float4*)(Hid + e * 132 + k4 * 4);
            s0 = fmaf(hv.x, We2[(k4 * 4 + 0) * 8 + cq], s0);
            s1 = fmaf(hv.x, We2[(k4 * 4 + 0) * 8 + cq + 4], s1);
            s0 = fmaf(hv.y, We2[(k4 * 4 + 1) * 8 + cq], s0);
            s1 = fmaf(hv.y, We2[(k4 * 4 + 1) * 8 + cq + 4], s1);
            s0 = fmaf(hv.z, We2[(k4 * 4 + 2) * 8 + cq], s0);
            s1 = fmaf(hv.z, We2[(k4 * 4 + 2) * 8 + cq + 4], s1);
            s0 = fmaf(hv.w, We2[(k4 * 4 + 3) * 8 + cq], s0);
            s1 = fmaf(hv.w, We2[(k4 * 4 + 3) * 8 + cq + 4], s1);
        }
        out[(size_t)(eb + e) * 8 + cq] = s0;
        out[(size_t)(eb + e) * 8 + cq + 4] = s1;
    }
}

// ---------------------------------------------------------------------------
extern "C" void kernel_launch(void* const* d_in, const int* in_sizes, int n_in,
                              void* d_out, int out_size, void* d_ws, size_t ws_size,
                              hipStream_t stream) {
    const float* x   = (const float*)d_in[0];
    const float* ef  = (const float*)d_in[1];
    const float* Ws1 = (const float*)d_in[2];
    const float* Wn1 = (const float*)d_in[3];
    const float* b1  = (const float*)d_in[4];
    const float* g1  = (const float*)d_in[5];
    const float* bt1 = (const float*)d_in[6];
    const float* Ws2 = (const float*)d_in[7];
    const float* Wn2 = (const float*)d_in[8];
    const float* b2  = (const float*)d_in[9];
    const float* g2  = (const float*)d_in[10];
    const float* bt2 = (const float*)d_in[11];
    const float* We1 = (const float*)d_in[12];
    const float* be1 = (const float*)d_in[13];
    const float* We2 = (const float*)d_in[14];
    const float* be2 = (const float*)d_in[15];
    const int* src = (const int*)d_in[16];
    const int* dst = (const int*)d_in[17];
    const int* u   = (const int*)d_in[18];
    const int* v   = (const int*)d_in[19];
    float* out = (float*)d_out;

    // Workspace layout (~85 MB, under the 103 MB proven in round 1).
    // h1 lives in d_out (N*128 == E*8 == out_size exactly); dead before the
    // edge head overwrites d_out. Layer-2 GEMM writes h2 in place over agg2.
    char* p = (char*)d_ws;
    auto take = [&](size_t bytes) {
        char* r = p;
        p += (bytes + 255) & ~(size_t)255;
        return r;
    };
    float* invd   = (float*)take(NN * 4);
    float* stats  = (float*)take(256 * 4);
    float* ab     = (float*)take(256 * 4);
    int* cnt      = (int*)take(NN * 4);
    int* offs     = (int*)take((NN + 1) * 4);
    int* cursor   = (int*)take(NN * 4);
    int* eidsrc   = (int*)take((size_t)EE * 4);
    float* agg1   = (float*)take((size_t)NN * 64 * 4);
    float* agg2   = (float*)take((size_t)NN * 128 * 4);
    float* h1 = out;
    float* h2 = agg2;  // GEMM output aliases agg2 (per-block rows only)

    // ---- CSR build (reused by both layers) ----
    hipMemsetAsync(cnt, 0, NN * sizeof(int), stream);
    k_count<<<(EE + 255) / 256, 256, 0, stream>>>(dst, cnt);
    k_scan<<<1, 1024, 0, stream>>>(cnt, offs, cursor, invd);
    k_fill<<<(EE + 255) / 256, 256, 0, stream>>>(src, dst, cursor, eidsrc);

    // ---- layer 1 ----
    k_gather_agg<64><<<(NN + 3) / 4, 256, 0, stream>>>(x, offs, eidsrc, invd, agg1);
    k_node_gemm<64, 64><<<(NN + 63) / 64, 256, 0, stream>>>(x, agg1, Ws1, Wn1, b1, h1);
    hipMemsetAsync(stats, 0, 256 * sizeof(float), stream);
    k_colstats<<<256, 256, 0, stream>>>(h1, stats);
    k_bnfin<<<1, 128, 0, stream>>>(stats, g1, bt1, ab);
    k_bnrelu<<<(NN * 32 + 255) / 256, 256, 0, stream>>>(h1, ab);

    // ---- layer 2 ----
    k_gather_agg<128><<<(NN + 3) / 4, 256, 0, stream>>>(h1, offs, eidsrc, invd, agg2);
    k_node_gemm<128, 128><<<(NN + 63) / 64, 256, 0, stream>>>(h1, agg2, Ws2, Wn2, b2, h2);
    hipMemsetAsync(stats, 0, 256 * sizeof(float), stream);
    k_colstats<<<256, 256, 0, stream>>>(h2, stats);
    k_bnfin<<<1, 128, 0, stream>>>(stats, g2, bt2, ab);
    k_bnrelu<<<(NN * 32 + 255) / 256, 256, 0, stream>>>(h2, ab);

    // ---- edge head ----
    k_edge_mlp<<<EE / 64, 256, 0, stream>>>(h2, ef, We1, be1, We2, be2, u, v, out);
}

// Round 3
// 1294.062 us; speedup vs baseline: 5.3739x; 2.4014x over previous
//
#include <hip/hip_runtime.h>

// Problem constants (fixed by the reference).
#define NN 100000
#define EE 1600000
// D_IN=64, H=128, E_IN=64, C=8
constexpr float BN_EPS = 1e-5f;

typedef __attribute__((ext_vector_type(8))) short short8;
typedef __attribute__((ext_vector_type(4))) float f32x4;

__device__ __forceinline__ short f2bf(float f) {  // RNE f32 -> bf16
    unsigned u = __float_as_uint(f);
    u += 0x7fff + ((u >> 16) & 1);
    return (short)(u >> 16);
}
__device__ __forceinline__ float bf2f(short s) {
    return __uint_as_float(((unsigned)(unsigned short)s) << 16);
}

// ---------------------------------------------------------------------------
// CSR build: count -> scan -> fill
// ---------------------------------------------------------------------------
__global__ void k_count(const int* __restrict__ dst, int* __restrict__ cnt) {
    int e = blockIdx.x * 256 + threadIdx.x;
    if (e < EE) atomicAdd(&cnt[dst[e]], 1);
}

__global__ __launch_bounds__(1024) void k_scan(const int* __restrict__ cnt,
                                               int* __restrict__ offs,
                                               int* __restrict__ cursor,
                                               float* __restrict__ invd) {
    const int t = threadIdx.x, lane = t & 63, w = t >> 6;  // 16 waves
    __shared__ int wsum[16], wexcl[16];
    __shared__ int carry_sh;
    if (t == 0) carry_sh = 0;
    __syncthreads();
    int ss = 0;
    for (int base = 0; base < NN; base += 1024) {
        int i = base + t;
        int v = (i < NN) ? cnt[i] : 0;
        int s = v;
#pragma unroll
        for (int d = 1; d < 64; d <<= 1) {
            int o = __shfl_up(s, d, 64);
            if (lane >= d) s += o;
        }
        if (lane == 63) wsum[w] = s;
        __syncthreads();
        if (t < 16) {
            int wv = wsum[t];
            ss = wv;
#pragma unroll
            for (int d = 1; d < 16; d <<= 1) {
                int o = __shfl_up(ss, d, 16);
                if (t >= d) ss += o;
            }
            wexcl[t] = ss - wv;
        }
        __syncthreads();
        int excl = (s - v) + wexcl[w];
        int c = carry_sh;
        if (i < NN) {
            int o = c + excl;
            offs[i] = o;
            cursor[i] = o;
            invd[i] = v > 0 ? 1.f / (float)v : 0.f;  // DGL mean: zero-degree -> 0
        }
        __syncthreads();
        if (t == 15) carry_sh = c + ss;
        __syncthreads();
    }
    if (t == 0) offs[NN] = carry_sh;
}

__global__ void k_fill(const int* __restrict__ src, const int* __restrict__ dst,
                       int* __restrict__ cursor, int* __restrict__ eidsrc) {
    int e = blockIdx.x * 256 + threadIdx.x;
    if (e < EE) {
        int pos = atomicAdd(&cursor[dst[e]], 1);
        eidsrc[pos] = src[e];
    }
}

// ---------------------------------------------------------------------------
// CSR mean-aggregation: one wave per dst node.
// ---------------------------------------------------------------------------
template <int F>
__global__ __launch_bounds__(256) void k_gather_agg(
    const float* __restrict__ h, const int* __restrict__ offs,
    const int* __restrict__ eidsrc, const float* __restrict__ invd,
    float* __restrict__ agg) {
    int node = (blockIdx.x * 256 + threadIdx.x) >> 6;
    int lane = threadIdx.x & 63;
    if (node >= NN) return;
    int beg = offs[node], end = offs[node + 1];
    float iv = invd[node];
    if constexpr (F == 128) {
        float2 s = {0.f, 0.f};
        for (int p = beg; p < end; ++p) {
            int sn = eidsrc[p];
            float2 v = *(const float2*)(h + (size_t)sn * 128 + lane * 2);
            s.x += v.x;
            s.y += v.y;
        }
        s.x *= iv;
        s.y *= iv;
        *(float2*)(agg + (size_t)node * 128 + lane * 2) = s;
    } else {
        float s = 0.f;
        for (int p = beg; p < end; ++p) s += h[(size_t)eidsrc[p] * 64 + lane];
        agg[(size_t)node * 64 + lane] = s * iv;
    }
}

// ---------------------------------------------------------------------------
// node GEMM: out[N,128] = [A1 | A2] @ [W1 ; W2] + bias (fp32 VALU, small)
// `out` may alias A2 (per-block rows only).
// ---------------------------------------------------------------------------
template <int K1, int K2>
__global__ __launch_bounds__(256) void k_node_gemm(
    const float* __restrict__ A1, const float* A2,
    const float* __restrict__ W1, const float* __restrict__ W2,
    const float* __restrict__ bias, float* out) {
    __shared__ float As[64][17];
    __shared__ float Ws[16][128];
    const int t = threadIdx.x;
    const int cg = t & 15;
    const int rg = t >> 4;
    const int rowbase = blockIdx.x * 64;

    float acc[4][8];
#pragma unroll
    for (int i = 0; i < 4; ++i)
#pragma unroll
        for (int j = 0; j < 8; ++j) acc[i][j] = 0.f;

    constexpr int KT = K1 + K2;
    const int lk = t & 15, lr0 = t >> 4;

    for (int kb = 0; kb < KT; kb += 16) {
        {
            int g = kb + lk;
            const float* Asrc;
            int Kst, gg;
            if (g < K1) { Asrc = A1; Kst = K1; gg = g; }
            else        { Asrc = A2; Kst = K2; gg = g - K1; }
#pragma unroll
            for (int p = 0; p < 4; ++p) {
                int r = lr0 + 16 * p;
                int row = rowbase + r;
                As[r][lk] = (row < NN) ? Asrc[(size_t)row * Kst + gg] : 0.f;
            }
        }
#pragma unroll
        for (int p = 0; p < 8; ++p) {
            int idx = t + 256 * p;
            int kr = idx >> 7, col = idx & 127;
            int gw = kb + kr;
            Ws[kr][col] = (gw < K1) ? W1[gw * 128 + col] : W2[(gw - K1) * 128 + col];
        }
        __syncthreads();
#pragma unroll
        for (int k = 0; k < 16; ++k) {
            float a0 = As[rg * 4 + 0][k], a1 = As[rg * 4 + 1][k];
            float a2 = As[rg * 4 + 2][k], a3 = As[rg * 4 + 3][k];
#pragma unroll
            for (int j = 0; j < 8; ++j) {
                float w = Ws[k][cg + 16 * j];
                acc[0][j] = fmaf(a0, w, acc[0][j]);
                acc[1][j] = fmaf(a1, w, acc[1][j]);
                acc[2][j] = fmaf(a2, w, acc[2][j]);
                acc[3][j] = fmaf(a3, w, acc[3][j]);
            }
        }
        __syncthreads();
    }
#pragma unroll
    for (int i = 0; i < 4; ++i) {
        int row = rowbase + rg * 4 + i;
        if (row < NN) {
#pragma unroll
            for (int j = 0; j < 8; ++j) {
                int c = cg + 16 * j;
                out[(size_t)row * 128 + c] = acc[i][j] + bias[c];
            }
        }
    }
}

// ---------------------------------------------------------------------------
// per-column sum / sumsq over [N,128]
// ---------------------------------------------------------------------------
__global__ void k_colstats(const float* __restrict__ h, float* __restrict__ stats) {
    const int t = threadIdx.x;
    const int col = t & 127, half = t >> 7;
    float s = 0.f, ss = 0.f;
    for (int row = blockIdx.x * 2 + half; row < NN; row += gridDim.x * 2) {
        float v = h[(size_t)row * 128 + col];
        s += v;
        ss += v * v;
    }
    __shared__ float red[256];
    red[t] = s;
    __syncthreads();
    if (t < 128) atomicAdd(&stats[col], red[t] + red[t + 128]);
    __syncthreads();
    red[t] = ss;
    __syncthreads();
    if (t < 128) atomicAdd(&stats[128 + col], red[t] + red[t + 128]);
}

__global__ void k_bnfin(const float* __restrict__ stats, const float* __restrict__ g,
                        const float* __restrict__ bt, float* __restrict__ ab) {
    int c = threadIdx.x;
    float mu = stats[c] * (1.f / NN);
    float ex2 = stats[128 + c] * (1.f / NN);
    float var = ex2 - mu * mu;
    float a = g[c] * rsqrtf(var + BN_EPS);
    ab[c] = a;
    ab[128 + c] = bt[c] - mu * a;
}

// in-place BN + ReLU (fp32) — layer 1
__global__ void k_bnrelu(float* __restrict__ h, const float* __restrict__ ab) {
    int idx = blockIdx.x * 256 + threadIdx.x;
    if (idx >= NN * 32) return;
    int c4 = idx & 31;
    float4 v = reinterpret_cast<float4*>(h)[idx];
    const float4 a = reinterpret_cast<const float4*>(ab)[c4];
    const float4 b = reinterpret_cast<const float4*>(ab)[32 + c4];
    v.x = fmaxf(fmaf(a.x, v.x, b.x), 0.f);
    v.y = fmaxf(fmaf(a.y, v.y, b.y), 0.f);
    v.z = fmaxf(fmaf(a.z, v.z, b.z), 0.f);
    v.w = fmaxf(fmaf(a.w, v.w, b.w), 0.f);
    reinterpret_cast<float4*>(h)[idx] = v;
}

// BN + ReLU + convert to bf16 — layer 2 output feeding the MFMA edge head
__global__ void k_bnrelu_bf16(const float* __restrict__ h, const float* __restrict__ ab,
                              short* __restrict__ hb) {
    int gid = blockIdx.x * 256 + threadIdx.x;  // over NN*16 groups of 8
    if (gid >= NN * 16) return;
    int c8 = gid & 15;
    const float4 a0 = reinterpret_cast<const float4*>(ab)[c8 * 2];
    const float4 a1 = reinterpret_cast<const float4*>(ab)[c8 * 2 + 1];
    const float4 b0 = reinterpret_cast<const float4*>(ab)[32 + c8 * 2];
    const float4 b1 = reinterpret_cast<const float4*>(ab)[32 + c8 * 2 + 1];
    float4 v0 = reinterpret_cast<const float4*>(h)[gid * 2];
    float4 v1 = reinterpret_cast<const float4*>(h)[gid * 2 + 1];
    short8 o;
    o[0] = f2bf(fmaxf(fmaf(a0.x, v0.x, b0.x), 0.f));
    o[1] = f2bf(fmaxf(fmaf(a0.y, v0.y, b0.y), 0.f));
    o[2] = f2bf(fmaxf(fmaf(a0.z, v0.z, b0.z), 0.f));
    o[3] = f2bf(fmaxf(fmaf(a0.w, v0.w, b0.w), 0.f));
    o[4] = f2bf(fmaxf(fmaf(a1.x, v1.x, b1.x), 0.f));
    o[5] = f2bf(fmaxf(fmaf(a1.y, v1.y, b1.y), 0.f));
    o[6] = f2bf(fmaxf(fmaf(a1.z, v1.z, b1.z), 0.f));
    o[7] = f2bf(fmaxf(fmaf(a1.w, v1.w, b1.w), 0.f));
    reinterpret_cast<short8*>(hb)[gid] = o;
}

// ---------------------------------------------------------------------------
// Pre-pack We1 [320][128] f32 into bf16 MFMA-B fragment order:
// Wp[kc][slot][j], slot = cb*64 + bp*16 + n, content = We1[kc*32+8*bp+j][16*cb+n]
// ---------------------------------------------------------------------------
__global__ void k_pack_we1(const float* __restrict__ We1, short* __restrict__ Wp) {
    int idx = blockIdx.x * 256 + threadIdx.x;
    if (idx >= 320 * 128) return;
    int k = idx >> 7, col = idx & 127;
    int kc = k >> 5, kw = k & 31, bp = kw >> 3, j = kw & 7;
    int cb = col >> 4, n = col & 15;
    int slot = cb * 64 + bp * 16 + n;
    Wp[kc * 4096 + slot * 8 + j] = f2bf(We1[k * 128 + col]);
}

// ---------------------------------------------------------------------------
// MFMA edge MLP: out = relu([hb[u]|hb[v]|bf16(ef)] @ We1 + be1) @ We2 + be2
// 128 edges/block, 4 waves; wave w owns edge rows [32w,32w+32).
// A/B staged in fragment-contiguous LDS slots -> conflict-free ds_read_b128.
// ---------------------------------------------------------------------------
__global__ __launch_bounds__(256) void k_edge_mfma(
    const short* __restrict__ hb, const float* __restrict__ ef,
    const short* __restrict__ Wp, const float* __restrict__ be1,
    const float* __restrict__ We2, const float* __restrict__ be2,
    const int* __restrict__ uu, const int* __restrict__ vv,
    float* __restrict__ out) {
    __shared__ __align__(16) short smem[17408];  // Hid[128][136] | (A 4096 + B 4096)
    __shared__ float We2s[1024];
    __shared__ float be1s[128];
    __shared__ int suv[256];
    short* A_l = smem;
    short* B_l = smem + 4096;
    const int t = threadIdx.x;
    const int eb = blockIdx.x * 128;
    if (t < 128) {
        suv[t] = uu[eb + t];
        suv[128 + t] = vv[eb + t];
        be1s[t] = be1[t];
    }
    We2s[t] = We2[t];
    We2s[t + 256] = We2[t + 256];
    We2s[t + 512] = We2[t + 512];
    We2s[t + 768] = We2[t + 768];
    __syncthreads();

    const int lane = t & 63, w = t >> 6;
    const int srow = t >> 1;       // staging row (0..127)
    const int sb0 = (t & 1) * 2;   // staging k-subblock base {0,2}
    const int sslotbase = (srow >> 4) * 64 + (srow & 15);

    f32x4 acc[2][8];
#pragma unroll
    for (int i = 0; i < 2; ++i)
#pragma unroll
        for (int j = 0; j < 8; ++j) acc[i][j] = (f32x4){0.f, 0.f, 0.f, 0.f};

    for (int kc = 0; kc < 10; ++kc) {
        // ---- stage A (gathered rows -> fragment slots) ----
        if (kc < 8) {
            const short* hrow =
                hb + (size_t)suv[(kc >= 4) ? 128 + srow : srow] * 128 + (kc & 3) * 32;
            *(short8*)(A_l + (sslotbase + sb0 * 16) * 8) =
                *(const short8*)(hrow + sb0 * 8);
            *(short8*)(A_l + (sslotbase + (sb0 + 1) * 16) * 8) =
                *(const short8*)(hrow + (sb0 + 1) * 8);
        } else {
            const float* er = ef + (size_t)(eb + srow) * 64 + (kc - 8) * 32;
#pragma unroll
            for (int p = 0; p < 2; ++p) {
                int b = sb0 + p;
                float4 f0 = *(const float4*)(er + b * 8);
                float4 f1 = *(const float4*)(er + b * 8 + 4);
                short8 v8;
                v8[0] = f2bf(f0.x); v8[1] = f2bf(f0.y);
                v8[2] = f2bf(f0.z); v8[3] = f2bf(f0.w);
                v8[4] = f2bf(f1.x); v8[5] = f2bf(f1.y);
                v8[6] = f2bf(f1.z); v8[7] = f2bf(f1.w);
                *(short8*)(A_l + (sslotbase + b * 16) * 8) = v8;
            }
        }
        // ---- stage B (pre-packed, straight coalesced copy) ----
        *(short8*)(B_l + t * 8) = *(const short8*)(Wp + (size_t)kc * 4096 + t * 8);
        *(short8*)(B_l + (t + 256) * 8) =
            *(const short8*)(Wp + (size_t)kc * 4096 + (t + 256) * 8);
        __syncthreads();

        const int fo = (lane >> 4) * 16 + (lane & 15);
        short8 afr0 = *(const short8*)(A_l + ((2 * w) * 64 + fo) * 8);
        short8 afr1 = *(const short8*)(A_l + ((2 * w + 1) * 64 + fo) * 8);
#pragma unroll
        for (int cb = 0; cb < 8; ++cb) {
            short8 bfr = *(const short8*)(B_l + (cb * 64 + fo) * 8);
            acc[0][cb] = __builtin_amdgcn_mfma_f32_16x16x32_bf16(afr0, bfr, acc[0][cb], 0, 0, 0);
            acc[1][cb] = __builtin_amdgcn_mfma_f32_16x16x32_bf16(afr1, bfr, acc[1][cb], 0, 0, 0);
        }
        __syncthreads();
    }

    // ---- epilogue: bias + relu -> Hid[128][136] bf16 (reuses A/B region) ----
    short* Hid = smem;
#pragma unroll
    for (int rb2 = 0; rb2 < 2; ++rb2)
#pragma unroll
        for (int cb = 0; cb < 8; ++cb) {
            int col = cb * 16 + (lane & 15);
            int rbase = 32 * w + rb2 * 16 + ((lane >> 4) << 2);
            float bb = be1s[col];
#pragma unroll
            for (int i = 0; i < 4; ++i)
                Hid[(rbase + i) * 136 + col] = f2bf(fmaxf(acc[rb2][cb][i] + bb, 0.f));
        }
    __syncthreads();

    // ---- layer 2: out[e][c] = Hid[e] @ We2 + be2 ----
    {
        int e = t >> 1, c0 = (t & 1) * 4;
        float s0 = be2[c0], s1 = be2[c0 + 1], s2 = be2[c0 + 2], s3 = be2[c0 + 3];
#pragma unroll
        for (int k8 = 0; k8 < 16; ++k8) {
            short8 hv = *(const short8*)(Hid + e * 136 + k8 * 8);
#pragma unroll
            for (int j = 0; j < 8; ++j) {
                float h = bf2f(hv[j]);
                const float* wr = We2s + (k8 * 8 + j) * 8 + c0;
                s0 = fmaf(h, wr[0], s0);
                s1 = fmaf(h, wr[1], s1);
                s2 = fmaf(h, wr[2], s2);
                s3 = fmaf(h, wr[3], s3);
            }
        }
        *(float4*)(out + (size_t)(eb + e) * 8 + c0) = make_float4(s0, s1, s2, s3);
    }
}

// ---------------------------------------------------------------------------
extern "C" void kernel_launch(void* const* d_in, const int* in_sizes, int n_in,
                              void* d_out, int out_size, void* d_ws, size_t ws_size,
                              hipStream_t stream) {
    const float* x   = (const float*)d_in[0];
    const float* ef  = (const float*)d_in[1];
    const float* Ws1 = (const float*)d_in[2];
    const float* Wn1 = (const float*)d_in[3];
    const float* b1  = (const float*)d_in[4];
    const float* g1  = (const float*)d_in[5];
    const float* bt1 = (const float*)d_in[6];
    const float* Ws2 = (const float*)d_in[7];
    const float* Wn2 = (const float*)d_in[8];
    const float* b2  = (const float*)d_in[9];
    const float* g2  = (const float*)d_in[10];
    const float* bt2 = (const float*)d_in[11];
    const float* We1 = (const float*)d_in[12];
    const float* be1 = (const float*)d_in[13];
    const float* We2 = (const float*)d_in[14];
    const float* be2 = (const float*)d_in[15];
    const int* src = (const int*)d_in[16];
    const int* dst = (const int*)d_in[17];
    const int* u   = (const int*)d_in[18];
    const int* v   = (const int*)d_in[19];
    float* out = (float*)d_out;

    // Workspace (~85 MB). h1 lives in d_out; h2 aliases agg2; hb aliases agg1
    // (agg1 dead after layer-1 GEMM, hb written after layer-2 BN).
    char* p = (char*)d_ws;
    auto take = [&](size_t bytes) {
        char* r = p;
        p += (bytes + 255) & ~(size_t)255;
        return r;
    };
    float* invd  = (float*)take(NN * 4);
    float* stats = (float*)take(256 * 4);
    float* ab    = (float*)take(256 * 4);
    int* cnt     = (int*)take(NN * 4);
    int* offs    = (int*)take((NN + 1) * 4);
    int* cursor  = (int*)take(NN * 4);
    int* eidsrc  = (int*)take((size_t)EE * 4);
    short* Wp    = (short*)take(320 * 128 * 2);
    float* agg1  = (float*)take((size_t)NN * 64 * 4);
    float* agg2  = (float*)take((size_t)NN * 128 * 4);
    float* h1 = out;
    float* h2 = agg2;
    short* hb = (short*)agg1;  // N*128 bf16 = 25.6 MB <= agg1's 25.6 MB

    // ---- CSR build + weight pre-pack ----
    hipMemsetAsync(cnt, 0, NN * sizeof(int), stream);
    k_count<<<(EE + 255) / 256, 256, 0, stream>>>(dst, cnt);
    k_scan<<<1, 1024, 0, stream>>>(cnt, offs, cursor, invd);
    k_fill<<<(EE + 255) / 256, 256, 0, stream>>>(src, dst, cursor, eidsrc);
    k_pack_we1<<<160, 256, 0, stream>>>(We1, Wp);

    // ---- layer 1 ----
    k_gather_agg<64><<<(NN + 3) / 4, 256, 0, stream>>>(x, offs, eidsrc, invd, agg1);
    k_node_gemm<64, 64><<<(NN + 63) / 64, 256, 0, stream>>>(x, agg1, Ws1, Wn1, b1, h1);
    hipMemsetAsync(stats, 0, 256 * sizeof(float), stream);
    k_colstats<<<256, 256, 0, stream>>>(h1, stats);
    k_bnfin<<<1, 128, 0, stream>>>(stats, g1, bt1, ab);
    k_bnrelu<<<(NN * 32 + 255) / 256, 256, 0, stream>>>(h1, ab);

    // ---- layer 2 ----
    k_gather_agg<128><<<(NN + 3) / 4, 256, 0, stream>>>(h1, offs, eidsrc, invd, agg2);
    k_node_gemm<128, 128><<<(NN + 63) / 64, 256, 0, stream>>>(h1, agg2, Ws2, Wn2, b2, h2);
    hipMemsetAsync(stats, 0, 256 * sizeof(float), stream);
    k_colstats<<<256, 256, 0, stream>>>(h2, stats);
    k_bnfin<<<1, 128, 0, stream>>>(stats, g2, bt2, ab);
    k_bnrelu_bf16<<<(NN * 16 + 255) / 256, 256, 0, stream>>>(h2, ab, hb);

    // ---- edge head (bf16 MFMA) ----
    k_edge_mfma<<<EE / 128, 256, 0, stream>>>(hb, ef, Wp, be1, We2, be2, u, v, out);
}

// Round 4
// 1010.312 us; speedup vs baseline: 6.8832x; 1.2809x over previous
//
#include <hip/hip_runtime.h>

// Problem constants (fixed by the reference).
#define NN 100000
#define EE 1600000
// D_IN=64, H=128, E_IN=64, C=8
constexpr float BN_EPS = 1e-5f;

typedef __attribute__((ext_vector_type(8))) short short8;
typedef __attribute__((ext_vector_type(4))) float f32x4;

__device__ __forceinline__ short f2bf(float f) {  // RNE f32 -> bf16
    unsigned u = __float_as_uint(f);
    u += 0x7fff + ((u >> 16) & 1);
    return (short)(u >> 16);
}
__device__ __forceinline__ float bf2f(short s) {
    return __uint_as_float(((unsigned)(unsigned short)s) << 16);
}

// async global->LDS DMA, 16 B per lane. LDS dest must be base + lane*16
// within each wave (guaranteed by construction at all call sites).
typedef __attribute__((address_space(1))) const unsigned int guint;
typedef __attribute__((address_space(3))) unsigned int luint;
__device__ __forceinline__ void gload_lds16(const void* g, void* l) {
    __builtin_amdgcn_global_load_lds((guint*)g, (luint*)l, 16, 0, 0);
}

// ---------------------------------------------------------------------------
// CSR build: count -> scan -> fill
// ---------------------------------------------------------------------------
__global__ void k_count(const int* __restrict__ dst, int* __restrict__ cnt) {
    int e = blockIdx.x * 256 + threadIdx.x;
    if (e < EE) atomicAdd(&cnt[dst[e]], 1);
}

__global__ __launch_bounds__(1024) void k_scan(const int* __restrict__ cnt,
                                               int* __restrict__ offs,
                                               int* __restrict__ cursor,
                                               float* __restrict__ invd) {
    const int t = threadIdx.x, lane = t & 63, w = t >> 6;  // 16 waves
    __shared__ int wsum[16], wexcl[16];
    __shared__ int carry_sh;
    if (t == 0) carry_sh = 0;
    __syncthreads();
    int ss = 0;
    for (int base = 0; base < NN; base += 1024) {
        int i = base + t;
        int v = (i < NN) ? cnt[i] : 0;
        int s = v;
#pragma unroll
        for (int d = 1; d < 64; d <<= 1) {
            int o = __shfl_up(s, d, 64);
            if (lane >= d) s += o;
        }
        if (lane == 63) wsum[w] = s;
        __syncthreads();
        if (t < 16) {
            int wv = wsum[t];
            ss = wv;
#pragma unroll
            for (int d = 1; d < 16; d <<= 1) {
                int o = __shfl_up(ss, d, 16);
                if (t >= d) ss += o;
            }
            wexcl[t] = ss - wv;
        }
        __syncthreads();
        int excl = (s - v) + wexcl[w];
        int c = carry_sh;
        if (i < NN) {
            int o = c + excl;
            offs[i] = o;
            cursor[i] = o;
            invd[i] = v > 0 ? 1.f / (float)v : 0.f;  // DGL mean: zero-degree -> 0
        }
        __syncthreads();
        if (t == 15) carry_sh = c + ss;
        __syncthreads();
    }
    if (t == 0) offs[NN] = carry_sh;
}

__global__ void k_fill(const int* __restrict__ src, const int* __restrict__ dst,
                       int* __restrict__ cursor, int* __restrict__ eidsrc) {
    int e = blockIdx.x * 256 + threadIdx.x;
    if (e < EE) {
        int pos = atomicAdd(&cursor[dst[e]], 1);
        eidsrc[pos] = src[e];
    }
}

// ---------------------------------------------------------------------------
// fp32 -> bf16 bulk convert (8 elems/thread)
// ---------------------------------------------------------------------------
__global__ void k_f2bf(const float* __restrict__ in, short* __restrict__ out, int n8) {
    int i = blockIdx.x * 256 + threadIdx.x;
    if (i >= n8) return;
    float4 a = ((const float4*)in)[i * 2];
    float4 b = ((const float4*)in)[i * 2 + 1];
    short8 o;
    o[0] = f2bf(a.x); o[1] = f2bf(a.y); o[2] = f2bf(a.z); o[3] = f2bf(a.w);
    o[4] = f2bf(b.x); o[5] = f2bf(b.y); o[6] = f2bf(b.z); o[7] = f2bf(b.w);
    ((short8*)out)[i] = o;
}

// ---------------------------------------------------------------------------
// bf16 CSR mean-aggregation: L lanes per node, 2 cols/lane, fp32 accum.
// ---------------------------------------------------------------------------
template <int F>
__global__ __launch_bounds__(256) void k_gather_bf(
    const short* __restrict__ hbsrc, const int* __restrict__ offs,
    const int* __restrict__ eidsrc, const float* __restrict__ invd,
    short* __restrict__ aggb) {
    constexpr int L = (F == 128) ? 64 : 32;
    int node = (blockIdx.x * 256 + threadIdx.x) / L;
    int lane = threadIdx.x % L;
    if (node >= NN) return;
    int beg = offs[node], end = offs[node + 1];
    float iv = invd[node];
    float s0 = 0.f, s1 = 0.f;
    for (int p = beg; p < end; ++p) {
        int sn = eidsrc[p];
        unsigned pv = *(const unsigned*)(hbsrc + (size_t)sn * F + lane * 2);
        s0 += bf2f((short)(pv & 0xffff));
        s1 += bf2f((short)(pv >> 16));
    }
    s0 *= iv;
    s1 *= iv;
    unsigned o = (unsigned)(unsigned short)f2bf(s0) |
                 ((unsigned)(unsigned short)f2bf(s1) << 16);
    *(unsigned*)(aggb + (size_t)node * F + lane * 2) = o;
}

// ---------------------------------------------------------------------------
// Pack row-major fp32 W[rows][128] into bf16 MFMA-B fragment order at kbase:
// Wp[kc][slot][j], slot = cb*64 + bp*16 + n, content = W[k][16*cb+n], gk=k+kbase
// ---------------------------------------------------------------------------
__global__ void k_pack_w(const float* __restrict__ W, short* __restrict__ Wp,
                         int rows, int kbase) {
    int idx = blockIdx.x * 256 + threadIdx.x;
    if (idx >= rows * 128) return;
    int k = idx >> 7, col = idx & 127;
    int gk = k + kbase;
    int kc = gk >> 5, kw = gk & 31, bp = kw >> 3, j = kw & 7;
    int cb = col >> 4, n = col & 15;
    Wp[kc * 4096 + (cb * 64 + bp * 16 + n) * 8 + j] = f2bf(W[k * 128 + col]);
}

// ---------------------------------------------------------------------------
// bf16 MFMA node GEMM: outf[N,128] = [A1b | A2b] @ Wp + bias (fp32 out)
// 128 rows/block, 4 waves. A/B staged via global_load_lds into fragment slots.
// Rows >= NN read into pad (garbage, discarded at epilogue).
// ---------------------------------------------------------------------------
template <int KC1, int KC2>
__global__ __launch_bounds__(256) void k_node_mfma(
    const short* __restrict__ A1, const short* __restrict__ A2,
    const short* __restrict__ Wp, const float* __restrict__ bias,
    float* __restrict__ outf) {
    __shared__ __align__(16) short A_l[4096];
    __shared__ __align__(16) short B_l[4096];
    __shared__ float bs[128];
    const int t = threadIdx.x;
    if (t < 128) bs[t] = bias[t];
    const int rowbase = blockIdx.x * 128;
    const int lane = t & 63, w = t >> 6;

    f32x4 acc[2][8];
#pragma unroll
    for (int i = 0; i < 2; ++i)
#pragma unroll
        for (int j = 0; j < 8; ++j) acc[i][j] = (f32x4){0.f, 0.f, 0.f, 0.f};

    constexpr int KC = KC1 + KC2;
    for (int kc = 0; kc < KC; ++kc) {
        const short* src;
        int kst, kloc;
        if (kc < KC1) { src = A1; kst = KC1 * 32; kloc = kc * 32; }
        else          { src = A2; kst = KC2 * 32; kloc = (kc - KC1) * 32; }
#pragma unroll
        for (int p = 0; p < 2; ++p) {
            int s = t + p * 256;
            int b = (s >> 4) & 3;
            int row = rowbase + ((s >> 6) << 4) + (s & 15);
            gload_lds16(src + (size_t)row * kst + kloc + b * 8, A_l + s * 8);
            gload_lds16(Wp + (size_t)kc * 4096 + s * 8, B_l + s * 8);
        }
        __syncthreads();
        const int fo = (lane >> 4) * 16 + (lane & 15);
        short8 a0 = *(const short8*)(A_l + (2 * w * 64 + fo) * 8);
        short8 a1 = *(const short8*)(A_l + ((2 * w + 1) * 64 + fo) * 8);
#pragma unroll
        for (int cb = 0; cb < 8; ++cb) {
            short8 bfr = *(const short8*)(B_l + (cb * 64 + fo) * 8);
            acc[0][cb] = __builtin_amdgcn_mfma_f32_16x16x32_bf16(a0, bfr, acc[0][cb], 0, 0, 0);
            acc[1][cb] = __builtin_amdgcn_mfma_f32_16x16x32_bf16(a1, bfr, acc[1][cb], 0, 0, 0);
        }
        __syncthreads();
    }
#pragma unroll
    for (int rb2 = 0; rb2 < 2; ++rb2) {
        int rloc = 32 * w + rb2 * 16 + ((lane >> 4) << 2);
#pragma unroll
        for (int cb = 0; cb < 8; ++cb) {
            int col = cb * 16 + (lane & 15);
            float bb = bs[col];
#pragma unroll
            for (int i = 0; i < 4; ++i) {
                int row = rowbase + rloc + i;
                if (row < NN) outf[(size_t)row * 128 + col] = acc[rb2][cb][i] + bb;
            }
        }
    }
}

// ---------------------------------------------------------------------------
// per-column sum / sumsq over [N,128]
// ---------------------------------------------------------------------------
__global__ void k_colstats(const float* __restrict__ h, float* __restrict__ stats) {
    const int t = threadIdx.x;
    const int col = t & 127, half = t >> 7;
    float s = 0.f, ss = 0.f;
    for (int row = blockIdx.x * 2 + half; row < NN; row += gridDim.x * 2) {
        float v = h[(size_t)row * 128 + col];
        s += v;
        ss += v * v;
    }
    __shared__ float red[256];
    red[t] = s;
    __syncthreads();
    if (t < 128) atomicAdd(&stats[col], red[t] + red[t + 128]);
    __syncthreads();
    red[t] = ss;
    __syncthreads();
    if (t < 128) atomicAdd(&stats[128 + col], red[t] + red[t + 128]);
}

__global__ void k_bnfin(const float* __restrict__ stats, const float* __restrict__ g,
                        const float* __restrict__ bt, float* __restrict__ ab) {
    int c = threadIdx.x;
    float mu = stats[c] * (1.f / NN);
    float ex2 = stats[128 + c] * (1.f / NN);
    float var = ex2 - mu * mu;  // biased variance (matches reference)
    float a = g[c] * rsqrtf(var + BN_EPS);
    ab[c] = a;
    ab[128 + c] = bt[c] - mu * a;
}

// BN + ReLU + convert to bf16
__global__ void k_bnrelu_bf16(const float* __restrict__ h, const float* __restrict__ ab,
                              short* __restrict__ hb) {
    int gid = blockIdx.x * 256 + threadIdx.x;  // over NN*16 groups of 8
    if (gid >= NN * 16) return;
    int c8 = gid & 15;
    const float4 a0 = reinterpret_cast<const float4*>(ab)[c8 * 2];
    const float4 a1 = reinterpret_cast<const float4*>(ab)[c8 * 2 + 1];
    const float4 b0 = reinterpret_cast<const float4*>(ab)[32 + c8 * 2];
    const float4 b1 = reinterpret_cast<const float4*>(ab)[32 + c8 * 2 + 1];
    float4 v0 = reinterpret_cast<const float4*>(h)[gid * 2];
    float4 v1 = reinterpret_cast<const float4*>(h)[gid * 2 + 1];
    short8 o;
    o[0] = f2bf(fmaxf(fmaf(a0.x, v0.x, b0.x), 0.f));
    o[1] = f2bf(fmaxf(fmaf(a0.y, v0.y, b0.y), 0.f));
    o[2] = f2bf(fmaxf(fmaf(a0.z, v0.z, b0.z), 0.f));
    o[3] = f2bf(fmaxf(fmaf(a0.w, v0.w, b0.w), 0.f));
    o[4] = f2bf(fmaxf(fmaf(a1.x, v1.x, b1.x), 0.f));
    o[5] = f2bf(fmaxf(fmaf(a1.y, v1.y, b1.y), 0.f));
    o[6] = f2bf(fmaxf(fmaf(a1.z, v1.z, b1.z), 0.f));
    o[7] = f2bf(fmaxf(fmaf(a1.w, v1.w, b1.w), 0.f));
    reinterpret_cast<short8*>(hb)[gid] = o;
}

// ---------------------------------------------------------------------------
// MFMA edge MLP: out = relu([hb[u]|hb[v]|bf16(ef)] @ We1 + be1) @ We2 + be2
// 128 edges/block, 4 waves. A (hb path) and B staged via global_load_lds.
// ---------------------------------------------------------------------------
__global__ __launch_bounds__(256) void k_edge_mfma(
    const short* __restrict__ hb, const float* __restrict__ ef,
    const short* __restrict__ Wp, const float* __restrict__ be1,
    const float* __restrict__ We2, const float* __restrict__ be2,
    const int* __restrict__ uu, const int* __restrict__ vv,
    float* __restrict__ out) {
    __shared__ __align__(16) short smem[17408];  // Hid[128][136] | (A 4096 + B 4096)
    __shared__ float We2s[1024];
    __shared__ float be1s[128];
    __shared__ int suv[256];
    short* A_l = smem;
    short* B_l = smem + 4096;
    const int t = threadIdx.x;
    const int eb = blockIdx.x * 128;
    if (t < 128) {
        suv[t] = uu[eb + t];
        suv[128 + t] = vv[eb + t];
        be1s[t] = be1[t];
    }
    We2s[t] = We2[t];
    We2s[t + 256] = We2[t + 256];
    We2s[t + 512] = We2[t + 512];
    We2s[t + 768] = We2[t + 768];
    __syncthreads();

    const int lane = t & 63, w = t >> 6;
    const int srow = t >> 1;      // ef-staging row
    const int sb0 = (t & 1) * 2;  // ef-staging k-subblock base
    const int sslotbase = (srow >> 4) * 64 + (srow & 15);

    f32x4 acc[2][8];
#pragma unroll
    for (int i = 0; i < 2; ++i)
#pragma unroll
        for (int j = 0; j < 8; ++j) acc[i][j] = (f32x4){0.f, 0.f, 0.f, 0.f};

    for (int kc = 0; kc < 10; ++kc) {
        // ---- stage A ----
        if (kc < 8) {
#pragma unroll
            for (int p = 0; p < 2; ++p) {
                int s = t + p * 256;
                int b = (s >> 4) & 3;
                int row = ((s >> 6) << 4) + (s & 15);
                const short* gsrc =
                    hb + (size_t)suv[(kc >= 4) * 128 + row] * 128 + (kc & 3) * 32 + b * 8;
                gload_lds16(gsrc, A_l + s * 8);
            }
        } else {
            const float* er = ef + (size_t)(eb + srow) * 64 + (kc - 8) * 32;
#pragma unroll
            for (int p = 0; p < 2; ++p) {
                int b = sb0 + p;
                float4 f0 = *(const float4*)(er + b * 8);
                float4 f1 = *(const float4*)(er + b * 8 + 4);
                short8 v8;
                v8[0] = f2bf(f0.x); v8[1] = f2bf(f0.y);
                v8[2] = f2bf(f0.z); v8[3] = f2bf(f0.w);
                v8[4] = f2bf(f1.x); v8[5] = f2bf(f1.y);
                v8[6] = f2bf(f1.z); v8[7] = f2bf(f1.w);
                *(short8*)(A_l + (sslotbase + b * 16) * 8) = v8;
            }
        }
        // ---- stage B (pre-packed, linear DMA) ----
#pragma unroll
        for (int p = 0; p < 2; ++p) {
            int s = t + p * 256;
            gload_lds16(Wp + (size_t)kc * 4096 + s * 8, B_l + s * 8);
        }
        __syncthreads();

        const int fo = (lane >> 4) * 16 + (lane & 15);
        short8 afr0 = *(const short8*)(A_l + ((2 * w) * 64 + fo) * 8);
        short8 afr1 = *(const short8*)(A_l + ((2 * w + 1) * 64 + fo) * 8);
#pragma unroll
        for (int cb = 0; cb < 8; ++cb) {
            short8 bfr = *(const short8*)(B_l + (cb * 64 + fo) * 8);
            acc[0][cb] = __builtin_amdgcn_mfma_f32_16x16x32_bf16(afr0, bfr, acc[0][cb], 0, 0, 0);
            acc[1][cb] = __builtin_amdgcn_mfma_f32_16x16x32_bf16(afr1, bfr, acc[1][cb], 0, 0, 0);
        }
        __syncthreads();
    }

    // ---- epilogue: bias + relu -> Hid[128][136] bf16 (reuses A/B region) ----
    short* Hid = smem;
#pragma unroll
    for (int rb2 = 0; rb2 < 2; ++rb2)
#pragma unroll
        for (int cb = 0; cb < 8; ++cb) {
            int col = cb * 16 + (lane & 15);
            int rbase = 32 * w + rb2 * 16 + ((lane >> 4) << 2);
            float bb = be1s[col];
#pragma unroll
            for (int i = 0; i < 4; ++i)
                Hid[(rbase + i) * 136 + col] = f2bf(fmaxf(acc[rb2][cb][i] + bb, 0.f));
        }
    __syncthreads();

    // ---- layer 2: out[e][c] = Hid[e] @ We2 + be2 ----
    {
        int e = t >> 1, c0 = (t & 1) * 4;
        float s0 = be2[c0], s1 = be2[c0 + 1], s2 = be2[c0 + 2], s3 = be2[c0 + 3];
#pragma unroll
        for (int k8 = 0; k8 < 16; ++k8) {
            short8 hv = *(const short8*)(Hid + e * 136 + k8 * 8);
#pragma unroll
            for (int j = 0; j < 8; ++j) {
                float h = bf2f(hv[j]);
                const float* wr = We2s + (k8 * 8 + j) * 8 + c0;
                s0 = fmaf(h, wr[0], s0);
                s1 = fmaf(h, wr[1], s1);
                s2 = fmaf(h, wr[2], s2);
                s3 = fmaf(h, wr[3], s3);
            }
        }
        *(float4*)(out + (size_t)(eb + e) * 8 + c0) = make_float4(s0, s1, s2, s3);
    }
}

// ---------------------------------------------------------------------------
extern "C" void kernel_launch(void* const* d_in, const int* in_sizes, int n_in,
                              void* d_out, int out_size, void* d_ws, size_t ws_size,
                              hipStream_t stream) {
    const float* x   = (const float*)d_in[0];
    const float* ef  = (const float*)d_in[1];
    const float* Ws1 = (const float*)d_in[2];
    const float* Wn1 = (const float*)d_in[3];
    const float* b1  = (const float*)d_in[4];
    const float* g1  = (const float*)d_in[5];
    const float* bt1 = (const float*)d_in[6];
    const float* Ws2 = (const float*)d_in[7];
    const float* Wn2 = (const float*)d_in[8];
    const float* b2  = (const float*)d_in[9];
    const float* g2  = (const float*)d_in[10];
    const float* bt2 = (const float*)d_in[11];
    const float* We1 = (const float*)d_in[12];
    const float* be1 = (const float*)d_in[13];
    const float* We2 = (const float*)d_in[14];
    const float* be2 = (const float*)d_in[15];
    const int* src = (const int*)d_in[16];
    const int* dst = (const int*)d_in[17];
    const int* u   = (const int*)d_in[18];
    const int* v   = (const int*)d_in[19];
    float* out = (float*)d_out;

    // Workspace (~85 MB). h1/h2 fp32 live in d_out (N*128 == out_size).
    // hb aliases xb+agg1b (dead after layer-1 GEMM; contiguous 25.6 MB).
    char* p = (char*)d_ws;
    auto take = [&](size_t bytes) {
        char* r = p;
        p += (bytes + 255) & ~(size_t)255;
        return r;
    };
    float* invd  = (float*)take(NN * 4);
    float* stats = (float*)take(256 * 4);
    float* ab    = (float*)take(256 * 4);
    int* cnt     = (int*)take(NN * 4);
    int* offs    = (int*)take((NN + 1) * 4);
    int* cursor  = (int*)take(NN * 4);
    int* eidsrc  = (int*)take((size_t)EE * 4);
    short* Wp_e  = (short*)take(320 * 128 * 2);
    short* Wp1   = (short*)take(128 * 128 * 2);
    short* Wp2   = (short*)take(256 * 128 * 2);
    short* xb    = (short*)take((size_t)NN * 64 * 2);   // NN*64*2 is 256-aligned
    short* agg1b = (short*)take((size_t)NN * 64 * 2);
    short* h1b   = (short*)take((size_t)NN * 128 * 2);
    short* agg2b = (short*)take((size_t)NN * 128 * 2);
    take(65536);  // pad: node GEMMs read up to ~25 KB past last row
    float* h1 = out;
    float* h2 = out;
    short* hb = xb;  // 25.6 MB union of xb+agg1b

    // ---- CSR build + weight pre-pack + x -> bf16 ----
    hipMemsetAsync(cnt, 0, NN * sizeof(int), stream);
    k_count<<<(EE + 255) / 256, 256, 0, stream>>>(dst, cnt);
    k_scan<<<1, 1024, 0, stream>>>(cnt, offs, cursor, invd);
    k_fill<<<(EE + 255) / 256, 256, 0, stream>>>(src, dst, cursor, eidsrc);
    k_pack_w<<<160, 256, 0, stream>>>(We1, Wp_e, 320, 0);
    k_pack_w<<<32, 256, 0, stream>>>(Ws1, Wp1, 64, 0);
    k_pack_w<<<32, 256, 0, stream>>>(Wn1, Wp1, 64, 64);
    k_pack_w<<<64, 256, 0, stream>>>(Ws2, Wp2, 128, 0);
    k_pack_w<<<64, 256, 0, stream>>>(Wn2, Wp2, 128, 128);
    k_f2bf<<<(NN * 8 + 255) / 256, 256, 0, stream>>>(x, xb, NN * 8);

    // ---- layer 1 (all bf16 inputs, fp32 accum) ----
    k_gather_bf<64><<<(NN * 32 + 255) / 256, 256, 0, stream>>>(xb, offs, eidsrc, invd, agg1b);
    k_node_mfma<2, 2><<<(NN + 127) / 128, 256, 0, stream>>>(xb, agg1b, Wp1, b1, h1);
    hipMemsetAsync(stats, 0, 256 * sizeof(float), stream);
    k_colstats<<<256, 256, 0, stream>>>(h1, stats);
    k_bnfin<<<1, 128, 0, stream>>>(stats, g1, bt1, ab);
    k_bnrelu_bf16<<<(NN * 16 + 255) / 256, 256, 0, stream>>>(h1, ab, h1b);

    // ---- layer 2 ----
    k_gather_bf<128><<<(NN * 64 + 255) / 256, 256, 0, stream>>>(h1b, offs, eidsrc, invd, agg2b);
    k_node_mfma<4, 4><<<(NN + 127) / 128, 256, 0, stream>>>(h1b, agg2b, Wp2, b2, h2);
    hipMemsetAsync(stats, 0, 256 * sizeof(float), stream);
    k_colstats<<<256, 256, 0, stream>>>(h2, stats);
    k_bnfin<<<1, 128, 0, stream>>>(stats, g2, bt2, ab);
    k_bnrelu_bf16<<<(NN * 16 + 255) / 256, 256, 0, stream>>>(h2, ab, hb);

    // ---- edge head (bf16 MFMA) ----
    k_edge_mfma<<<EE / 128, 256, 0, stream>>>(hb, ef, Wp_e, be1, We2, be2, u, v, out);
}

// Round 5
// 836.568 us; speedup vs baseline: 8.3127x; 1.2077x over previous
//
#include <hip/hip_runtime.h>

// Problem constants (fixed by the reference).
#define NN 100000
#define EE 1600000
// D_IN=64, H=128, E_IN=64, C=8
constexpr float BN_EPS = 1e-5f;

typedef __attribute__((ext_vector_type(8))) short short8;
typedef __attribute__((ext_vector_type(4))) float f32x4;

__device__ __forceinline__ short f2bf(float f) {  // RNE f32 -> bf16
    unsigned u = __float_as_uint(f);
    u += 0x7fff + ((u >> 16) & 1);
    return (short)(u >> 16);
}
__device__ __forceinline__ float bf2f(short s) {
    return __uint_as_float(((unsigned)(unsigned short)s) << 16);
}

// async global->LDS DMA, 16 B per lane. LDS dest must be base + lane*16
// within each wave (guaranteed by construction at all call sites).
typedef __attribute__((address_space(1))) const unsigned int guint;
typedef __attribute__((address_space(3))) unsigned int luint;
__device__ __forceinline__ void gload_lds16(const void* g, void* l) {
    __builtin_amdgcn_global_load_lds((guint*)g, (luint*)l, 16, 0, 0);
}

// ---------------------------------------------------------------------------
// CSR build: count -> scan -> fill
// ---------------------------------------------------------------------------
__global__ void k_count(const int* __restrict__ dst, int* __restrict__ cnt) {
    int e = blockIdx.x * 256 + threadIdx.x;
    if (e < EE) atomicAdd(&cnt[dst[e]], 1);
}

__global__ __launch_bounds__(1024) void k_scan(const int* __restrict__ cnt,
                                               int* __restrict__ offs,
                                               int* __restrict__ cursor,
                                               float* __restrict__ invd) {
    const int t = threadIdx.x, lane = t & 63, w = t >> 6;  // 16 waves
    __shared__ int wsum[16], wexcl[16];
    __shared__ int carry_sh;
    if (t == 0) carry_sh = 0;
    __syncthreads();
    int ss = 0;
    for (int base = 0; base < NN; base += 1024) {
        int i = base + t;
        int v = (i < NN) ? cnt[i] : 0;
        int s = v;
#pragma unroll
        for (int d = 1; d < 64; d <<= 1) {
            int o = __shfl_up(s, d, 64);
            if (lane >= d) s += o;
        }
        if (lane == 63) wsum[w] = s;
        __syncthreads();
        if (t < 16) {
            int wv = wsum[t];
            ss = wv;
#pragma unroll
            for (int d = 1; d < 16; d <<= 1) {
                int o = __shfl_up(ss, d, 16);
                if (t >= d) ss += o;
            }
            wexcl[t] = ss - wv;
        }
        __syncthreads();
        int excl = (s - v) + wexcl[w];
        int c = carry_sh;
        if (i < NN) {
            int o = c + excl;
            offs[i] = o;
            cursor[i] = o;
            invd[i] = v > 0 ? 1.f / (float)v : 0.f;  // DGL mean: zero-degree -> 0
        }
        __syncthreads();
        if (t == 15) carry_sh = c + ss;
        __syncthreads();
    }
    if (t == 0) offs[NN] = carry_sh;
}

__global__ void k_fill(const int* __restrict__ src, const int* __restrict__ dst,
                       int* __restrict__ cursor, int* __restrict__ eidsrc) {
    int e = blockIdx.x * 256 + threadIdx.x;
    if (e < EE) {
        int pos = atomicAdd(&cursor[dst[e]], 1);
        eidsrc[pos] = src[e];
    }
}

// ---------------------------------------------------------------------------
// fp32 -> bf16 bulk convert (8 elems/thread)
// ---------------------------------------------------------------------------
__global__ void k_f2bf(const float* __restrict__ in, short* __restrict__ out, int n8) {
    int i = blockIdx.x * 256 + threadIdx.x;
    if (i >= n8) return;
    float4 a = ((const float4*)in)[i * 2];
    float4 b = ((const float4*)in)[i * 2 + 1];
    short8 o;
    o[0] = f2bf(a.x); o[1] = f2bf(a.y); o[2] = f2bf(a.z); o[3] = f2bf(a.w);
    o[4] = f2bf(b.x); o[5] = f2bf(b.y); o[6] = f2bf(b.z); o[7] = f2bf(b.w);
    ((short8*)out)[i] = o;
}

// ---------------------------------------------------------------------------
// bf16 CSR mean-aggregation: L lanes per node, 2 cols/lane, fp32 accum.
// 4-wide unrolled: 4 indices + 4 independent row loads in flight.
// ---------------------------------------------------------------------------
template <int F>
__global__ __launch_bounds__(256) void k_gather_bf(
    const short* __restrict__ hbsrc, const int* __restrict__ offs,
    const int* __restrict__ eidsrc, const float* __restrict__ invd,
    short* __restrict__ aggb) {
    constexpr int L = (F == 128) ? 64 : 32;
    int node = (blockIdx.x * 256 + threadIdx.x) / L;
    int lane = threadIdx.x % L;
    if (node >= NN) return;
    int beg = offs[node], end = offs[node + 1];
    float iv = invd[node];
    float s0 = 0.f, s1 = 0.f;
    const int o2 = lane * 2;
    int p = beg;
    for (; p + 4 <= end; p += 4) {
        int i0 = eidsrc[p], i1 = eidsrc[p + 1], i2 = eidsrc[p + 2], i3 = eidsrc[p + 3];
        unsigned v0 = *(const unsigned*)(hbsrc + (size_t)i0 * F + o2);
        unsigned v1 = *(const unsigned*)(hbsrc + (size_t)i1 * F + o2);
        unsigned v2 = *(const unsigned*)(hbsrc + (size_t)i2 * F + o2);
        unsigned v3 = *(const unsigned*)(hbsrc + (size_t)i3 * F + o2);
        s0 += bf2f((short)(v0 & 0xffff)) + bf2f((short)(v1 & 0xffff)) +
              bf2f((short)(v2 & 0xffff)) + bf2f((short)(v3 & 0xffff));
        s1 += bf2f((short)(v0 >> 16)) + bf2f((short)(v1 >> 16)) +
              bf2f((short)(v2 >> 16)) + bf2f((short)(v3 >> 16));
    }
    for (; p < end; ++p) {
        unsigned pv = *(const unsigned*)(hbsrc + (size_t)eidsrc[p] * F + o2);
        s0 += bf2f((short)(pv & 0xffff));
        s1 += bf2f((short)(pv >> 16));
    }
    s0 *= iv;
    s1 *= iv;
    unsigned o = (unsigned)(unsigned short)f2bf(s0) |
                 ((unsigned)(unsigned short)f2bf(s1) << 16);
    *(unsigned*)(aggb + (size_t)node * F + o2) = o;
}

// ---------------------------------------------------------------------------
// Unified weight pre-pack into bf16 MFMA-B fragment order.
// slot = cb*64 + bp*16 + n, elem j; content = W[k][16*cb+n], gk = k + kbase,
// kc = gk>>5, bp = (gk&31)>>3, j = gk&7.
// Segments: We1->Wp_e | Ws1,Wn1->Wp1 | Ws2,Wn2->Wp2 | We2(pad to 16 cols)->Wp2e
// ---------------------------------------------------------------------------
__device__ __forceinline__ void packW(const float* W, short* Wp, int local, int kbase) {
    int k = local >> 7, col = local & 127;
    int gk = k + kbase;
    int kc = gk >> 5, kw = gk & 31, bp = kw >> 3, j = kw & 7;
    int cb = col >> 4, n = col & 15;
    Wp[kc * 4096 + (cb * 64 + bp * 16 + n) * 8 + j] = f2bf(W[k * 128 + col]);
}

__global__ void k_pack_all(const float* __restrict__ We1, const float* __restrict__ Ws1,
                           const float* __restrict__ Wn1, const float* __restrict__ Ws2,
                           const float* __restrict__ Wn2, const float* __restrict__ We2,
                           short* __restrict__ Wp_e, short* __restrict__ Wp1,
                           short* __restrict__ Wp2, short* __restrict__ Wp2e) {
    int idx = blockIdx.x * 256 + threadIdx.x;
    if (idx < 40960) {
        packW(We1, Wp_e, idx, 0);
    } else if (idx < 49152) {
        packW(Ws1, Wp1, idx - 40960, 0);
    } else if (idx < 57344) {
        packW(Wn1, Wp1, idx - 49152, 64);
    } else if (idx < 73728) {
        packW(Ws2, Wp2, idx - 57344, 0);
    } else if (idx < 90112) {
        packW(Wn2, Wp2, idx - 73728, 128);
    } else if (idx < 92160) {
        int local = idx - 90112;  // over 128 k x 16 n
        int k = local >> 4, n = local & 15;
        float val = (n < 8) ? We2[k * 8 + n] : 0.f;
        int kc2 = k >> 5, kl = k & 31, bp = kl >> 3, j = kl & 7;
        Wp2e[(kc2 * 64 + bp * 16 + n) * 8 + j] = f2bf(val);
    }
}

// ---------------------------------------------------------------------------
// bf16 MFMA node GEMM: outf[N,128] = [A1b | A2b] @ Wp + bias (fp32 out)
// ---------------------------------------------------------------------------
template <int KC1, int KC2>
__global__ __launch_bounds__(256) void k_node_mfma(
    const short* __restrict__ A1, const short* __restrict__ A2,
    const short* __restrict__ Wp, const float* __restrict__ bias,
    float* __restrict__ outf) {
    __shared__ __align__(16) short A_l[4096];
    __shared__ __align__(16) short B_l[4096];
    __shared__ float bs[128];
    const int t = threadIdx.x;
    if (t < 128) bs[t] = bias[t];
    const int rowbase = blockIdx.x * 128;
    const int lane = t & 63, w = t >> 6;

    f32x4 acc[2][8];
#pragma unroll
    for (int i = 0; i < 2; ++i)
#pragma unroll
        for (int j = 0; j < 8; ++j) acc[i][j] = (f32x4){0.f, 0.f, 0.f, 0.f};

    constexpr int KC = KC1 + KC2;
    for (int kc = 0; kc < KC; ++kc) {
        const short* src;
        int kst, kloc;
        if (kc < KC1) { src = A1; kst = KC1 * 32; kloc = kc * 32; }
        else          { src = A2; kst = KC2 * 32; kloc = (kc - KC1) * 32; }
#pragma unroll
        for (int p = 0; p < 2; ++p) {
            int s = t + p * 256;
            int b = (s >> 4) & 3;
            int row = rowbase + ((s >> 6) << 4) + (s & 15);
            gload_lds16(src + (size_t)row * kst + kloc + b * 8, A_l + s * 8);
            gload_lds16(Wp + (size_t)kc * 4096 + s * 8, B_l + s * 8);
        }
        __syncthreads();
        const int fo = (lane >> 4) * 16 + (lane & 15);
        short8 a0 = *(const short8*)(A_l + (2 * w * 64 + fo) * 8);
        short8 a1 = *(const short8*)(A_l + ((2 * w + 1) * 64 + fo) * 8);
#pragma unroll
        for (int cb = 0; cb < 8; ++cb) {
            short8 bfr = *(const short8*)(B_l + (cb * 64 + fo) * 8);
            acc[0][cb] = __builtin_amdgcn_mfma_f32_16x16x32_bf16(a0, bfr, acc[0][cb], 0, 0, 0);
            acc[1][cb] = __builtin_amdgcn_mfma_f32_16x16x32_bf16(a1, bfr, acc[1][cb], 0, 0, 0);
        }
        __syncthreads();
    }
#pragma unroll
    for (int rb2 = 0; rb2 < 2; ++rb2) {
        int rloc = 32 * w + rb2 * 16 + ((lane >> 4) << 2);
#pragma unroll
        for (int cb = 0; cb < 8; ++cb) {
            int col = cb * 16 + (lane & 15);
            float bb = bs[col];
#pragma unroll
            for (int i = 0; i < 4; ++i) {
                int row = rowbase + rloc + i;
                if (row < NN) outf[(size_t)row * 128 + col] = acc[rb2][cb][i] + bb;
            }
        }
    }
}

// ---------------------------------------------------------------------------
// per-column sum / sumsq over [N,128]
// ---------------------------------------------------------------------------
__global__ void k_colstats(const float* __restrict__ h, float* __restrict__ stats) {
    const int t = threadIdx.x;
    const int col = t & 127, half = t >> 7;
    float s = 0.f, ss = 0.f;
    for (int row = blockIdx.x * 2 + half; row < NN; row += gridDim.x * 2) {
        float v = h[(size_t)row * 128 + col];
        s += v;
        ss += v * v;
    }
    __shared__ float red[256];
    red[t] = s;
    __syncthreads();
    if (t < 128) atomicAdd(&stats[col], red[t] + red[t + 128]);
    __syncthreads();
    red[t] = ss;
    __syncthreads();
    if (t < 128) atomicAdd(&stats[128 + col], red[t] + red[t + 128]);
}

// BN (inline stats->scale/shift) + ReLU + convert to bf16
__global__ void k_bnrelu_bf16(const float* __restrict__ h, const float* __restrict__ stats,
                              const float* __restrict__ g, const float* __restrict__ bt,
                              short* __restrict__ hb) {
    int gid = blockIdx.x * 256 + threadIdx.x;  // over NN*16 groups of 8
    if (gid >= NN * 16) return;
    int c8 = gid & 15;
    float av[8], bv[8];
#pragma unroll
    for (int j = 0; j < 8; ++j) {
        int c = c8 * 8 + j;
        float mu = stats[c] * (1.f / NN);
        float var = stats[128 + c] * (1.f / NN) - mu * mu;  // biased (matches ref)
        float a = g[c] * rsqrtf(var + BN_EPS);
        av[j] = a;
        bv[j] = bt[c] - mu * a;
    }
    float4 v0 = reinterpret_cast<const float4*>(h)[gid * 2];
    float4 v1 = reinterpret_cast<const float4*>(h)[gid * 2 + 1];
    short8 o;
    o[0] = f2bf(fmaxf(fmaf(av[0], v0.x, bv[0]), 0.f));
    o[1] = f2bf(fmaxf(fmaf(av[1], v0.y, bv[1]), 0.f));
    o[2] = f2bf(fmaxf(fmaf(av[2], v0.z, bv[2]), 0.f));
    o[3] = f2bf(fmaxf(fmaf(av[3], v0.w, bv[3]), 0.f));
    o[4] = f2bf(fmaxf(fmaf(av[4], v1.x, bv[4]), 0.f));
    o[5] = f2bf(fmaxf(fmaf(av[5], v1.y, bv[5]), 0.f));
    o[6] = f2bf(fmaxf(fmaf(av[6], v1.z, bv[6]), 0.f));
    o[7] = f2bf(fmaxf(fmaf(av[7], v1.w, bv[7]), 0.f));
    reinterpret_cast<short8*>(hb)[gid] = o;
}

// ---------------------------------------------------------------------------
// MFMA edge MLP: out = relu([hb[u]|hb[v]|bf16(ef)] @ We1 + be1) @ We2 + be2
// 128 edges/block, 4 waves. Layer 2 is ALSO MFMA (We2 zero-padded to 16 cols,
// B-frags preloaded to registers; Hid LDS round-trip for the A transpose).
// ---------------------------------------------------------------------------
__global__ __launch_bounds__(256) void k_edge_mfma(
    const short* __restrict__ hb, const float* __restrict__ ef,
    const short* __restrict__ Wp, const short* __restrict__ Wp2e,
    const float* __restrict__ be1, const float* __restrict__ be2,
    const int* __restrict__ uu, const int* __restrict__ vv,
    float* __restrict__ out) {
    __shared__ __align__(16) short smem[17408];  // Hid[128][136] | (A 4096 + B 4096)
    __shared__ float be1s[128];
    __shared__ int suv[256];
    short* A_l = smem;
    short* B_l = smem + 4096;
    const int t = threadIdx.x;
    const int eb = blockIdx.x * 128;
    if (t < 128) {
        suv[t] = uu[eb + t];
        suv[128 + t] = vv[eb + t];
        be1s[t] = be1[t];
    }
    __syncthreads();

    const int lane = t & 63, w = t >> 6;
    const int fo = (lane >> 4) * 16 + (lane & 15);
    const int srow = t >> 1;      // ef-staging row
    const int sb0 = (t & 1) * 2;  // ef-staging k-subblock base
    const int sslotbase = (srow >> 4) * 64 + (srow & 15);

    // preload layer-2 B-frags (4 KB, L2-resident)
    short8 b2f[4];
#pragma unroll
    for (int kc2 = 0; kc2 < 4; ++kc2)
        b2f[kc2] = *(const short8*)(Wp2e + (kc2 * 64 + fo) * 8);

    f32x4 acc[2][8];
#pragma unroll
    for (int i = 0; i < 2; ++i)
#pragma unroll
        for (int j = 0; j < 8; ++j) acc[i][j] = (f32x4){0.f, 0.f, 0.f, 0.f};

    for (int kc = 0; kc < 10; ++kc) {
        // ---- stage A ----
        if (kc < 8) {
#pragma unroll
            for (int p = 0; p < 2; ++p) {
                int s = t + p * 256;
                int b = (s >> 4) & 3;
                int row = ((s >> 6) << 4) + (s & 15);
                const short* gsrc =
                    hb + (size_t)suv[(kc >= 4) * 128 + row] * 128 + (kc & 3) * 32 + b * 8;
                gload_lds16(gsrc, A_l + s * 8);
            }
        } else {
            const float* er = ef + (size_t)(eb + srow) * 64 + (kc - 8) * 32;
#pragma unroll
            for (int p = 0; p < 2; ++p) {
                int b = sb0 + p;
                float4 f0 = *(const float4*)(er + b * 8);
                float4 f1 = *(const float4*)(er + b * 8 + 4);
                short8 v8;
                v8[0] = f2bf(f0.x); v8[1] = f2bf(f0.y);
                v8[2] = f2bf(f0.z); v8[3] = f2bf(f0.w);
                v8[4] = f2bf(f1.x); v8[5] = f2bf(f1.y);
                v8[6] = f2bf(f1.z); v8[7] = f2bf(f1.w);
                *(short8*)(A_l + (sslotbase + b * 16) * 8) = v8;
            }
        }
        // ---- stage B (pre-packed, linear DMA) ----
#pragma unroll
        for (int p = 0; p < 2; ++p) {
            int s = t + p * 256;
            gload_lds16(Wp + (size_t)kc * 4096 + s * 8, B_l + s * 8);
        }
        __syncthreads();

        short8 afr0 = *(const short8*)(A_l + ((2 * w) * 64 + fo) * 8);
        short8 afr1 = *(const short8*)(A_l + ((2 * w + 1) * 64 + fo) * 8);
#pragma unroll
        for (int cb = 0; cb < 8; ++cb) {
            short8 bfr = *(const short8*)(B_l + (cb * 64 + fo) * 8);
            acc[0][cb] = __builtin_amdgcn_mfma_f32_16x16x32_bf16(afr0, bfr, acc[0][cb], 0, 0, 0);
            acc[1][cb] = __builtin_amdgcn_mfma_f32_16x16x32_bf16(afr1, bfr, acc[1][cb], 0, 0, 0);
        }
        __syncthreads();
    }

    // ---- epilogue 1: bias + relu -> Hid[128][136] bf16 (reuses A/B region) ----
    short* Hid = smem;
#pragma unroll
    for (int rb2 = 0; rb2 < 2; ++rb2)
#pragma unroll
        for (int cb = 0; cb < 8; ++cb) {
            int col = cb * 16 + (lane & 15);
            int rbase = 32 * w + rb2 * 16 + ((lane >> 4) << 2);
            float bb = be1s[col];
#pragma unroll
            for (int i = 0; i < 4; ++i)
                Hid[(rbase + i) * 136 + col] = f2bf(fmaxf(acc[rb2][cb][i] + bb, 0.f));
        }
    __syncthreads();

    // ---- layer 2 via MFMA: out[e][0..7] = Hid @ We2p + be2 ----
#pragma unroll
    for (int rf = 0; rf < 2; ++rf) {
        f32x4 a2 = (f32x4){0.f, 0.f, 0.f, 0.f};
        const int rbl = 32 * w + 16 * rf + (lane & 15);
#pragma unroll
        for (int kc2 = 0; kc2 < 4; ++kc2) {
            short8 af = *(const short8*)(Hid + rbl * 136 + kc2 * 32 + 8 * (lane >> 4));
            a2 = __builtin_amdgcn_mfma_f32_16x16x32_bf16(af, b2f[kc2], a2, 0, 0, 0);
        }
        int col = lane & 15;
        if (col < 8) {
            int r0 = eb + 32 * w + 16 * rf + 4 * (lane >> 4);
            float bb = be2[col];
#pragma unroll
            for (int i = 0; i < 4; ++i)
                out[(size_t)(r0 + i) * 8 + col] = a2[i] + bb;
        }
    }
}

// ---------------------------------------------------------------------------
extern "C" void kernel_launch(void* const* d_in, const int* in_sizes, int n_in,
                              void* d_out, int out_size, void* d_ws, size_t ws_size,
                              hipStream_t stream) {
    const float* x   = (const float*)d_in[0];
    const float* ef  = (const float*)d_in[1];
    const float* Ws1 = (const float*)d_in[2];
    const float* Wn1 = (const float*)d_in[3];
    const float* b1  = (const float*)d_in[4];
    const float* g1  = (const float*)d_in[5];
    const float* bt1 = (const float*)d_in[6];
    const float* Ws2 = (const float*)d_in[7];
    const float* Wn2 = (const float*)d_in[8];
    const float* b2  = (const float*)d_in[9];
    const float* g2  = (const float*)d_in[10];
    const float* bt2 = (const float*)d_in[11];
    const float* We1 = (const float*)d_in[12];
    const float* be1 = (const float*)d_in[13];
    const float* We2 = (const float*)d_in[14];
    const float* be2 = (const float*)d_in[15];
    const int* src = (const int*)d_in[16];
    const int* dst = (const int*)d_in[17];
    const int* u   = (const int*)d_in[18];
    const int* v   = (const int*)d_in[19];
    float* out = (float*)d_out;

    // Workspace (~85 MB). h1/h2 fp32 live in d_out (N*128 == out_size).
    // hb aliases xb+agg1b (dead after layer-1 GEMM; contiguous 25.6 MB).
    char* p = (char*)d_ws;
    auto take = [&](size_t bytes) {
        char* r = p;
        p += (bytes + 255) & ~(size_t)255;
        return r;
    };
    int* cnt     = (int*)take(NN * 4);       // adjacent to stats: one memset
    float* stats = (float*)take(512 * 4);    // [0:256)=layer1, [256:512)=layer2
    float* invd  = (float*)take(NN * 4);
    int* offs    = (int*)take((NN + 1) * 4);
    int* cursor  = (int*)take(NN * 4);
    int* eidsrc  = (int*)take((size_t)EE * 4);
    short* Wp_e  = (short*)take(320 * 128 * 2);
    short* Wp1   = (short*)take(128 * 128 * 2);
    short* Wp2   = (short*)take(256 * 128 * 2);
    short* Wp2e  = (short*)take(256 * 8 * 2);
    short* xb    = (short*)take((size_t)NN * 64 * 2);
    short* agg1b = (short*)take((size_t)NN * 64 * 2);
    short* h1b   = (short*)take((size_t)NN * 128 * 2);
    short* agg2b = (short*)take((size_t)NN * 128 * 2);
    take(65536);  // pad: node GEMMs read up to ~25 KB past last row
    float* h1 = out;
    float* h2 = out;
    short* hb = xb;  // 25.6 MB union of xb+agg1b

    // ---- CSR build + weight pre-pack + x -> bf16 ----
    hipMemsetAsync(cnt, 0, ((char*)stats - (char*)cnt) + 512 * 4, stream);
    k_count<<<(EE + 255) / 256, 256, 0, stream>>>(dst, cnt);
    k_scan<<<1, 1024, 0, stream>>>(cnt, offs, cursor, invd);
    k_fill<<<(EE + 255) / 256, 256, 0, stream>>>(src, dst, cursor, eidsrc);
    k_pack_all<<<360, 256, 0, stream>>>(We1, Ws1, Wn1, Ws2, Wn2, We2, Wp_e, Wp1, Wp2, Wp2e);
    k_f2bf<<<(NN * 8 + 255) / 256, 256, 0, stream>>>(x, xb, NN * 8);

    // ---- layer 1 (bf16 inputs, fp32 accum/stats) ----
    k_gather_bf<64><<<(NN * 32 + 255) / 256, 256, 0, stream>>>(xb, offs, eidsrc, invd, agg1b);
    k_node_mfma<2, 2><<<(NN + 127) / 128, 256, 0, stream>>>(xb, agg1b, Wp1, b1, h1);
    k_colstats<<<256, 256, 0, stream>>>(h1, stats);
    k_bnrelu_bf16<<<(NN * 16 + 255) / 256, 256, 0, stream>>>(h1, stats, g1, bt1, h1b);

    // ---- layer 2 ----
    k_gather_bf<128><<<(NN * 64 + 255) / 256, 256, 0, stream>>>(h1b, offs, eidsrc, invd, agg2b);
    k_node_mfma<4, 4><<<(NN + 127) / 128, 256, 0, stream>>>(h1b, agg2b, Wp2, b2, h2);
    k_colstats<<<256, 256, 0, stream>>>(h2, stats + 256);
    k_bnrelu_bf16<<<(NN * 16 + 255) / 256, 256, 0, stream>>>(h2, stats + 256, g2, bt2, hb);

    // ---- edge head (bf16 MFMA, both layers) ----
    k_edge_mfma<<<EE / 128, 256, 0, stream>>>(hb, ef, Wp_e, Wp2e, be1, be2, u, v, out);
}

// Round 6
// 773.005 us; speedup vs baseline: 8.9963x; 1.0822x over previous
//
#include <hip/hip_runtime.h>

// Problem constants (fixed by the reference).
#define NN 100000
#define EE 1600000
// D_IN=64, H=128, E_IN=64, C=8
constexpr float BN_EPS = 1e-5f;

typedef __attribute__((ext_vector_type(8))) short short8;
typedef __attribute__((ext_vector_type(4))) float f32x4;

__device__ __forceinline__ short f2bf(float f) {  // RNE f32 -> bf16
    unsigned u = __float_as_uint(f);
    u += 0x7fff + ((u >> 16) & 1);
    return (short)(u >> 16);
}
__device__ __forceinline__ float bf2f(short s) {
    return __uint_as_float(((unsigned)(unsigned short)s) << 16);
}

// async global->LDS DMA, 16 B per lane. LDS dest must be base + lane*16
// within each wave (guaranteed by construction at all call sites).
typedef __attribute__((address_space(1))) const unsigned int guint;
typedef __attribute__((address_space(3))) unsigned int luint;
__device__ __forceinline__ void gload_lds16(const void* g, void* l) {
    __builtin_amdgcn_global_load_lds((guint*)g, (luint*)l, 16, 0, 0);
}

// ---------------------------------------------------------------------------
// CSR build: count -> scan -> fill
// ---------------------------------------------------------------------------
__global__ void k_count(const int* __restrict__ dst, int* __restrict__ cnt) {
    int e = blockIdx.x * 256 + threadIdx.x;
    if (e < EE) atomicAdd(&cnt[dst[e]], 1);
}

__global__ __launch_bounds__(1024) void k_scan(const int* __restrict__ cnt,
                                               int* __restrict__ offs,
                                               int* __restrict__ cursor,
                                               float* __restrict__ invd) {
    const int t = threadIdx.x, lane = t & 63, w = t >> 6;  // 16 waves
    __shared__ int wsum[16], wexcl[16];
    __shared__ int carry_sh;
    if (t == 0) carry_sh = 0;
    __syncthreads();
    int ss = 0;
    for (int base = 0; base < NN; base += 1024) {
        int i = base + t;
        int v = (i < NN) ? cnt[i] : 0;
        int s = v;
#pragma unroll
        for (int d = 1; d < 64; d <<= 1) {
            int o = __shfl_up(s, d, 64);
            if (lane >= d) s += o;
        }
        if (lane == 63) wsum[w] = s;
        __syncthreads();
        if (t < 16) {
            int wv = wsum[t];
            ss = wv;
#pragma unroll
            for (int d = 1; d < 16; d <<= 1) {
                int o = __shfl_up(ss, d, 16);
                if (t >= d) ss += o;
            }
            wexcl[t] = ss - wv;
        }
        __syncthreads();
        int excl = (s - v) + wexcl[w];
        int c = carry_sh;
        if (i < NN) {
            int o = c + excl;
            offs[i] = o;
            cursor[i] = o;
            invd[i] = v > 0 ? 1.f / (float)v : 0.f;  // DGL mean: zero-degree -> 0
        }
        __syncthreads();
        if (t == 15) carry_sh = c + ss;
        __syncthreads();
    }
    if (t == 0) offs[NN] = carry_sh;
}

__global__ void k_fill(const int* __restrict__ src, const int* __restrict__ dst,
                       int* __restrict__ cursor, int* __restrict__ eidsrc) {
    int e = blockIdx.x * 256 + threadIdx.x;
    if (e < EE) {
        int pos = atomicAdd(&cursor[dst[e]], 1);
        eidsrc[pos] = src[e];
    }
}

// ---------------------------------------------------------------------------
// fp32 -> bf16 bulk convert (8 elems/thread)
// ---------------------------------------------------------------------------
__global__ void k_f2bf(const float* __restrict__ in, short* __restrict__ out, int n8) {
    int i = blockIdx.x * 256 + threadIdx.x;
    if (i >= n8) return;
    float4 a = ((const float4*)in)[i * 2];
    float4 b = ((const float4*)in)[i * 2 + 1];
    short8 o;
    o[0] = f2bf(a.x); o[1] = f2bf(a.y); o[2] = f2bf(a.z); o[3] = f2bf(a.w);
    o[4] = f2bf(b.x); o[5] = f2bf(b.y); o[6] = f2bf(b.z); o[7] = f2bf(b.w);
    ((short8*)out)[i] = o;
}

// ---------------------------------------------------------------------------
// bf16 CSR mean-aggregation: F/8 lanes per node, 16 B (8 cols) per lane,
// fp32 accum, 4-deep unrolled -> 4 KB/wave outstanding.
// ---------------------------------------------------------------------------
template <int F>
__global__ __launch_bounds__(256) void k_gather_bf(
    const short* __restrict__ hbsrc, const int* __restrict__ offs,
    const int* __restrict__ eidsrc, const float* __restrict__ invd,
    short* __restrict__ aggb) {
    constexpr int G = F / 8;  // lanes per node
    int gid = blockIdx.x * 256 + threadIdx.x;
    int node = gid / G;
    int sub = gid % G;
    if (node >= NN) return;
    int beg = offs[node], end = offs[node + 1];
    float iv = invd[node];
    float s[8] = {0.f, 0.f, 0.f, 0.f, 0.f, 0.f, 0.f, 0.f};
    const size_t co = (size_t)sub * 8;
    int p = beg;
    for (; p + 4 <= end; p += 4) {
        int i0 = eidsrc[p], i1 = eidsrc[p + 1], i2 = eidsrc[p + 2], i3 = eidsrc[p + 3];
        short8 r0 = *(const short8*)(hbsrc + (size_t)i0 * F + co);
        short8 r1 = *(const short8*)(hbsrc + (size_t)i1 * F + co);
        short8 r2 = *(const short8*)(hbsrc + (size_t)i2 * F + co);
        short8 r3 = *(const short8*)(hbsrc + (size_t)i3 * F + co);
#pragma unroll
        for (int j = 0; j < 8; ++j)
            s[j] += (bf2f(r0[j]) + bf2f(r1[j])) + (bf2f(r2[j]) + bf2f(r3[j]));
    }
    for (; p < end; ++p) {
        short8 r = *(const short8*)(hbsrc + (size_t)eidsrc[p] * F + co);
#pragma unroll
        for (int j = 0; j < 8; ++j) s[j] += bf2f(r[j]);
    }
    short8 o;
#pragma unroll
    for (int j = 0; j < 8; ++j) o[j] = f2bf(s[j] * iv);
    *(short8*)(aggb + (size_t)node * F + co) = o;
}

// ---------------------------------------------------------------------------
// Unified weight pre-pack into bf16 MFMA-B fragment order.
// slot = cb*64 + bp*16 + n, elem j; content = W[k][16*cb+n], gk = k + kbase,
// kc = gk>>5, bp = (gk&31)>>3, j = gk&7.
// ---------------------------------------------------------------------------
__device__ __forceinline__ void packW(const float* W, short* Wp, int local, int kbase) {
    int k = local >> 7, col = local & 127;
    int gk = k + kbase;
    int kc = gk >> 5, kw = gk & 31, bp = kw >> 3, j = kw & 7;
    int cb = col >> 4, n = col & 15;
    Wp[kc * 4096 + (cb * 64 + bp * 16 + n) * 8 + j] = f2bf(W[k * 128 + col]);
}

__global__ void k_pack_all(const float* __restrict__ We1, const float* __restrict__ Ws1,
                           const float* __restrict__ Wn1, const float* __restrict__ Ws2,
                           const float* __restrict__ Wn2, const float* __restrict__ We2,
                           short* __restrict__ Wp_e, short* __restrict__ Wp1,
                           short* __restrict__ Wp2, short* __restrict__ Wp2e) {
    int idx = blockIdx.x * 256 + threadIdx.x;
    if (idx < 40960) {
        packW(We1, Wp_e, idx, 0);
    } else if (idx < 49152) {
        packW(Ws1, Wp1, idx - 40960, 0);
    } else if (idx < 57344) {
        packW(Wn1, Wp1, idx - 49152, 64);
    } else if (idx < 73728) {
        packW(Ws2, Wp2, idx - 57344, 0);
    } else if (idx < 90112) {
        packW(Wn2, Wp2, idx - 73728, 128);
    } else if (idx < 92160) {
        int local = idx - 90112;  // over 128 k x 16 n
        int k = local >> 4, n = local & 15;
        float val = (n < 8) ? We2[k * 8 + n] : 0.f;
        int kc2 = k >> 5, kl = k & 31, bp = kl >> 3, j = kl & 7;
        Wp2e[(kc2 * 64 + bp * 16 + n) * 8 + j] = f2bf(val);
    }
}

// ---------------------------------------------------------------------------
// bf16 MFMA node GEMM, 2-phase double-buffered staging, fused col-stats.
// outf[N,128] = [A1b | A2b] @ Wp + bias; stats[0:128)=colsum, [128:256)=colsumsq
// ---------------------------------------------------------------------------
template <int KC1, int KC2>
__global__ __launch_bounds__(256) void k_node_mfma(
    const short* __restrict__ A1, const short* __restrict__ A2,
    const short* __restrict__ Wp, const float* __restrict__ bias,
    float* __restrict__ outf, float* __restrict__ stats) {
    __shared__ __align__(16) short sbuf[16384];  // A0|B0|A1|B1, 4096 each
    __shared__ float bs[128];
    __shared__ float reds[4][128], redss[4][128];
    const int t = threadIdx.x;
    if (t < 128) bs[t] = bias[t];
    const int rowbase = blockIdx.x * 128;
    const int lane = t & 63, w = t >> 6;
    const int fo = (lane >> 4) * 16 + (lane & 15);

    auto NSTAGE = [&](int kc, short* Ad, short* Bd) {
        const short* src;
        int kst, kloc;
        if (kc < KC1) { src = A1; kst = KC1 * 32; kloc = kc * 32; }
        else          { src = A2; kst = KC2 * 32; kloc = (kc - KC1) * 32; }
#pragma unroll
        for (int p = 0; p < 2; ++p) {
            int s = t + p * 256;
            int b = (s >> 4) & 3;
            int row = rowbase + ((s >> 6) << 4) + (s & 15);
            gload_lds16(src + (size_t)row * kst + kloc + b * 8, Ad + s * 8);
            gload_lds16(Wp + (size_t)kc * 4096 + s * 8, Bd + s * 8);
        }
    };

    f32x4 acc[2][8];
#pragma unroll
    for (int i = 0; i < 2; ++i)
#pragma unroll
        for (int j = 0; j < 8; ++j) acc[i][j] = (f32x4){0.f, 0.f, 0.f, 0.f};

    constexpr int KC = KC1 + KC2;
    NSTAGE(0, sbuf, sbuf + 4096);
    __syncthreads();
    for (int kc = 0; kc < KC; ++kc) {
        const int cur = kc & 1;
        short* Ac = sbuf + (cur ? 8192 : 0);
        short* Bc = Ac + 4096;
        if (kc + 1 < KC) {
            short* An = sbuf + (cur ? 0 : 8192);
            NSTAGE(kc + 1, An, An + 4096);  // async, overlaps MFMA below
        }
        short8 a0 = *(const short8*)(Ac + (2 * w * 64 + fo) * 8);
        short8 a1 = *(const short8*)(Ac + ((2 * w + 1) * 64 + fo) * 8);
#pragma unroll
        for (int cb = 0; cb < 8; ++cb) {
            short8 bfr = *(const short8*)(Bc + (cb * 64 + fo) * 8);
            acc[0][cb] = __builtin_amdgcn_mfma_f32_16x16x32_bf16(a0, bfr, acc[0][cb], 0, 0, 0);
            acc[1][cb] = __builtin_amdgcn_mfma_f32_16x16x32_bf16(a1, bfr, acc[1][cb], 0, 0, 0);
        }
        __syncthreads();
    }

    // epilogue: bias-add, store, per-column partial stats
    float cs[8], css[8];
#pragma unroll
    for (int cb = 0; cb < 8; ++cb) { cs[cb] = 0.f; css[cb] = 0.f; }
#pragma unroll
    for (int rb2 = 0; rb2 < 2; ++rb2) {
        int rloc = 32 * w + rb2 * 16 + ((lane >> 4) << 2);
#pragma unroll
        for (int cb = 0; cb < 8; ++cb) {
            int col = cb * 16 + (lane & 15);
            float bb = bs[col];
#pragma unroll
            for (int i = 0; i < 4; ++i) {
                int row = rowbase + rloc + i;
                if (row < NN) {
                    float v = acc[rb2][cb][i] + bb;
                    outf[(size_t)row * 128 + col] = v;
                    cs[cb] += v;
                    css[cb] += v * v;
                }
            }
        }
    }
#pragma unroll
    for (int cb = 0; cb < 8; ++cb) {
        cs[cb] += __shfl_xor(cs[cb], 16);
        cs[cb] += __shfl_xor(cs[cb], 32);
        css[cb] += __shfl_xor(css[cb], 16);
        css[cb] += __shfl_xor(css[cb], 32);
    }
    if (lane < 16) {
#pragma unroll
        for (int cb = 0; cb < 8; ++cb) {
            reds[w][cb * 16 + lane] = cs[cb];
            redss[w][cb * 16 + lane] = css[cb];
        }
    }
    __syncthreads();
    if (t < 128) {
        atomicAdd(&stats[t], reds[0][t] + reds[1][t] + reds[2][t] + reds[3][t]);
    } else {
        int c = t - 128;
        atomicAdd(&stats[128 + c], redss[0][c] + redss[1][c] + redss[2][c] + redss[3][c]);
    }
}

// BN (inline stats->scale/shift) + ReLU + convert to bf16
__global__ void k_bnrelu_bf16(const float* __restrict__ h, const float* __restrict__ stats,
                              const float* __restrict__ g, const float* __restrict__ bt,
                              short* __restrict__ hb) {
    int gid = blockIdx.x * 256 + threadIdx.x;  // over NN*16 groups of 8
    if (gid >= NN * 16) return;
    int c8 = gid & 15;
    float av[8], bv[8];
#pragma unroll
    for (int j = 0; j < 8; ++j) {
        int c = c8 * 8 + j;
        float mu = stats[c] * (1.f / NN);
        float var = stats[128 + c] * (1.f / NN) - mu * mu;  // biased (matches ref)
        float a = g[c] * rsqrtf(var + BN_EPS);
        av[j] = a;
        bv[j] = bt[c] - mu * a;
    }
    float4 v0 = reinterpret_cast<const float4*>(h)[gid * 2];
    float4 v1 = reinterpret_cast<const float4*>(h)[gid * 2 + 1];
    short8 o;
    o[0] = f2bf(fmaxf(fmaf(av[0], v0.x, bv[0]), 0.f));
    o[1] = f2bf(fmaxf(fmaf(av[1], v0.y, bv[1]), 0.f));
    o[2] = f2bf(fmaxf(fmaf(av[2], v0.z, bv[2]), 0.f));
    o[3] = f2bf(fmaxf(fmaf(av[3], v0.w, bv[3]), 0.f));
    o[4] = f2bf(fmaxf(fmaf(av[4], v1.x, bv[4]), 0.f));
    o[5] = f2bf(fmaxf(fmaf(av[5], v1.y, bv[5]), 0.f));
    o[6] = f2bf(fmaxf(fmaf(av[6], v1.z, bv[6]), 0.f));
    o[7] = f2bf(fmaxf(fmaf(av[7], v1.w, bv[7]), 0.f));
    reinterpret_cast<short8*>(hb)[gid] = o;
}

// ---------------------------------------------------------------------------
// MFMA edge MLP, 2-phase double-buffered: out = relu(A @ We1 + be1) @ We2 + be2
// A = [hb[u] | hb[v] | bf16(ef)], 128 edges/block, 4 waves.
// ef rows preloaded+converted to registers at start (pure ds_write at stage).
// ---------------------------------------------------------------------------
__global__ __launch_bounds__(256) void k_edge_mfma(
    const short* __restrict__ hb, const float* __restrict__ ef,
    const short* __restrict__ Wp, const short* __restrict__ Wp2e,
    const float* __restrict__ be1, const float* __restrict__ be2,
    const int* __restrict__ uu, const int* __restrict__ vv,
    float* __restrict__ out) {
    __shared__ __align__(16) short smem[17408];  // A0|B0|A1|B1 (16K) ∪ Hid[128][136]
    __shared__ float be1s[128];
    __shared__ int suv[256];
    const int t = threadIdx.x;
    const int eb = blockIdx.x * 128;
    if (t < 128) {
        suv[t] = uu[eb + t];
        suv[128 + t] = vv[eb + t];
        be1s[t] = be1[t];
    }
    const int lane = t & 63, w = t >> 6;
    const int fo = (lane >> 4) * 16 + (lane & 15);
    const int srow = t >> 1;      // ef-staging row
    const int sb0 = (t & 1) * 2;  // ef-staging k-subblock base
    const int sslotbase = (srow >> 4) * 64 + (srow & 15);

    // preload layer-2 B-frags (4 KB, L2-resident)
    short8 b2f[4];
#pragma unroll
    for (int kc2 = 0; kc2 < 4; ++kc2)
        b2f[kc2] = *(const short8*)(Wp2e + (kc2 * 64 + fo) * 8);

    // preload + convert this block's ef A-tiles (kc = 8,9)
    short8 efs[4];
    {
        const float* er = ef + (size_t)(eb + srow) * 64;
#pragma unroll
        for (int kcx = 0; kcx < 2; ++kcx)
#pragma unroll
            for (int pp = 0; pp < 2; ++pp) {
                int b = sb0 + pp;
                float4 f0 = *(const float4*)(er + kcx * 32 + b * 8);
                float4 f1 = *(const float4*)(er + kcx * 32 + b * 8 + 4);
                short8 v8;
                v8[0] = f2bf(f0.x); v8[1] = f2bf(f0.y);
                v8[2] = f2bf(f0.z); v8[3] = f2bf(f0.w);
                v8[4] = f2bf(f1.x); v8[5] = f2bf(f1.y);
                v8[6] = f2bf(f1.z); v8[7] = f2bf(f1.w);
                efs[kcx * 2 + pp] = v8;
            }
    }
    __syncthreads();  // suv ready

    auto STAGE = [&](int kc, short* Ad, short* Bd) {
        if (kc < 8) {
#pragma unroll
            for (int p = 0; p < 2; ++p) {
                int s = t + p * 256;
                int b = (s >> 4) & 3;
                int row = ((s >> 6) << 4) + (s & 15);
                const short* gsrc =
                    hb + (size_t)suv[(kc >= 4) * 128 + row] * 128 + (kc & 3) * 32 + b * 8;
                gload_lds16(gsrc, Ad + s * 8);
            }
        } else {
#pragma unroll
            for (int p = 0; p < 2; ++p)
                *(short8*)(Ad + (sslotbase + (sb0 + p) * 16) * 8) = efs[(kc - 8) * 2 + p];
        }
#pragma unroll
        for (int p = 0; p < 2; ++p) {
            int s = t + p * 256;
            gload_lds16(Wp + (size_t)kc * 4096 + s * 8, Bd + s * 8);
        }
    };

    f32x4 acc[2][8];
#pragma unroll
    for (int i = 0; i < 2; ++i)
#pragma unroll
        for (int j = 0; j < 8; ++j) acc[i][j] = (f32x4){0.f, 0.f, 0.f, 0.f};

    STAGE(0, smem, smem + 4096);
    __syncthreads();
    for (int kc = 0; kc < 10; ++kc) {
        const int cur = kc & 1;
        short* Ac = smem + (cur ? 8192 : 0);
        short* Bc = Ac + 4096;
        if (kc < 9) {
            short* An = smem + (cur ? 0 : 8192);
            STAGE(kc + 1, An, An + 4096);  // async, overlaps MFMA below
        }
        short8 afr0 = *(const short8*)(Ac + (2 * w * 64 + fo) * 8);
        short8 afr1 = *(const short8*)(Ac + ((2 * w + 1) * 64 + fo) * 8);
#pragma unroll
        for (int cb = 0; cb < 8; ++cb) {
            short8 bfr = *(const short8*)(Bc + (cb * 64 + fo) * 8);
            acc[0][cb] = __builtin_amdgcn_mfma_f32_16x16x32_bf16(afr0, bfr, acc[0][cb], 0, 0, 0);
            acc[1][cb] = __builtin_amdgcn_mfma_f32_16x16x32_bf16(afr1, bfr, acc[1][cb], 0, 0, 0);
        }
        __syncthreads();
    }

    // ---- epilogue 1: bias + relu -> Hid[128][136] bf16 (reuses stage region) ----
    short* Hid = smem;
#pragma unroll
    for (int rb2 = 0; rb2 < 2; ++rb2)
#pragma unroll
        for (int cb = 0; cb < 8; ++cb) {
            int col = cb * 16 + (lane & 15);
            int rbase = 32 * w + rb2 * 16 + ((lane >> 4) << 2);
            float bb = be1s[col];
#pragma unroll
            for (int i = 0; i < 4; ++i)
                Hid[(rbase + i) * 136 + col] = f2bf(fmaxf(acc[rb2][cb][i] + bb, 0.f));
        }
    __syncthreads();

    // ---- layer 2 via MFMA: out[e][0..7] = Hid @ We2p + be2 ----
#pragma unroll
    for (int rf = 0; rf < 2; ++rf) {
        f32x4 a2 = (f32x4){0.f, 0.f, 0.f, 0.f};
        const int rbl = 32 * w + 16 * rf + (lane & 15);
#pragma unroll
        for (int kc2 = 0; kc2 < 4; ++kc2) {
            short8 af = *(const short8*)(Hid + rbl * 136 + kc2 * 32 + 8 * (lane >> 4));
            a2 = __builtin_amdgcn_mfma_f32_16x16x32_bf16(af, b2f[kc2], a2, 0, 0, 0);
        }
        int col = lane & 15;
        if (col < 8) {
            int r0 = eb + 32 * w + 16 * rf + 4 * (lane >> 4);
            float bb = be2[col];
#pragma unroll
            for (int i = 0; i < 4; ++i)
                out[(size_t)(r0 + i) * 8 + col] = a2[i] + bb;
        }
    }
}

// ---------------------------------------------------------------------------
extern "C" void kernel_launch(void* const* d_in, const int* in_sizes, int n_in,
                              void* d_out, int out_size, void* d_ws, size_t ws_size,
                              hipStream_t stream) {
    const float* x   = (const float*)d_in[0];
    const float* ef  = (const float*)d_in[1];
    const float* Ws1 = (const float*)d_in[2];
    const float* Wn1 = (const float*)d_in[3];
    const float* b1  = (const float*)d_in[4];
    const float* g1  = (const float*)d_in[5];
    const float* bt1 = (const float*)d_in[6];
    const float* Ws2 = (const float*)d_in[7];
    const float* Wn2 = (const float*)d_in[8];
    const float* b2  = (const float*)d_in[9];
    const float* g2  = (const float*)d_in[10];
    const float* bt2 = (const float*)d_in[11];
    const float* We1 = (const float*)d_in[12];
    const float* be1 = (const float*)d_in[13];
    const float* We2 = (const float*)d_in[14];
    const float* be2 = (const float*)d_in[15];
    const int* src = (const int*)d_in[16];
    const int* dst = (const int*)d_in[17];
    const int* u   = (const int*)d_in[18];
    const int* v   = (const int*)d_in[19];
    float* out = (float*)d_out;

    // Workspace (~85 MB). h1/h2 fp32 live in d_out (N*128 == out_size).
    // hb aliases xb+agg1b (dead after layer-1 GEMM; contiguous 25.6 MB).
    char* p = (char*)d_ws;
    auto take = [&](size_t bytes) {
        char* r = p;
        p += (bytes + 255) & ~(size_t)255;
        return r;
    };
    int* cnt     = (int*)take(NN * 4);       // adjacent to stats: one memset
    float* stats = (float*)take(512 * 4);    // [0:256)=layer1, [256:512)=layer2
    float* invd  = (float*)take(NN * 4);
    int* offs    = (int*)take((NN + 1) * 4);
    int* cursor  = (int*)take(NN * 4);
    int* eidsrc  = (int*)take((size_t)EE * 4);
    short* Wp_e  = (short*)take(320 * 128 * 2);
    short* Wp1   = (short*)take(128 * 128 * 2);
    short* Wp2   = (short*)take(256 * 128 * 2);
    short* Wp2e  = (short*)take(256 * 8 * 2);
    short* xb    = (short*)take((size_t)NN * 64 * 2);
    short* agg1b = (short*)take((size_t)NN * 64 * 2);
    short* h1b   = (short*)take((size_t)NN * 128 * 2);
    short* agg2b = (short*)take((size_t)NN * 128 * 2);
    take(65536);  // pad: node GEMMs read up to ~25 KB past last row
    float* h1 = out;
    float* h2 = out;
    short* hb = xb;  // 25.6 MB union of xb+agg1b

    // ---- CSR build + weight pre-pack + x -> bf16 ----
    hipMemsetAsync(cnt, 0, ((char*)stats - (char*)cnt) + 512 * 4, stream);
    k_count<<<(EE + 255) / 256, 256, 0, stream>>>(dst, cnt);
    k_scan<<<1, 1024, 0, stream>>>(cnt, offs, cursor, invd);
    k_fill<<<(EE + 255) / 256, 256, 0, stream>>>(src, dst, cursor, eidsrc);
    k_pack_all<<<360, 256, 0, stream>>>(We1, Ws1, Wn1, Ws2, Wn2, We2, Wp_e, Wp1, Wp2, Wp2e);
    k_f2bf<<<(NN * 8 + 255) / 256, 256, 0, stream>>>(x, xb, NN * 8);

    // ---- layer 1 (bf16 inputs, fp32 accum/stats; stats fused in GEMM) ----
    k_gather_bf<64><<<(NN * 8 + 255) / 256, 256, 0, stream>>>(xb, offs, eidsrc, invd, agg1b);
    k_node_mfma<2, 2><<<(NN + 127) / 128, 256, 0, stream>>>(xb, agg1b, Wp1, b1, h1, stats);
    k_bnrelu_bf16<<<(NN * 16 + 255) / 256, 256, 0, stream>>>(h1, stats, g1, bt1, h1b);

    // ---- layer 2 ----
    k_gather_bf<128><<<(NN * 16 + 255) / 256, 256, 0, stream>>>(h1b, offs, eidsrc, invd, agg2b);
    k_node_mfma<4, 4><<<(NN + 127) / 128, 256, 0, stream>>>(h1b, agg2b, Wp2, b2, h2, stats + 256);
    k_bnrelu_bf16<<<(NN * 16 + 255) / 256, 256, 0, stream>>>(h2, stats + 256, g2, bt2, hb);

    // ---- edge head (bf16 MFMA, both layers, 2-phase pipelined) ----
    k_edge_mfma<<<EE / 128, 256, 0, stream>>>(hb, ef, Wp_e, Wp2e, be1, be2, u, v, out);
}

// Round 7
// 662.049 us; speedup vs baseline: 10.5040x; 1.1676x over previous
//
#include <hip/hip_runtime.h>

// Problem constants (fixed by the reference).
#define NN 100000
#define EE 1600000
// D_IN=64, H=128, E_IN=64, C=8
constexpr float BN_EPS = 1e-5f;

typedef __attribute__((ext_vector_type(8))) short short8;
typedef __attribute__((ext_vector_type(4))) float f32x4;

__device__ __forceinline__ short f2bf(float f) {  // RNE f32 -> bf16
    unsigned u = __float_as_uint(f);
    u += 0x7fff + ((u >> 16) & 1);
    return (short)(u >> 16);
}
__device__ __forceinline__ float bf2f(short s) {
    return __uint_as_float(((unsigned)(unsigned short)s) << 16);
}

// async global->LDS DMA, 16 B per lane. LDS dest must be base + lane*16
// within each wave (guaranteed by construction at all call sites).
typedef __attribute__((address_space(1))) const unsigned int guint;
typedef __attribute__((address_space(3))) unsigned int luint;
__device__ __forceinline__ void gload_lds16(const void* g, void* l) {
    __builtin_amdgcn_global_load_lds((guint*)g, (luint*)l, 16, 0, 0);
}

// ---------------------------------------------------------------------------
// CSR build: count -> 3-stage parallel scan -> fill
// ---------------------------------------------------------------------------
__global__ void k_count(const int* __restrict__ dst, int* __restrict__ cnt) {
    int e = blockIdx.x * 256 + threadIdx.x;
    if (e < EE) atomicAdd(&cnt[dst[e]], 1);
}

// stage 1: per-1024-block sums
__global__ __launch_bounds__(1024) void k_scan_part(const int* __restrict__ cnt,
                                                    int* __restrict__ bsum) {
    const int t = threadIdx.x, lane = t & 63, w = t >> 6;
    int i = blockIdx.x * 1024 + t;
    int v = (i < NN) ? cnt[i] : 0;
#pragma unroll
    for (int d = 1; d < 64; d <<= 1) v += __shfl_xor(v, d, 64);
    __shared__ int ws[16];
    if (lane == 0) ws[w] = v;
    __syncthreads();
    if (t == 0) {
        int s = 0;
#pragma unroll
        for (int k = 0; k < 16; ++k) s += ws[k];
        bsum[blockIdx.x] = s;
    }
}

// stage 2: exclusive scan of the 98 block sums (single thread; tiny)
__global__ void k_scan_base(int* __restrict__ bsum, int* __restrict__ offs, int nb) {
    if (threadIdx.x == 0) {
        int run = 0;
        for (int k = 0; k < nb; ++k) {
            int v = bsum[k];
            bsum[k] = run;
            run += v;
        }
        offs[NN] = run;
    }
}

// stage 3: local exclusive scan + base; emits offs, cursor, invd
__global__ __launch_bounds__(1024) void k_scan_final(const int* __restrict__ cnt,
                                                     const int* __restrict__ bsum,
                                                     int* __restrict__ offs,
                                                     int* __restrict__ cursor,
                                                     float* __restrict__ invd) {
    const int t = threadIdx.x, lane = t & 63, w = t >> 6;
    __shared__ int wsum[16], wexcl[16];
    int i = blockIdx.x * 1024 + t;
    int v = (i < NN) ? cnt[i] : 0;
    int s = v;
#pragma unroll
    for (int d = 1; d < 64; d <<= 1) {
        int o = __shfl_up(s, d, 64);
        if (lane >= d) s += o;
    }
    if (lane == 63) wsum[w] = s;
    __syncthreads();
    if (t < 16) {
        int wv = wsum[t];
        int ss = wv;
#pragma unroll
        for (int d = 1; d < 16; d <<= 1) {
            int o = __shfl_up(ss, d, 16);
            if (t >= d) ss += o;
        }
        wexcl[t] = ss - wv;
    }
    __syncthreads();
    if (i < NN) {
        int o = bsum[blockIdx.x] + (s - v) + wexcl[w];
        offs[i] = o;
        cursor[i] = o;
        invd[i] = v > 0 ? 1.f / (float)v : 0.f;  // DGL mean: zero-degree -> 0
    }
}

__global__ void k_fill(const int* __restrict__ src, const int* __restrict__ dst,
                       int* __restrict__ cursor, int* __restrict__ eidsrc) {
    int e = blockIdx.x * 256 + threadIdx.x;
    if (e < EE) {
        int pos = atomicAdd(&cursor[dst[e]], 1);
        eidsrc[pos] = src[e];
    }
}

// ---------------------------------------------------------------------------
// fp32 -> bf16 bulk convert (8 elems/thread)
// ---------------------------------------------------------------------------
__global__ void k_f2bf(const float* __restrict__ in, short* __restrict__ out, int n8) {
    int i = blockIdx.x * 256 + threadIdx.x;
    if (i >= n8) return;
    float4 a = ((const float4*)in)[i * 2];
    float4 b = ((const float4*)in)[i * 2 + 1];
    short8 o;
    o[0] = f2bf(a.x); o[1] = f2bf(a.y); o[2] = f2bf(a.z); o[3] = f2bf(a.w);
    o[4] = f2bf(b.x); o[5] = f2bf(b.y); o[6] = f2bf(b.z); o[7] = f2bf(b.w);
    ((short8*)out)[i] = o;
}

// ---------------------------------------------------------------------------
// bf16 CSR mean-aggregation: F/8 lanes per node, 16 B (8 cols) per lane,
// fp32 accum, 4-deep unrolled -> 4 KB/wave outstanding.
// ---------------------------------------------------------------------------
template <int F>
__global__ __launch_bounds__(256) void k_gather_bf(
    const short* __restrict__ hbsrc, const int* __restrict__ offs,
    const int* __restrict__ eidsrc, const float* __restrict__ invd,
    short* __restrict__ aggb) {
    constexpr int G = F / 8;  // lanes per node
    int gid = blockIdx.x * 256 + threadIdx.x;
    int node = gid / G;
    int sub = gid % G;
    if (node >= NN) return;
    int beg = offs[node], end = offs[node + 1];
    float iv = invd[node];
    float s[8] = {0.f, 0.f, 0.f, 0.f, 0.f, 0.f, 0.f, 0.f};
    const size_t co = (size_t)sub * 8;
    int p = beg;
    for (; p + 4 <= end; p += 4) {
        int i0 = eidsrc[p], i1 = eidsrc[p + 1], i2 = eidsrc[p + 2], i3 = eidsrc[p + 3];
        short8 r0 = *(const short8*)(hbsrc + (size_t)i0 * F + co);
        short8 r1 = *(const short8*)(hbsrc + (size_t)i1 * F + co);
        short8 r2 = *(const short8*)(hbsrc + (size_t)i2 * F + co);
        short8 r3 = *(const short8*)(hbsrc + (size_t)i3 * F + co);
#pragma unroll
        for (int j = 0; j < 8; ++j)
            s[j] += (bf2f(r0[j]) + bf2f(r1[j])) + (bf2f(r2[j]) + bf2f(r3[j]));
    }
    for (; p < end; ++p) {
        short8 r = *(const short8*)(hbsrc + (size_t)eidsrc[p] * F + co);
#pragma unroll
        for (int j = 0; j < 8; ++j) s[j] += bf2f(r[j]);
    }
    short8 o;
#pragma unroll
    for (int j = 0; j < 8; ++j) o[j] = f2bf(s[j] * iv);
    *(short8*)(aggb + (size_t)node * F + co) = o;
}

// ---------------------------------------------------------------------------
// Unified weight pre-pack into bf16 MFMA-B fragment order.
// slot = cb*64 + bp*16 + n, elem j; content = W[k][16*cb+n], gk = k + kbase,
// kc = gk>>5, bp = (gk&31)>>3, j = gk&7.
// ---------------------------------------------------------------------------
__device__ __forceinline__ void packW(const float* W, short* Wp, int local, int kbase) {
    int k = local >> 7, col = local & 127;
    int gk = k + kbase;
    int kc = gk >> 5, kw = gk & 31, bp = kw >> 3, j = kw & 7;
    int cb = col >> 4, n = col & 15;
    Wp[kc * 4096 + (cb * 64 + bp * 16 + n) * 8 + j] = f2bf(W[k * 128 + col]);
}

__global__ void k_pack_all(const float* __restrict__ We1, const float* __restrict__ Ws1,
                           const float* __restrict__ Wn1, const float* __restrict__ Ws2,
                           const float* __restrict__ Wn2, const float* __restrict__ We2,
                           short* __restrict__ Wp_e, short* __restrict__ Wp1,
                           short* __restrict__ Wp2, short* __restrict__ Wp2e) {
    int idx = blockIdx.x * 256 + threadIdx.x;
    if (idx < 40960) {
        packW(We1, Wp_e, idx, 0);
    } else if (idx < 49152) {
        packW(Ws1, Wp1, idx - 40960, 0);
    } else if (idx < 57344) {
        packW(Wn1, Wp1, idx - 49152, 64);
    } else if (idx < 73728) {
        packW(Ws2, Wp2, idx - 57344, 0);
    } else if (idx < 90112) {
        packW(Wn2, Wp2, idx - 73728, 128);
    } else if (idx < 92160) {
        int local = idx - 90112;  // over 128 k x 16 n
        int k = local >> 4, n = local & 15;
        float val = (n < 8) ? We2[k * 8 + n] : 0.f;
        int kc2 = k >> 5, kl = k & 31, bp = kl >> 3, j = kl & 7;
        Wp2e[(kc2 * 64 + bp * 16 + n) * 8 + j] = f2bf(val);
    }
}

// ---------------------------------------------------------------------------
// bf16 MFMA node GEMM, 2-phase double-buffered staging, fused col-stats.
// outf[N,128] = [A1b | A2b] @ Wp + bias; stats[0:128)=colsum, [128:256)=colsumsq
// ---------------------------------------------------------------------------
template <int KC1, int KC2>
__global__ __launch_bounds__(256) void k_node_mfma(
    const short* __restrict__ A1, const short* __restrict__ A2,
    const short* __restrict__ Wp, const float* __restrict__ bias,
    float* __restrict__ outf, float* __restrict__ stats) {
    __shared__ __align__(16) short sbuf[16384];  // A0|B0|A1|B1, 4096 each
    __shared__ float bs[128];
    __shared__ float reds[4][128], redss[4][128];
    const int t = threadIdx.x;
    if (t < 128) bs[t] = bias[t];
    const int rowbase = blockIdx.x * 128;
    const int lane = t & 63, w = t >> 6;
    const int fo = (lane >> 4) * 16 + (lane & 15);

    auto NSTAGE = [&](int kc, short* Ad, short* Bd) {
        const short* src;
        int kst, kloc;
        if (kc < KC1) { src = A1; kst = KC1 * 32; kloc = kc * 32; }
        else          { src = A2; kst = KC2 * 32; kloc = (kc - KC1) * 32; }
#pragma unroll
        for (int p = 0; p < 2; ++p) {
            int s = t + p * 256;
            int b = (s >> 4) & 3;
            int row = rowbase + ((s >> 6) << 4) + (s & 15);
            gload_lds16(src + (size_t)row * kst + kloc + b * 8, Ad + s * 8);
            gload_lds16(Wp + (size_t)kc * 4096 + s * 8, Bd + s * 8);
        }
    };

    f32x4 acc[2][8];
#pragma unroll
    for (int i = 0; i < 2; ++i)
#pragma unroll
        for (int j = 0; j < 8; ++j) acc[i][j] = (f32x4){0.f, 0.f, 0.f, 0.f};

    constexpr int KC = KC1 + KC2;
    NSTAGE(0, sbuf, sbuf + 4096);
    __syncthreads();
    for (int kc = 0; kc < KC; ++kc) {
        const int cur = kc & 1;
        short* Ac = sbuf + (cur ? 8192 : 0);
        short* Bc = Ac + 4096;
        if (kc + 1 < KC) {
            short* An = sbuf + (cur ? 0 : 8192);
            NSTAGE(kc + 1, An, An + 4096);  // async, overlaps MFMA below
        }
        short8 a0 = *(const short8*)(Ac + (2 * w * 64 + fo) * 8);
        short8 a1 = *(const short8*)(Ac + ((2 * w + 1) * 64 + fo) * 8);
#pragma unroll
        for (int cb = 0; cb < 8; ++cb) {
            short8 bfr = *(const short8*)(Bc + (cb * 64 + fo) * 8);
            acc[0][cb] = __builtin_amdgcn_mfma_f32_16x16x32_bf16(a0, bfr, acc[0][cb], 0, 0, 0);
            acc[1][cb] = __builtin_amdgcn_mfma_f32_16x16x32_bf16(a1, bfr, acc[1][cb], 0, 0, 0);
        }
        __syncthreads();
    }

    // epilogue: bias-add, store, per-column partial stats
    float cs[8], css[8];
#pragma unroll
    for (int cb = 0; cb < 8; ++cb) { cs[cb] = 0.f; css[cb] = 0.f; }
#pragma unroll
    for (int rb2 = 0; rb2 < 2; ++rb2) {
        int rloc = 32 * w + rb2 * 16 + ((lane >> 4) << 2);
#pragma unroll
        for (int cb = 0; cb < 8; ++cb) {
            int col = cb * 16 + (lane & 15);
            float bb = bs[col];
#pragma unroll
            for (int i = 0; i < 4; ++i) {
                int row = rowbase + rloc + i;
                if (row < NN) {
                    float v = acc[rb2][cb][i] + bb;
                    outf[(size_t)row * 128 + col] = v;
                    cs[cb] += v;
                    css[cb] += v * v;
                }
            }
        }
    }
#pragma unroll
    for (int cb = 0; cb < 8; ++cb) {
        cs[cb] += __shfl_xor(cs[cb], 16);
        cs[cb] += __shfl_xor(cs[cb], 32);
        css[cb] += __shfl_xor(css[cb], 16);
        css[cb] += __shfl_xor(css[cb], 32);
    }
    if (lane < 16) {
#pragma unroll
        for (int cb = 0; cb < 8; ++cb) {
            reds[w][cb * 16 + lane] = cs[cb];
            redss[w][cb * 16 + lane] = css[cb];
        }
    }
    __syncthreads();
    if (t < 128) {
        atomicAdd(&stats[t], reds[0][t] + reds[1][t] + reds[2][t] + reds[3][t]);
    } else {
        int c = t - 128;
        atomicAdd(&stats[128 + c], redss[0][c] + redss[1][c] + redss[2][c] + redss[3][c]);
    }
}

// BN + ReLU + convert to bf16; scale/shift computed once per block in LDS.
__global__ void k_bnrelu_bf16(const float* __restrict__ h, const float* __restrict__ stats,
                              const float* __restrict__ g, const float* __restrict__ bt,
                              short* __restrict__ hb) {
    __shared__ float a_sh[128], b_sh[128];
    const int t = threadIdx.x;
    if (t < 128) {
        float mu = stats[t] * (1.f / NN);
        float var = stats[128 + t] * (1.f / NN) - mu * mu;  // biased (matches ref)
        float a = g[t] * rsqrtf(var + BN_EPS);
        a_sh[t] = a;
        b_sh[t] = bt[t] - mu * a;
    }
    __syncthreads();
    int gid = blockIdx.x * 256 + t;  // over NN*16 groups of 8
    if (gid >= NN * 16) return;
    int c0 = (gid & 15) * 8;
    float4 v0 = reinterpret_cast<const float4*>(h)[gid * 2];
    float4 v1 = reinterpret_cast<const float4*>(h)[gid * 2 + 1];
    short8 o;
    o[0] = f2bf(fmaxf(fmaf(a_sh[c0 + 0], v0.x, b_sh[c0 + 0]), 0.f));
    o[1] = f2bf(fmaxf(fmaf(a_sh[c0 + 1], v0.y, b_sh[c0 + 1]), 0.f));
    o[2] = f2bf(fmaxf(fmaf(a_sh[c0 + 2], v0.z, b_sh[c0 + 2]), 0.f));
    o[3] = f2bf(fmaxf(fmaf(a_sh[c0 + 3], v0.w, b_sh[c0 + 3]), 0.f));
    o[4] = f2bf(fmaxf(fmaf(a_sh[c0 + 4], v1.x, b_sh[c0 + 4]), 0.f));
    o[5] = f2bf(fmaxf(fmaf(a_sh[c0 + 5], v1.y, b_sh[c0 + 5]), 0.f));
    o[6] = f2bf(fmaxf(fmaf(a_sh[c0 + 6], v1.z, b_sh[c0 + 6]), 0.f));
    o[7] = f2bf(fmaxf(fmaf(a_sh[c0 + 7], v1.w, b_sh[c0 + 7]), 0.f));
    reinterpret_cast<short8*>(hb)[gid] = o;
}

// ---------------------------------------------------------------------------
// MFMA edge MLP (R5-proven structure): 128 edges/block, 4 waves, single-buffer
// stage->sync->MFMA->sync. Layer 2 via MFMA through Hid LDS round-trip.
// ---------------------------------------------------------------------------
__global__ __launch_bounds__(256) void k_edge_mfma(
    const short* __restrict__ hb, const float* __restrict__ ef,
    const short* __restrict__ Wp, const short* __restrict__ Wp2e,
    const float* __restrict__ be1, const float* __restrict__ be2,
    const int* __restrict__ uu, const int* __restrict__ vv,
    float* __restrict__ out) {
    __shared__ __align__(16) short smem[17408];  // Hid[128][136] | (A 4096 + B 4096)
    __shared__ float be1s[128];
    __shared__ int suv[256];
    short* A_l = smem;
    short* B_l = smem + 4096;
    const int t = threadIdx.x;
    const int eb = blockIdx.x * 128;
    if (t < 128) {
        suv[t] = uu[eb + t];
        suv[128 + t] = vv[eb + t];
        be1s[t] = be1[t];
    }
    __syncthreads();

    const int lane = t & 63, w = t >> 6;
    const int fo = (lane >> 4) * 16 + (lane & 15);
    const int srow = t >> 1;      // ef-staging row
    const int sb0 = (t & 1) * 2;  // ef-staging k-subblock base
    const int sslotbase = (srow >> 4) * 64 + (srow & 15);

    // preload layer-2 B-frags (4 KB, L2-resident)
    short8 b2f[4];
#pragma unroll
    for (int kc2 = 0; kc2 < 4; ++kc2)
        b2f[kc2] = *(const short8*)(Wp2e + (kc2 * 64 + fo) * 8);

    f32x4 acc[2][8];
#pragma unroll
    for (int i = 0; i < 2; ++i)
#pragma unroll
        for (int j = 0; j < 8; ++j) acc[i][j] = (f32x4){0.f, 0.f, 0.f, 0.f};

    for (int kc = 0; kc < 10; ++kc) {
        // ---- stage A ----
        if (kc < 8) {
#pragma unroll
            for (int p = 0; p < 2; ++p) {
                int s = t + p * 256;
                int b = (s >> 4) & 3;
                int row = ((s >> 6) << 4) + (s & 15);
                const short* gsrc =
                    hb + (size_t)suv[(kc >= 4) * 128 + row] * 128 + (kc & 3) * 32 + b * 8;
                gload_lds16(gsrc, A_l + s * 8);
            }
        } else {
            const float* er = ef + (size_t)(eb + srow) * 64 + (kc - 8) * 32;
#pragma unroll
            for (int p = 0; p < 2; ++p) {
                int b = sb0 + p;
                float4 f0 = *(const float4*)(er + b * 8);
                float4 f1 = *(const float4*)(er + b * 8 + 4);
                short8 v8;
                v8[0] = f2bf(f0.x); v8[1] = f2bf(f0.y);
                v8[2] = f2bf(f0.z); v8[3] = f2bf(f0.w);
                v8[4] = f2bf(f1.x); v8[5] = f2bf(f1.y);
                v8[6] = f2bf(f1.z); v8[7] = f2bf(f1.w);
                *(short8*)(A_l + (sslotbase + b * 16) * 8) = v8;
            }
        }
        // ---- stage B (pre-packed, linear DMA) ----
#pragma unroll
        for (int p = 0; p < 2; ++p) {
            int s = t + p * 256;
            gload_lds16(Wp + (size_t)kc * 4096 + s * 8, B_l + s * 8);
        }
        __syncthreads();

        short8 afr0 = *(const short8*)(A_l + ((2 * w) * 64 + fo) * 8);
        short8 afr1 = *(const short8*)(A_l + ((2 * w + 1) * 64 + fo) * 8);
#pragma unroll
        for (int cb = 0; cb < 8; ++cb) {
            short8 bfr = *(const short8*)(B_l + (cb * 64 + fo) * 8);
            acc[0][cb] = __builtin_amdgcn_mfma_f32_16x16x32_bf16(afr0, bfr, acc[0][cb], 0, 0, 0);
            acc[1][cb] = __builtin_amdgcn_mfma_f32_16x16x32_bf16(afr1, bfr, acc[1][cb], 0, 0, 0);
        }
        __syncthreads();
    }

    // ---- epilogue 1: bias + relu -> Hid[128][136] bf16 (reuses A/B region) ----
    short* Hid = smem;
#pragma unroll
    for (int rb2 = 0; rb2 < 2; ++rb2)
#pragma unroll
        for (int cb = 0; cb < 8; ++cb) {
            int col = cb * 16 + (lane & 15);
            int rbase = 32 * w + rb2 * 16 + ((lane >> 4) << 2);
            float bb = be1s[col];
#pragma unroll
            for (int i = 0; i < 4; ++i)
                Hid[(rbase + i) * 136 + col] = f2bf(fmaxf(acc[rb2][cb][i] + bb, 0.f));
        }
    __syncthreads();

    // ---- layer 2 via MFMA: out[e][0..7] = Hid @ We2p + be2 ----
#pragma unroll
    for (int rf = 0; rf < 2; ++rf) {
        f32x4 a2 = (f32x4){0.f, 0.f, 0.f, 0.f};
        const int rbl = 32 * w + 16 * rf + (lane & 15);
#pragma unroll
        for (int kc2 = 0; kc2 < 4; ++kc2) {
            short8 af = *(const short8*)(Hid + rbl * 136 + kc2 * 32 + 8 * (lane >> 4));
            a2 = __builtin_amdgcn_mfma_f32_16x16x32_bf16(af, b2f[kc2], a2, 0, 0, 0);
        }
        int col = lane & 15;
        if (col < 8) {
            int r0 = eb + 32 * w + 16 * rf + 4 * (lane >> 4);
            float bb = be2[col];
#pragma unroll
            for (int i = 0; i < 4; ++i)
                out[(size_t)(r0 + i) * 8 + col] = a2[i] + bb;
        }
    }
}

// ---------------------------------------------------------------------------
extern "C" void kernel_launch(void* const* d_in, const int* in_sizes, int n_in,
                              void* d_out, int out_size, void* d_ws, size_t ws_size,
                              hipStream_t stream) {
    const float* x   = (const float*)d_in[0];
    const float* ef  = (const float*)d_in[1];
    const float* Ws1 = (const float*)d_in[2];
    const float* Wn1 = (const float*)d_in[3];
    const float* b1  = (const float*)d_in[4];
    const float* g1  = (const float*)d_in[5];
    const float* bt1 = (const float*)d_in[6];
    const float* Ws2 = (const float*)d_in[7];
    const float* Wn2 = (const float*)d_in[8];
    const float* b2  = (const float*)d_in[9];
    const float* g2  = (const float*)d_in[10];
    const float* bt2 = (const float*)d_in[11];
    const float* We1 = (const float*)d_in[12];
    const float* be1 = (const float*)d_in[13];
    const float* We2 = (const float*)d_in[14];
    const float* be2 = (const float*)d_in[15];
    const int* src = (const int*)d_in[16];
    const int* dst = (const int*)d_in[17];
    const int* u   = (const int*)d_in[18];
    const int* v   = (const int*)d_in[19];
    float* out = (float*)d_out;

    // Workspace (~85 MB). h1/h2 fp32 live in d_out (N*128 == out_size).
    // hb aliases xb+agg1b (dead after layer-1 GEMM; contiguous 25.6 MB).
    char* p = (char*)d_ws;
    auto take = [&](size_t bytes) {
        char* r = p;
        p += (bytes + 255) & ~(size_t)255;
        return r;
    };
    int* cnt     = (int*)take(NN * 4);       // adjacent to stats: one memset
    float* stats = (float*)take(512 * 4);    // [0:256)=layer1, [256:512)=layer2
    float* invd  = (float*)take(NN * 4);
    int* offs    = (int*)take((NN + 1) * 4);
    int* cursor  = (int*)take(NN * 4);
    int* bsum    = (int*)take(128 * 4);
    int* eidsrc  = (int*)take((size_t)EE * 4);
    short* Wp_e  = (short*)take(320 * 128 * 2);
    short* Wp1   = (short*)take(128 * 128 * 2);
    short* Wp2   = (short*)take(256 * 128 * 2);
    short* Wp2e  = (short*)take(256 * 8 * 2);
    short* xb    = (short*)take((size_t)NN * 64 * 2);
    short* agg1b = (short*)take((size_t)NN * 64 * 2);
    short* h1b   = (short*)take((size_t)NN * 128 * 2);
    short* agg2b = (short*)take((size_t)NN * 128 * 2);
    take(65536);  // pad: node GEMMs read up to ~25 KB past last row
    float* h1 = out;
    float* h2 = out;
    short* hb = xb;  // 25.6 MB union of xb+agg1b

    const int NB = (NN + 1023) / 1024;  // 98 scan blocks

    // ---- CSR build + weight pre-pack + x -> bf16 ----
    hipMemsetAsync(cnt, 0, ((char*)stats - (char*)cnt) + 512 * 4, stream);
    k_count<<<(EE + 255) / 256, 256, 0, stream>>>(dst, cnt);
    k_scan_part<<<NB, 1024, 0, stream>>>(cnt, bsum);
    k_scan_base<<<1, 64, 0, stream>>>(bsum, offs, NB);
    k_scan_final<<<NB, 1024, 0, stream>>>(cnt, bsum, offs, cursor, invd);
    k_fill<<<(EE + 255) / 256, 256, 0, stream>>>(src, dst, cursor, eidsrc);
    k_pack_all<<<360, 256, 0, stream>>>(We1, Ws1, Wn1, Ws2, Wn2, We2, Wp_e, Wp1, Wp2, Wp2e);
    k_f2bf<<<(NN * 8 + 255) / 256, 256, 0, stream>>>(x, xb, NN * 8);

    // ---- layer 1 (bf16 inputs, fp32 accum/stats; stats fused in GEMM) ----
    k_gather_bf<64><<<(NN * 8 + 255) / 256, 256, 0, stream>>>(xb, offs, eidsrc, invd, agg1b);
    k_node_mfma<2, 2><<<(NN + 127) / 128, 256, 0, stream>>>(xb, agg1b, Wp1, b1, h1, stats);
    k_bnrelu_bf16<<<(NN * 16 + 255) / 256, 256, 0, stream>>>(h1, stats, g1, bt1, h1b);

    // ---- layer 2 ----
    k_gather_bf<128><<<(NN * 16 + 255) / 256, 256, 0, stream>>>(h1b, offs, eidsrc, invd, agg2b);
    k_node_mfma<4, 4><<<(NN + 127) / 128, 256, 0, stream>>>(h1b, agg2b, Wp2, b2, h2, stats + 256);
    k_bnrelu_bf16<<<(NN * 16 + 255) / 256, 256, 0, stream>>>(h2, stats + 256, g2, bt2, hb);

    // ---- edge head (bf16 MFMA, both layers; R5-proven structure) ----
    k_edge_mfma<<<EE / 128, 256, 0, stream>>>(hb, ef, Wp_e, Wp2e, be1, be2, u, v, out);
}

// Round 8
// 656.324 us; speedup vs baseline: 10.5956x; 1.0087x over previous
//
#include <hip/hip_runtime.h>

// Problem constants (fixed by the reference).
#define NN 100000
#define EE 1600000
// D_IN=64, H=128, E_IN=64, C=8
constexpr float BN_EPS = 1e-5f;

typedef __attribute__((ext_vector_type(8))) short short8;
typedef __attribute__((ext_vector_type(4))) float f32x4;

__device__ __forceinline__ short f2bf(float f) {  // RNE f32 -> bf16
    unsigned u = __float_as_uint(f);
    u += 0x7fff + ((u >> 16) & 1);
    return (short)(u >> 16);
}
__device__ __forceinline__ float bf2f(short s) {
    return __uint_as_float(((unsigned)(unsigned short)s) << 16);
}

// async global->LDS DMA, 16 B per lane. LDS dest must be base + lane*16
// within each wave (guaranteed by construction at all call sites).
typedef __attribute__((address_space(1))) const unsigned int guint;
typedef __attribute__((address_space(3))) unsigned int luint;
__device__ __forceinline__ void gload_lds16(const void* g, void* l) {
    __builtin_amdgcn_global_load_lds((guint*)g, (luint*)l, 16, 0, 0);
}

// ---------------------------------------------------------------------------
// CSR build: count -> 3-stage parallel scan -> fill
// ---------------------------------------------------------------------------
__global__ void k_count(const int* __restrict__ dst, int* __restrict__ cnt) {
    int e = blockIdx.x * 256 + threadIdx.x;
    if (e < EE) atomicAdd(&cnt[dst[e]], 1);
}

// stage 1: per-1024-block sums
__global__ __launch_bounds__(1024) void k_scan_part(const int* __restrict__ cnt,
                                                    int* __restrict__ bsum) {
    const int t = threadIdx.x, lane = t & 63, w = t >> 6;
    int i = blockIdx.x * 1024 + t;
    int v = (i < NN) ? cnt[i] : 0;
#pragma unroll
    for (int d = 1; d < 64; d <<= 1) v += __shfl_xor(v, d, 64);
    __shared__ int ws[16];
    if (lane == 0) ws[w] = v;
    __syncthreads();
    if (t == 0) {
        int s = 0;
#pragma unroll
        for (int k = 0; k < 16; ++k) s += ws[k];
        bsum[blockIdx.x] = s;
    }
}

// stage 2: exclusive scan of the 98 block sums (single thread; tiny)
__global__ void k_scan_base(int* __restrict__ bsum, int* __restrict__ offs, int nb) {
    if (threadIdx.x == 0) {
        int run = 0;
        for (int k = 0; k < nb; ++k) {
            int v = bsum[k];
            bsum[k] = run;
            run += v;
        }
        offs[NN] = run;
    }
}

// stage 3: local exclusive scan + base; emits offs, cursor, invd
__global__ __launch_bounds__(1024) void k_scan_final(const int* __restrict__ cnt,
                                                     const int* __restrict__ bsum,
                                                     int* __restrict__ offs,
                                                     int* __restrict__ cursor,
                                                     float* __restrict__ invd) {
    const int t = threadIdx.x, lane = t & 63, w = t >> 6;
    __shared__ int wsum[16], wexcl[16];
    int i = blockIdx.x * 1024 + t;
    int v = (i < NN) ? cnt[i] : 0;
    int s = v;
#pragma unroll
    for (int d = 1; d < 64; d <<= 1) {
        int o = __shfl_up(s, d, 64);
        if (lane >= d) s += o;
    }
    if (lane == 63) wsum[w] = s;
    __syncthreads();
    if (t < 16) {
        int wv = wsum[t];
        int ss = wv;
#pragma unroll
        for (int d = 1; d < 16; d <<= 1) {
            int o = __shfl_up(ss, d, 16);
            if (t >= d) ss += o;
        }
        wexcl[t] = ss - wv;
    }
    __syncthreads();
    if (i < NN) {
        int o = bsum[blockIdx.x] + (s - v) + wexcl[w];
        offs[i] = o;
        cursor[i] = o;
        invd[i] = v > 0 ? 1.f / (float)v : 0.f;  // DGL mean: zero-degree -> 0
    }
}

__global__ void k_fill(const int* __restrict__ src, const int* __restrict__ dst,
                       int* __restrict__ cursor, int* __restrict__ eidsrc) {
    int e = blockIdx.x * 256 + threadIdx.x;
    if (e < EE) {
        int pos = atomicAdd(&cursor[dst[e]], 1);
        eidsrc[pos] = src[e];
    }
}

// ---------------------------------------------------------------------------
// fp32 -> bf16 bulk convert (8 elems/thread)
// ---------------------------------------------------------------------------
__global__ void k_f2bf(const float* __restrict__ in, short* __restrict__ out, int n8) {
    int i = blockIdx.x * 256 + threadIdx.x;
    if (i >= n8) return;
    float4 a = ((const float4*)in)[i * 2];
    float4 b = ((const float4*)in)[i * 2 + 1];
    short8 o;
    o[0] = f2bf(a.x); o[1] = f2bf(a.y); o[2] = f2bf(a.z); o[3] = f2bf(a.w);
    o[4] = f2bf(b.x); o[5] = f2bf(b.y); o[6] = f2bf(b.z); o[7] = f2bf(b.w);
    ((short8*)out)[i] = o;
}

// ---------------------------------------------------------------------------
// bf16 CSR mean-aggregation: F/8 lanes per node, 16 B (8 cols) per lane,
// fp32 accum, 8-deep unrolled -> 8 KB/wave outstanding (deg~16 => 2 iters).
// ---------------------------------------------------------------------------
template <int F>
__global__ __launch_bounds__(256) void k_gather_bf(
    const short* __restrict__ hbsrc, const int* __restrict__ offs,
    const int* __restrict__ eidsrc, const float* __restrict__ invd,
    short* __restrict__ aggb) {
    constexpr int G = F / 8;  // lanes per node
    int gid = blockIdx.x * 256 + threadIdx.x;
    int node = gid / G;
    int sub = gid % G;
    if (node >= NN) return;
    int beg = offs[node], end = offs[node + 1];
    float iv = invd[node];
    float s[8] = {0.f, 0.f, 0.f, 0.f, 0.f, 0.f, 0.f, 0.f};
    const size_t co = (size_t)sub * 8;
    int p = beg;
    for (; p + 8 <= end; p += 8) {
        int idx[8];
#pragma unroll
        for (int q = 0; q < 8; ++q) idx[q] = eidsrc[p + q];
        short8 r[8];
#pragma unroll
        for (int q = 0; q < 8; ++q)
            r[q] = *(const short8*)(hbsrc + (size_t)idx[q] * F + co);
#pragma unroll
        for (int q = 0; q < 8; ++q)
#pragma unroll
            for (int j = 0; j < 8; ++j) s[j] += bf2f(r[q][j]);
    }
    for (; p + 4 <= end; p += 4) {
        int i0 = eidsrc[p], i1 = eidsrc[p + 1], i2 = eidsrc[p + 2], i3 = eidsrc[p + 3];
        short8 r0 = *(const short8*)(hbsrc + (size_t)i0 * F + co);
        short8 r1 = *(const short8*)(hbsrc + (size_t)i1 * F + co);
        short8 r2 = *(const short8*)(hbsrc + (size_t)i2 * F + co);
        short8 r3 = *(const short8*)(hbsrc + (size_t)i3 * F + co);
#pragma unroll
        for (int j = 0; j < 8; ++j)
            s[j] += (bf2f(r0[j]) + bf2f(r1[j])) + (bf2f(r2[j]) + bf2f(r3[j]));
    }
    for (; p < end; ++p) {
        short8 r = *(const short8*)(hbsrc + (size_t)eidsrc[p] * F + co);
#pragma unroll
        for (int j = 0; j < 8; ++j) s[j] += bf2f(r[j]);
    }
    short8 o;
#pragma unroll
    for (int j = 0; j < 8; ++j) o[j] = f2bf(s[j] * iv);
    *(short8*)(aggb + (size_t)node * F + co) = o;
}

// ---------------------------------------------------------------------------
// Unified weight pre-pack into bf16 MFMA-B fragment order.
// slot = cb*64 + bp*16 + n, elem j; content = W[k][16*cb+n], gk = k + kbase,
// kc = gk>>5, bp = (gk&31)>>3, j = gk&7.
// ---------------------------------------------------------------------------
__device__ __forceinline__ void packW(const float* W, short* Wp, int local, int kbase) {
    int k = local >> 7, col = local & 127;
    int gk = k + kbase;
    int kc = gk >> 5, kw = gk & 31, bp = kw >> 3, j = kw & 7;
    int cb = col >> 4, n = col & 15;
    Wp[kc * 4096 + (cb * 64 + bp * 16 + n) * 8 + j] = f2bf(W[k * 128 + col]);
}

__global__ void k_pack_all(const float* __restrict__ We1, const float* __restrict__ Ws1,
                           const float* __restrict__ Wn1, const float* __restrict__ Ws2,
                           const float* __restrict__ Wn2, const float* __restrict__ We2,
                           short* __restrict__ Wp_e, short* __restrict__ Wp1,
                           short* __restrict__ Wp2, short* __restrict__ Wp2e) {
    int idx = blockIdx.x * 256 + threadIdx.x;
    if (idx < 40960) {
        packW(We1, Wp_e, idx, 0);
    } else if (idx < 49152) {
        packW(Ws1, Wp1, idx - 40960, 0);
    } else if (idx < 57344) {
        packW(Wn1, Wp1, idx - 49152, 64);
    } else if (idx < 73728) {
        packW(Ws2, Wp2, idx - 57344, 0);
    } else if (idx < 90112) {
        packW(Wn2, Wp2, idx - 73728, 128);
    } else if (idx < 92160) {
        int local = idx - 90112;  // over 128 k x 16 n
        int k = local >> 4, n = local & 15;
        float val = (n < 8) ? We2[k * 8 + n] : 0.f;
        int kc2 = k >> 5, kl = k & 31, bp = kl >> 3, j = kl & 7;
        Wp2e[(kc2 * 64 + bp * 16 + n) * 8 + j] = f2bf(val);
    }
}

// ---------------------------------------------------------------------------
// bf16 MFMA node GEMM, 2-phase double-buffered staging, fused col-stats.
// outf[N,128] = [A1b | A2b] @ Wp + bias; stats[0:128)=colsum, [128:256)=colsumsq
// ---------------------------------------------------------------------------
template <int KC1, int KC2>
__global__ __launch_bounds__(256) void k_node_mfma(
    const short* __restrict__ A1, const short* __restrict__ A2,
    const short* __restrict__ Wp, const float* __restrict__ bias,
    float* __restrict__ outf, float* __restrict__ stats) {
    __shared__ __align__(16) short sbuf[16384];  // A0|B0|A1|B1, 4096 each
    __shared__ float bs[128];
    __shared__ float reds[4][128], redss[4][128];
    const int t = threadIdx.x;
    if (t < 128) bs[t] = bias[t];
    const int rowbase = blockIdx.x * 128;
    const int lane = t & 63, w = t >> 6;
    const int fo = (lane >> 4) * 16 + (lane & 15);

    auto NSTAGE = [&](int kc, short* Ad, short* Bd) {
        const short* src;
        int kst, kloc;
        if (kc < KC1) { src = A1; kst = KC1 * 32; kloc = kc * 32; }
        else          { src = A2; kst = KC2 * 32; kloc = (kc - KC1) * 32; }
#pragma unroll
        for (int p = 0; p < 2; ++p) {
            int s = t + p * 256;
            int b = (s >> 4) & 3;
            int row = rowbase + ((s >> 6) << 4) + (s & 15);
            gload_lds16(src + (size_t)row * kst + kloc + b * 8, Ad + s * 8);
            gload_lds16(Wp + (size_t)kc * 4096 + s * 8, Bd + s * 8);
        }
    };

    f32x4 acc[2][8];
#pragma unroll
    for (int i = 0; i < 2; ++i)
#pragma unroll
        for (int j = 0; j < 8; ++j) acc[i][j] = (f32x4){0.f, 0.f, 0.f, 0.f};

    constexpr int KC = KC1 + KC2;
    NSTAGE(0, sbuf, sbuf + 4096);
    __syncthreads();
    for (int kc = 0; kc < KC; ++kc) {
        const int cur = kc & 1;
        short* Ac = sbuf + (cur ? 8192 : 0);
        short* Bc = Ac + 4096;
        if (kc + 1 < KC) {
            short* An = sbuf + (cur ? 0 : 8192);
            NSTAGE(kc + 1, An, An + 4096);  // async, overlaps MFMA below
        }
        short8 a0 = *(const short8*)(Ac + (2 * w * 64 + fo) * 8);
        short8 a1 = *(const short8*)(Ac + ((2 * w + 1) * 64 + fo) * 8);
#pragma unroll
        for (int cb = 0; cb < 8; ++cb) {
            short8 bfr = *(const short8*)(Bc + (cb * 64 + fo) * 8);
            acc[0][cb] = __builtin_amdgcn_mfma_f32_16x16x32_bf16(a0, bfr, acc[0][cb], 0, 0, 0);
            acc[1][cb] = __builtin_amdgcn_mfma_f32_16x16x32_bf16(a1, bfr, acc[1][cb], 0, 0, 0);
        }
        __syncthreads();
    }

    // epilogue: bias-add, store, per-column partial stats
    float cs[8], css[8];
#pragma unroll
    for (int cb = 0; cb < 8; ++cb) { cs[cb] = 0.f; css[cb] = 0.f; }
#pragma unroll
    for (int rb2 = 0; rb2 < 2; ++rb2) {
        int rloc = 32 * w + rb2 * 16 + ((lane >> 4) << 2);
#pragma unroll
        for (int cb = 0; cb < 8; ++cb) {
            int col = cb * 16 + (lane & 15);
            float bb = bs[col];
#pragma unroll
            for (int i = 0; i < 4; ++i) {
                int row = rowbase + rloc + i;
                if (row < NN) {
                    float v = acc[rb2][cb][i] + bb;
                    outf[(size_t)row * 128 + col] = v;
                    cs[cb] += v;
                    css[cb] += v * v;
                }
            }
        }
    }
#pragma unroll
    for (int cb = 0; cb < 8; ++cb) {
        cs[cb] += __shfl_xor(cs[cb], 16);
        cs[cb] += __shfl_xor(cs[cb], 32);
        css[cb] += __shfl_xor(css[cb], 16);
        css[cb] += __shfl_xor(css[cb], 32);
    }
    if (lane < 16) {
#pragma unroll
        for (int cb = 0; cb < 8; ++cb) {
            reds[w][cb * 16 + lane] = cs[cb];
            redss[w][cb * 16 + lane] = css[cb];
        }
    }
    __syncthreads();
    if (t < 128) {
        atomicAdd(&stats[t], reds[0][t] + reds[1][t] + reds[2][t] + reds[3][t]);
    } else {
        int c = t - 128;
        atomicAdd(&stats[128 + c], redss[0][c] + redss[1][c] + redss[2][c] + redss[3][c]);
    }
}

// BN + ReLU + convert to bf16; scale/shift computed once per block in LDS.
__global__ void k_bnrelu_bf16(const float* __restrict__ h, const float* __restrict__ stats,
                              const float* __restrict__ g, const float* __restrict__ bt,
                              short* __restrict__ hb) {
    __shared__ float a_sh[128], b_sh[128];
    const int t = threadIdx.x;
    if (t < 128) {
        float mu = stats[t] * (1.f / NN);
        float var = stats[128 + t] * (1.f / NN) - mu * mu;  // biased (matches ref)
        float a = g[t] * rsqrtf(var + BN_EPS);
        a_sh[t] = a;
        b_sh[t] = bt[t] - mu * a;
    }
    __syncthreads();
    int gid = blockIdx.x * 256 + t;  // over NN*16 groups of 8
    if (gid >= NN * 16) return;
    int c0 = (gid & 15) * 8;
    float4 v0 = reinterpret_cast<const float4*>(h)[gid * 2];
    float4 v1 = reinterpret_cast<const float4*>(h)[gid * 2 + 1];
    short8 o;
    o[0] = f2bf(fmaxf(fmaf(a_sh[c0 + 0], v0.x, b_sh[c0 + 0]), 0.f));
    o[1] = f2bf(fmaxf(fmaf(a_sh[c0 + 1], v0.y, b_sh[c0 + 1]), 0.f));
    o[2] = f2bf(fmaxf(fmaf(a_sh[c0 + 2], v0.z, b_sh[c0 + 2]), 0.f));
    o[3] = f2bf(fmaxf(fmaf(a_sh[c0 + 3], v0.w, b_sh[c0 + 3]), 0.f));
    o[4] = f2bf(fmaxf(fmaf(a_sh[c0 + 4], v1.x, b_sh[c0 + 4]), 0.f));
    o[5] = f2bf(fmaxf(fmaf(a_sh[c0 + 5], v1.y, b_sh[c0 + 5]), 0.f));
    o[6] = f2bf(fmaxf(fmaf(a_sh[c0 + 6], v1.z, b_sh[c0 + 6]), 0.f));
    o[7] = f2bf(fmaxf(fmaf(a_sh[c0 + 7], v1.w, b_sh[c0 + 7]), 0.f));
    reinterpret_cast<short8*>(hb)[gid] = o;
}

// ---------------------------------------------------------------------------
// MFMA edge MLP: R5 structure + ONLY double-buffered staging added (clean A/B
// vs R6: no ef register preload, no extra live state). 128 edges/block.
// ---------------------------------------------------------------------------
__global__ __launch_bounds__(256) void k_edge_mfma(
    const short* __restrict__ hb, const float* __restrict__ ef,
    const short* __restrict__ Wp, const short* __restrict__ Wp2e,
    const float* __restrict__ be1, const float* __restrict__ be2,
    const int* __restrict__ uu, const int* __restrict__ vv,
    float* __restrict__ out) {
    // 34816 B: staging A0|B0|A1|B1 (32768 B) ∪ Hid[128][136]
    __shared__ __align__(16) short smem[17408];
    __shared__ float be1s[128];
    __shared__ int suv[256];
    const int t = threadIdx.x;
    const int eb = blockIdx.x * 128;
    if (t < 128) {
        suv[t] = uu[eb + t];
        suv[128 + t] = vv[eb + t];
        be1s[t] = be1[t];
    }
    __syncthreads();

    const int lane = t & 63, w = t >> 6;
    const int fo = (lane >> 4) * 16 + (lane & 15);
    const int srow = t >> 1;      // ef-staging row
    const int sb0 = (t & 1) * 2;  // ef-staging k-subblock base
    const int sslotbase = (srow >> 4) * 64 + (srow & 15);

    // preload layer-2 B-frags (4 KB, L2-resident) — present in R5 too
    short8 b2f[4];
#pragma unroll
    for (int kc2 = 0; kc2 < 4; ++kc2)
        b2f[kc2] = *(const short8*)(Wp2e + (kc2 * 64 + fo) * 8);

    auto STAGE = [&](int kc, short* Ad, short* Bd) {
        if (kc < 8) {
#pragma unroll
            for (int p = 0; p < 2; ++p) {
                int s = t + p * 256;
                int b = (s >> 4) & 3;
                int row = ((s >> 6) << 4) + (s & 15);
                const short* gsrc =
                    hb + (size_t)suv[(kc >= 4) * 128 + row] * 128 + (kc & 3) * 32 + b * 8;
                gload_lds16(gsrc, Ad + s * 8);
            }
        } else {
            const float* er = ef + (size_t)(eb + srow) * 64 + (kc - 8) * 32;
#pragma unroll
            for (int p = 0; p < 2; ++p) {
                int b = sb0 + p;
                float4 f0 = *(const float4*)(er + b * 8);
                float4 f1 = *(const float4*)(er + b * 8 + 4);
                short8 v8;
                v8[0] = f2bf(f0.x); v8[1] = f2bf(f0.y);
                v8[2] = f2bf(f0.z); v8[3] = f2bf(f0.w);
                v8[4] = f2bf(f1.x); v8[5] = f2bf(f1.y);
                v8[6] = f2bf(f1.z); v8[7] = f2bf(f1.w);
                *(short8*)(Ad + (sslotbase + b * 16) * 8) = v8;
            }
        }
#pragma unroll
        for (int p = 0; p < 2; ++p) {
            int s = t + p * 256;
            gload_lds16(Wp + (size_t)kc * 4096 + s * 8, Bd + s * 8);
        }
    };

    f32x4 acc[2][8];
#pragma unroll
    for (int i = 0; i < 2; ++i)
#pragma unroll
        for (int j = 0; j < 8; ++j) acc[i][j] = (f32x4){0.f, 0.f, 0.f, 0.f};

    STAGE(0, smem, smem + 4096);
    __syncthreads();
    for (int kc = 0; kc < 10; ++kc) {
        short* Ac = smem + (kc & 1) * 8192;
        short* Bc = Ac + 4096;
        if (kc < 9) {
            short* An = smem + ((kc + 1) & 1) * 8192;
            STAGE(kc + 1, An, An + 4096);  // async, overlaps frag reads + MFMA
        }
        short8 afr0 = *(const short8*)(Ac + ((2 * w) * 64 + fo) * 8);
        short8 afr1 = *(const short8*)(Ac + ((2 * w + 1) * 64 + fo) * 8);
#pragma unroll
        for (int cb = 0; cb < 8; ++cb) {
            short8 bfr = *(const short8*)(Bc + (cb * 64 + fo) * 8);
            acc[0][cb] = __builtin_amdgcn_mfma_f32_16x16x32_bf16(afr0, bfr, acc[0][cb], 0, 0, 0);
            acc[1][cb] = __builtin_amdgcn_mfma_f32_16x16x32_bf16(afr1, bfr, acc[1][cb], 0, 0, 0);
        }
        __syncthreads();
    }

    // ---- epilogue 1: bias + relu -> Hid[128][136] bf16 (reuses stage region) ----
    short* Hid = smem;
#pragma unroll
    for (int rb2 = 0; rb2 < 2; ++rb2)
#pragma unroll
        for (int cb = 0; cb < 8; ++cb) {
            int col = cb * 16 + (lane & 15);
            int rbase = 32 * w + rb2 * 16 + ((lane >> 4) << 2);
            float bb = be1s[col];
#pragma unroll
            for (int i = 0; i < 4; ++i)
                Hid[(rbase + i) * 136 + col] = f2bf(fmaxf(acc[rb2][cb][i] + bb, 0.f));
        }
    __syncthreads();

    // ---- layer 2 via MFMA: out[e][0..7] = Hid @ We2p + be2 ----
#pragma unroll
    for (int rf = 0; rf < 2; ++rf) {
        f32x4 a2 = (f32x4){0.f, 0.f, 0.f, 0.f};
        const int rbl = 32 * w + 16 * rf + (lane & 15);
#pragma unroll
        for (int kc2 = 0; kc2 < 4; ++kc2) {
            short8 af = *(const short8*)(Hid + rbl * 136 + kc2 * 32 + 8 * (lane >> 4));
            a2 = __builtin_amdgcn_mfma_f32_16x16x32_bf16(af, b2f[kc2], a2, 0, 0, 0);
        }
        int col = lane & 15;
        if (col < 8) {
            int r0 = eb + 32 * w + 16 * rf + 4 * (lane >> 4);
            float bb = be2[col];
#pragma unroll
            for (int i = 0; i < 4; ++i)
                out[(size_t)(r0 + i) * 8 + col] = a2[i] + bb;
        }
    }
}

// ---------------------------------------------------------------------------
extern "C" void kernel_launch(void* const* d_in, const int* in_sizes, int n_in,
                              void* d_out, int out_size, void* d_ws, size_t ws_size,
                              hipStream_t stream) {
    const float* x   = (const float*)d_in[0];
    const float* ef  = (const float*)d_in[1];
    const float* Ws1 = (const float*)d_in[2];
    const float* Wn1 = (const float*)d_in[3];
    const float* b1  = (const float*)d_in[4];
    const float* g1  = (const float*)d_in[5];
    const float* bt1 = (const float*)d_in[6];
    const float* Ws2 = (const float*)d_in[7];
    const float* Wn2 = (const float*)d_in[8];
    const float* b2  = (const float*)d_in[9];
    const float* g2  = (const float*)d_in[10];
    const float* bt2 = (const float*)d_in[11];
    const float* We1 = (const float*)d_in[12];
    const float* be1 = (const float*)d_in[13];
    const float* We2 = (const float*)d_in[14];
    const float* be2 = (const float*)d_in[15];
    const int* src = (const int*)d_in[16];
    const int* dst = (const int*)d_in[17];
    const int* u   = (const int*)d_in[18];
    const int* v   = (const int*)d_in[19];
    float* out = (float*)d_out;

    // Workspace (~85 MB). h1/h2 fp32 live in d_out (N*128 == out_size).
    // hb aliases xb+agg1b (dead after layer-1 GEMM; contiguous 25.6 MB).
    char* p = (char*)d_ws;
    auto take = [&](size_t bytes) {
        char* r = p;
        p += (bytes + 255) & ~(size_t)255;
        return r;
    };
    int* cnt     = (int*)take(NN * 4);       // adjacent to stats: one memset
    float* stats = (float*)take(512 * 4);    // [0:256)=layer1, [256:512)=layer2
    float* invd  = (float*)take(NN * 4);
    int* offs    = (int*)take((NN + 1) * 4);
    int* cursor  = (int*)take(NN * 4);
    int* bsum    = (int*)take(128 * 4);
    int* eidsrc  = (int*)take((size_t)EE * 4);
    short* Wp_e  = (short*)take(320 * 128 * 2);
    short* Wp1   = (short*)take(128 * 128 * 2);
    short* Wp2   = (short*)take(256 * 128 * 2);
    short* Wp2e  = (short*)take(256 * 8 * 2);
    short* xb    = (short*)take((size_t)NN * 64 * 2);
    short* agg1b = (short*)take((size_t)NN * 64 * 2);
    short* h1b   = (short*)take((size_t)NN * 128 * 2);
    short* agg2b = (short*)take((size_t)NN * 128 * 2);
    take(65536);  // pad: node GEMMs read up to ~25 KB past last row
    float* h1 = out;
    float* h2 = out;
    short* hb = xb;  // 25.6 MB union of xb+agg1b

    const int NB = (NN + 1023) / 1024;  // 98 scan blocks

    // ---- CSR build + weight pre-pack + x -> bf16 ----
    hipMemsetAsync(cnt, 0, ((char*)stats - (char*)cnt) + 512 * 4, stream);
    k_count<<<(EE + 255) / 256, 256, 0, stream>>>(dst, cnt);
    k_scan_part<<<NB, 1024, 0, stream>>>(cnt, bsum);
    k_scan_base<<<1, 64, 0, stream>>>(bsum, offs, NB);
    k_scan_final<<<NB, 1024, 0, stream>>>(cnt, bsum, offs, cursor, invd);
    k_fill<<<(EE + 255) / 256, 256, 0, stream>>>(src, dst, cursor, eidsrc);
    k_pack_all<<<360, 256, 0, stream>>>(We1, Ws1, Wn1, Ws2, Wn2, We2, Wp_e, Wp1, Wp2, Wp2e);
    k_f2bf<<<(NN * 8 + 255) / 256, 256, 0, stream>>>(x, xb, NN * 8);

    // ---- layer 1 (bf16 inputs, fp32 accum/stats; stats fused in GEMM) ----
    k_gather_bf<64><<<(NN * 8 + 255) / 256, 256, 0, stream>>>(xb, offs, eidsrc, invd, agg1b);
    k_node_mfma<2, 2><<<(NN + 127) / 128, 256, 0, stream>>>(xb, agg1b, Wp1, b1, h1, stats);
    k_bnrelu_bf16<<<(NN * 16 + 255) / 256, 256, 0, stream>>>(h1, stats, g1, bt1, h1b);

    // ---- layer 2 ----
    k_gather_bf<128><<<(NN * 16 + 255) / 256, 256, 0, stream>>>(h1b, offs, eidsrc, invd, agg2b);
    k_node_mfma<4, 4><<<(NN + 127) / 128, 256, 0, stream>>>(h1b, agg2b, Wp2, b2, h2, stats + 256);
    k_bnrelu_bf16<<<(NN * 16 + 255) / 256, 256, 0, stream>>>(h2, stats + 256, g2, bt2, hb);

    // ---- edge head (bf16 MFMA, 2-phase double-buffered staging) ----
    k_edge_mfma<<<EE / 128, 256, 0, stream>>>(hb, ef, Wp_e, Wp2e, be1, be2, u, v, out);
}

// Round 9
// 647.311 us; speedup vs baseline: 10.7431x; 1.0139x over previous
//
#include <hip/hip_runtime.h>

// Problem constants (fixed by the reference).
#define NN 100000
#define EE 1600000
// D_IN=64, H=128, E_IN=64, C=8
constexpr float BN_EPS = 1e-5f;

typedef __attribute__((ext_vector_type(8))) short short8;
typedef __attribute__((ext_vector_type(4))) float f32x4;

__device__ __forceinline__ short f2bf(float f) {  // RNE f32 -> bf16
    unsigned u = __float_as_uint(f);
    u += 0x7fff + ((u >> 16) & 1);
    return (short)(u >> 16);
}
__device__ __forceinline__ float bf2f(short s) {
    return __uint_as_float(((unsigned)(unsigned short)s) << 16);
}

// async global->LDS DMA, 16 B per lane. LDS dest must be base + lane*16
// within each wave (guaranteed by construction at all call sites).
typedef __attribute__((address_space(1))) const unsigned int guint;
typedef __attribute__((address_space(3))) unsigned int luint;
__device__ __forceinline__ void gload_lds16(const void* g, void* l) {
    __builtin_amdgcn_global_load_lds((guint*)g, (luint*)l, 16, 0, 0);
}

// ---------------------------------------------------------------------------
// CSR build: count -> 3-stage parallel scan -> fill
// ---------------------------------------------------------------------------
__global__ void k_count(const int* __restrict__ dst, int* __restrict__ cnt) {
    int e = blockIdx.x * 256 + threadIdx.x;
    if (e < EE) atomicAdd(&cnt[dst[e]], 1);
}

// stage 1: per-1024-block sums
__global__ __launch_bounds__(1024) void k_scan_part(const int* __restrict__ cnt,
                                                    int* __restrict__ bsum) {
    const int t = threadIdx.x, lane = t & 63, w = t >> 6;
    int i = blockIdx.x * 1024 + t;
    int v = (i < NN) ? cnt[i] : 0;
#pragma unroll
    for (int d = 1; d < 64; d <<= 1) v += __shfl_xor(v, d, 64);
    __shared__ int ws[16];
    if (lane == 0) ws[w] = v;
    __syncthreads();
    if (t == 0) {
        int s = 0;
#pragma unroll
        for (int k = 0; k < 16; ++k) s += ws[k];
        bsum[blockIdx.x] = s;
    }
}

// stage 2: exclusive scan of the 98 block sums (single thread; tiny)
__global__ void k_scan_base(int* __restrict__ bsum, int* __restrict__ offs, int nb) {
    if (threadIdx.x == 0) {
        int run = 0;
        for (int k = 0; k < nb; ++k) {
            int v = bsum[k];
            bsum[k] = run;
            run += v;
        }
        offs[NN] = run;
    }
}

// stage 3: local exclusive scan + base; emits offs, cursor, invd
__global__ __launch_bounds__(1024) void k_scan_final(const int* __restrict__ cnt,
                                                     const int* __restrict__ bsum,
                                                     int* __restrict__ offs,
                                                     int* __restrict__ cursor,
                                                     float* __restrict__ invd) {
    const int t = threadIdx.x, lane = t & 63, w = t >> 6;
    __shared__ int wsum[16], wexcl[16];
    int i = blockIdx.x * 1024 + t;
    int v = (i < NN) ? cnt[i] : 0;
    int s = v;
#pragma unroll
    for (int d = 1; d < 64; d <<= 1) {
        int o = __shfl_up(s, d, 64);
        if (lane >= d) s += o;
    }
    if (lane == 63) wsum[w] = s;
    __syncthreads();
    if (t < 16) {
        int wv = wsum[t];
        int ss = wv;
#pragma unroll
        for (int d = 1; d < 16; d <<= 1) {
            int o = __shfl_up(ss, d, 16);
            if (t >= d) ss += o;
        }
        wexcl[t] = ss - wv;
    }
    __syncthreads();
    if (i < NN) {
        int o = bsum[blockIdx.x] + (s - v) + wexcl[w];
        offs[i] = o;
        cursor[i] = o;
        invd[i] = v > 0 ? 1.f / (float)v : 0.f;  // DGL mean: zero-degree -> 0
    }
}

__global__ void k_fill(const int* __restrict__ src, const int* __restrict__ dst,
                       int* __restrict__ cursor, int* __restrict__ eidsrc) {
    int e = blockIdx.x * 256 + threadIdx.x;
    if (e < EE) {
        int pos = atomicAdd(&cursor[dst[e]], 1);
        eidsrc[pos] = src[e];
    }
}

// ---------------------------------------------------------------------------
// fp32 -> bf16 bulk convert (8 elems/thread)
// ---------------------------------------------------------------------------
__global__ void k_f2bf(const float* __restrict__ in, short* __restrict__ out, int n8) {
    int i = blockIdx.x * 256 + threadIdx.x;
    if (i >= n8) return;
    float4 a = ((const float4*)in)[i * 2];
    float4 b = ((const float4*)in)[i * 2 + 1];
    short8 o;
    o[0] = f2bf(a.x); o[1] = f2bf(a.y); o[2] = f2bf(a.z); o[3] = f2bf(a.w);
    o[4] = f2bf(b.x); o[5] = f2bf(b.y); o[6] = f2bf(b.z); o[7] = f2bf(b.w);
    ((short8*)out)[i] = o;
}

// ---------------------------------------------------------------------------
// bf16 CSR mean-aggregation: F/8 lanes per node, 16 B (8 cols) per lane,
// fp32 accum, 8-deep unrolled.
// ---------------------------------------------------------------------------
template <int F>
__global__ __launch_bounds__(256) void k_gather_bf(
    const short* __restrict__ hbsrc, const int* __restrict__ offs,
    const int* __restrict__ eidsrc, const float* __restrict__ invd,
    short* __restrict__ aggb) {
    constexpr int G = F / 8;  // lanes per node
    int gid = blockIdx.x * 256 + threadIdx.x;
    int node = gid / G;
    int sub = gid % G;
    if (node >= NN) return;
    int beg = offs[node], end = offs[node + 1];
    float iv = invd[node];
    float s[8] = {0.f, 0.f, 0.f, 0.f, 0.f, 0.f, 0.f, 0.f};
    const size_t co = (size_t)sub * 8;
    int p = beg;
    for (; p + 8 <= end; p += 8) {
        int idx[8];
#pragma unroll
        for (int q = 0; q < 8; ++q) idx[q] = eidsrc[p + q];
        short8 r[8];
#pragma unroll
        for (int q = 0; q < 8; ++q)
            r[q] = *(const short8*)(hbsrc + (size_t)idx[q] * F + co);
#pragma unroll
        for (int q = 0; q < 8; ++q)
#pragma unroll
            for (int j = 0; j < 8; ++j) s[j] += bf2f(r[q][j]);
    }
    for (; p + 4 <= end; p += 4) {
        int i0 = eidsrc[p], i1 = eidsrc[p + 1], i2 = eidsrc[p + 2], i3 = eidsrc[p + 3];
        short8 r0 = *(const short8*)(hbsrc + (size_t)i0 * F + co);
        short8 r1 = *(const short8*)(hbsrc + (size_t)i1 * F + co);
        short8 r2 = *(const short8*)(hbsrc + (size_t)i2 * F + co);
        short8 r3 = *(const short8*)(hbsrc + (size_t)i3 * F + co);
#pragma unroll
        for (int j = 0; j < 8; ++j)
            s[j] += (bf2f(r0[j]) + bf2f(r1[j])) + (bf2f(r2[j]) + bf2f(r3[j]));
    }
    for (; p < end; ++p) {
        short8 r = *(const short8*)(hbsrc + (size_t)eidsrc[p] * F + co);
#pragma unroll
        for (int j = 0; j < 8; ++j) s[j] += bf2f(r[j]);
    }
    short8 o;
#pragma unroll
    for (int j = 0; j < 8; ++j) o[j] = f2bf(s[j] * iv);
    *(short8*)(aggb + (size_t)node * F + co) = o;
}

// ---------------------------------------------------------------------------
// Unified weight pre-pack into bf16 MFMA-B fragment order.
// ---------------------------------------------------------------------------
__device__ __forceinline__ void packW(const float* W, short* Wp, int local, int kbase) {
    int k = local >> 7, col = local & 127;
    int gk = k + kbase;
    int kc = gk >> 5, kw = gk & 31, bp = kw >> 3, j = kw & 7;
    int cb = col >> 4, n = col & 15;
    Wp[kc * 4096 + (cb * 64 + bp * 16 + n) * 8 + j] = f2bf(W[k * 128 + col]);
}

__global__ void k_pack_all(const float* __restrict__ We1, const float* __restrict__ Ws1,
                           const float* __restrict__ Wn1, const float* __restrict__ Ws2,
                           const float* __restrict__ Wn2, const float* __restrict__ We2,
                           short* __restrict__ Wp_e, short* __restrict__ Wp1,
                           short* __restrict__ Wp2, short* __restrict__ Wp2e) {
    int idx = blockIdx.x * 256 + threadIdx.x;
    if (idx < 40960) {
        packW(We1, Wp_e, idx, 0);
    } else if (idx < 49152) {
        packW(Ws1, Wp1, idx - 40960, 0);
    } else if (idx < 57344) {
        packW(Wn1, Wp1, idx - 49152, 64);
    } else if (idx < 73728) {
        packW(Ws2, Wp2, idx - 57344, 0);
    } else if (idx < 90112) {
        packW(Wn2, Wp2, idx - 73728, 128);
    } else if (idx < 92160) {
        int local = idx - 90112;  // over 128 k x 16 n
        int k = local >> 4, n = local & 15;
        float val = (n < 8) ? We2[k * 8 + n] : 0.f;
        int kc2 = k >> 5, kl = k & 31, bp = kl >> 3, j = kl & 7;
        Wp2e[(kc2 * 64 + bp * 16 + n) * 8 + j] = f2bf(val);
    }
}

// ---------------------------------------------------------------------------
// bf16 MFMA node GEMM, 2-phase double-buffered staging, fused col-stats.
// ---------------------------------------------------------------------------
template <int KC1, int KC2>
__global__ __launch_bounds__(256) void k_node_mfma(
    const short* __restrict__ A1, const short* __restrict__ A2,
    const short* __restrict__ Wp, const float* __restrict__ bias,
    float* __restrict__ outf, float* __restrict__ stats) {
    __shared__ __align__(16) short sbuf[16384];  // A0|B0|A1|B1, 4096 each
    __shared__ float bs[128];
    __shared__ float reds[4][128], redss[4][128];
    const int t = threadIdx.x;
    if (t < 128) bs[t] = bias[t];
    const int rowbase = blockIdx.x * 128;
    const int lane = t & 63, w = t >> 6;
    const int fo = (lane >> 4) * 16 + (lane & 15);

    auto NSTAGE = [&](int kc, short* Ad, short* Bd) {
        const short* src;
        int kst, kloc;
        if (kc < KC1) { src = A1; kst = KC1 * 32; kloc = kc * 32; }
        else          { src = A2; kst = KC2 * 32; kloc = (kc - KC1) * 32; }
#pragma unroll
        for (int p = 0; p < 2; ++p) {
            int s = t + p * 256;
            int b = (s >> 4) & 3;
            int row = rowbase + ((s >> 6) << 4) + (s & 15);
            gload_lds16(src + (size_t)row * kst + kloc + b * 8, Ad + s * 8);
            gload_lds16(Wp + (size_t)kc * 4096 + s * 8, Bd + s * 8);
        }
    };

    f32x4 acc[2][8];
#pragma unroll
    for (int i = 0; i < 2; ++i)
#pragma unroll
        for (int j = 0; j < 8; ++j) acc[i][j] = (f32x4){0.f, 0.f, 0.f, 0.f};

    constexpr int KC = KC1 + KC2;
    NSTAGE(0, sbuf, sbuf + 4096);
    __syncthreads();
    for (int kc = 0; kc < KC; ++kc) {
        const int cur = kc & 1;
        short* Ac = sbuf + (cur ? 8192 : 0);
        short* Bc = Ac + 4096;
        if (kc + 1 < KC) {
            short* An = sbuf + (cur ? 0 : 8192);
            NSTAGE(kc + 1, An, An + 4096);  // async, overlaps MFMA below
        }
        short8 a0 = *(const short8*)(Ac + (2 * w * 64 + fo) * 8);
        short8 a1 = *(const short8*)(Ac + ((2 * w + 1) * 64 + fo) * 8);
#pragma unroll
        for (int cb = 0; cb < 8; ++cb) {
            short8 bfr = *(const short8*)(Bc + (cb * 64 + fo) * 8);
            acc[0][cb] = __builtin_amdgcn_mfma_f32_16x16x32_bf16(a0, bfr, acc[0][cb], 0, 0, 0);
            acc[1][cb] = __builtin_amdgcn_mfma_f32_16x16x32_bf16(a1, bfr, acc[1][cb], 0, 0, 0);
        }
        __syncthreads();
    }

    // epilogue: bias-add, store, per-column partial stats
    float cs[8], css[8];
#pragma unroll
    for (int cb = 0; cb < 8; ++cb) { cs[cb] = 0.f; css[cb] = 0.f; }
#pragma unroll
    for (int rb2 = 0; rb2 < 2; ++rb2) {
        int rloc = 32 * w + rb2 * 16 + ((lane >> 4) << 2);
#pragma unroll
        for (int cb = 0; cb < 8; ++cb) {
            int col = cb * 16 + (lane & 15);
            float bb = bs[col];
#pragma unroll
            for (int i = 0; i < 4; ++i) {
                int row = rowbase + rloc + i;
                if (row < NN) {
                    float v = acc[rb2][cb][i] + bb;
                    outf[(size_t)row * 128 + col] = v;
                    cs[cb] += v;
                    css[cb] += v * v;
                }
            }
        }
    }
#pragma unroll
    for (int cb = 0; cb < 8; ++cb) {
        cs[cb] += __shfl_xor(cs[cb], 16);
        cs[cb] += __shfl_xor(cs[cb], 32);
        css[cb] += __shfl_xor(css[cb], 16);
        css[cb] += __shfl_xor(css[cb], 32);
    }
    if (lane < 16) {
#pragma unroll
        for (int cb = 0; cb < 8; ++cb) {
            reds[w][cb * 16 + lane] = cs[cb];
            redss[w][cb * 16 + lane] = css[cb];
        }
    }
    __syncthreads();
    if (t < 128) {
        atomicAdd(&stats[t], reds[0][t] + reds[1][t] + reds[2][t] + reds[3][t]);
    } else {
        int c = t - 128;
        atomicAdd(&stats[128 + c], redss[0][c] + redss[1][c] + redss[2][c] + redss[3][c]);
    }
}

// BN + ReLU + convert to bf16; scale/shift computed once per block in LDS.
__global__ void k_bnrelu_bf16(const float* __restrict__ h, const float* __restrict__ stats,
                              const float* __restrict__ g, const float* __restrict__ bt,
                              short* __restrict__ hb) {
    __shared__ float a_sh[128], b_sh[128];
    const int t = threadIdx.x;
    if (t < 128) {
        float mu = stats[t] * (1.f / NN);
        float var = stats[128 + t] * (1.f / NN) - mu * mu;  // biased (matches ref)
        float a = g[t] * rsqrtf(var + BN_EPS);
        a_sh[t] = a;
        b_sh[t] = bt[t] - mu * a;
    }
    __syncthreads();
    int gid = blockIdx.x * 256 + t;  // over NN*16 groups of 8
    if (gid >= NN * 16) return;
    int c0 = (gid & 15) * 8;
    float4 v0 = reinterpret_cast<const float4*>(h)[gid * 2];
    float4 v1 = reinterpret_cast<const float4*>(h)[gid * 2 + 1];
    short8 o;
    o[0] = f2bf(fmaxf(fmaf(a_sh[c0 + 0], v0.x, b_sh[c0 + 0]), 0.f));
    o[1] = f2bf(fmaxf(fmaf(a_sh[c0 + 1], v0.y, b_sh[c0 + 1]), 0.f));
    o[2] = f2bf(fmaxf(fmaf(a_sh[c0 + 2], v0.z, b_sh[c0 + 2]), 0.f));
    o[3] = f2bf(fmaxf(fmaf(a_sh[c0 + 3], v0.w, b_sh[c0 + 3]), 0.f));
    o[4] = f2bf(fmaxf(fmaf(a_sh[c0 + 4], v1.x, b_sh[c0 + 4]), 0.f));
    o[5] = f2bf(fmaxf(fmaf(a_sh[c0 + 5], v1.y, b_sh[c0 + 5]), 0.f));
    o[6] = f2bf(fmaxf(fmaf(a_sh[c0 + 6], v1.z, b_sh[c0 + 6]), 0.f));
    o[7] = f2bf(fmaxf(fmaf(a_sh[c0 + 7], v1.w, b_sh[c0 + 7]), 0.f));
    reinterpret_cast<short8*>(hb)[gid] = o;
}

// ---------------------------------------------------------------------------
// MFMA edge MLP: T4 counted-vmcnt pipeline, prefetch distance 2, 3 buffers.
// Per-iter: s_waitcnt vmcnt(N) (N = newest in-flight stage's loads, never 0
// in steady state) + raw s_barrier + sched_barrier(0); STAGE(kc+2) issued
// after the barrier so its DMA writes can't race readers of buffer kc-1.
// ---------------------------------------------------------------------------
__global__ __launch_bounds__(256) void k_edge_mfma(
    const short* __restrict__ hb, const float* __restrict__ ef,
    const short* __restrict__ Wp, const short* __restrict__ Wp2e,
    const float* __restrict__ be1, const float* __restrict__ be2,
    const int* __restrict__ uu, const int* __restrict__ vv,
    float* __restrict__ out) {
    // 49152 B: staging buf[3] × (A 8KB|B 8KB)  ∪  Hid[128][136] (34816 B)
    __shared__ __align__(16) short smem[24576];
    __shared__ float be1s[128];
    __shared__ int suv[256];
    const int t = threadIdx.x;
    const int eb = blockIdx.x * 128;
    if (t < 128) {
        suv[t] = uu[eb + t];
        suv[128 + t] = vv[eb + t];
        be1s[t] = be1[t];
    }
    __syncthreads();

    const int lane = t & 63, w = t >> 6;
    const int fo = (lane >> 4) * 16 + (lane & 15);
    const int srow = t >> 1;      // ef-staging row
    const int sb0 = (t & 1) * 2;  // ef-staging k-subblock base
    const int sslotbase = (srow >> 4) * 64 + (srow & 15);

    // preload layer-2 B-frags (4 KB, L2-resident)
    short8 b2f[4];
#pragma unroll
    for (int kc2 = 0; kc2 < 4; ++kc2)
        b2f[kc2] = *(const short8*)(Wp2e + (kc2 * 64 + fo) * 8);

    auto STAGE = [&](int kc, short* Ad, short* Bd) {
        if (kc < 8) {
#pragma unroll
            for (int p = 0; p < 2; ++p) {
                int s = t + p * 256;
                int b = (s >> 4) & 3;
                int row = ((s >> 6) << 4) + (s & 15);
                const short* gsrc =
                    hb + (size_t)suv[(kc >= 4) * 128 + row] * 128 + (kc & 3) * 32 + b * 8;
                gload_lds16(gsrc, Ad + s * 8);
            }
        } else {
            const float* er = ef + (size_t)(eb + srow) * 64 + (kc - 8) * 32;
#pragma unroll
            for (int p = 0; p < 2; ++p) {
                int b = sb0 + p;
                float4 f0 = *(const float4*)(er + b * 8);
                float4 f1 = *(const float4*)(er + b * 8 + 4);
                short8 v8;
                v8[0] = f2bf(f0.x); v8[1] = f2bf(f0.y);
                v8[2] = f2bf(f0.z); v8[3] = f2bf(f0.w);
                v8[4] = f2bf(f1.x); v8[5] = f2bf(f1.y);
                v8[6] = f2bf(f1.z); v8[7] = f2bf(f1.w);
                *(short8*)(Ad + (sslotbase + b * 16) * 8) = v8;
            }
        }
#pragma unroll
        for (int p = 0; p < 2; ++p) {
            int s = t + p * 256;
            gload_lds16(Wp + (size_t)kc * 4096 + s * 8, Bd + s * 8);
        }
    };

    f32x4 acc[2][8];
#pragma unroll
    for (int i = 0; i < 2; ++i)
#pragma unroll
        for (int j = 0; j < 8; ++j) acc[i][j] = (f32x4){0.f, 0.f, 0.f, 0.f};

    // prologue: 2 stages in flight
    STAGE(0, smem, smem + 4096);
    STAGE(1, smem + 8192, smem + 8192 + 4096);
    for (int kc = 0; kc < 10; ++kc) {
        // buffer kc must be complete; leave STAGE(kc+1)'s loads in flight.
        // (kc>=8: ef reg-loads inside STAGE self-drained older vm loads.)
        if (kc < 8)
            asm volatile("s_waitcnt vmcnt(4) lgkmcnt(0)" ::: "memory");
        else if (kc == 8)
            asm volatile("s_waitcnt vmcnt(2) lgkmcnt(0)" ::: "memory");
        else
            asm volatile("s_waitcnt vmcnt(0) lgkmcnt(0)" ::: "memory");
        __builtin_amdgcn_s_barrier();
        __builtin_amdgcn_sched_barrier(0);
        if (kc + 2 < 10) {
            short* An = smem + ((kc + 2) % 3) * 8192;
            STAGE(kc + 2, An, An + 4096);
        }
        short* Ac = smem + (kc % 3) * 8192;
        short* Bc = Ac + 4096;
        short8 afr0 = *(const short8*)(Ac + ((2 * w) * 64 + fo) * 8);
        short8 afr1 = *(const short8*)(Ac + ((2 * w + 1) * 64 + fo) * 8);
#pragma unroll
        for (int cb = 0; cb < 8; ++cb) {
            short8 bfr = *(const short8*)(Bc + (cb * 64 + fo) * 8);
            acc[0][cb] = __builtin_amdgcn_mfma_f32_16x16x32_bf16(afr0, bfr, acc[0][cb], 0, 0, 0);
            acc[1][cb] = __builtin_amdgcn_mfma_f32_16x16x32_bf16(afr1, bfr, acc[1][cb], 0, 0, 0);
        }
    }
    __syncthreads();  // all waves done with staging region before Hid overwrite

    // ---- epilogue 1: bias + relu -> Hid[128][136] bf16 (reuses stage region) ----
    short* Hid = smem;
#pragma unroll
    for (int rb2 = 0; rb2 < 2; ++rb2)
#pragma unroll
        for (int cb = 0; cb < 8; ++cb) {
            int col = cb * 16 + (lane & 15);
            int rbase = 32 * w + rb2 * 16 + ((lane >> 4) << 2);
            float bb = be1s[col];
#pragma unroll
            for (int i = 0; i < 4; ++i)
                Hid[(rbase + i) * 136 + col] = f2bf(fmaxf(acc[rb2][cb][i] + bb, 0.f));
        }
    __syncthreads();

    // ---- layer 2 via MFMA: out[e][0..7] = Hid @ We2p + be2 ----
#pragma unroll
    for (int rf = 0; rf < 2; ++rf) {
        f32x4 a2 = (f32x4){0.f, 0.f, 0.f, 0.f};
        const int rbl = 32 * w + 16 * rf + (lane & 15);
#pragma unroll
        for (int kc2 = 0; kc2 < 4; ++kc2) {
            short8 af = *(const short8*)(Hid + rbl * 136 + kc2 * 32 + 8 * (lane >> 4));
            a2 = __builtin_amdgcn_mfma_f32_16x16x32_bf16(af, b2f[kc2], a2, 0, 0, 0);
        }
        int col = lane & 15;
        if (col < 8) {
            int r0 = eb + 32 * w + 16 * rf + 4 * (lane >> 4);
            float bb = be2[col];
#pragma unroll
            for (int i = 0; i < 4; ++i)
                out[(size_t)(r0 + i) * 8 + col] = a2[i] + bb;
        }
    }
}

// ---------------------------------------------------------------------------
extern "C" void kernel_launch(void* const* d_in, const int* in_sizes, int n_in,
                              void* d_out, int out_size, void* d_ws, size_t ws_size,
                              hipStream_t stream) {
    const float* x   = (const float*)d_in[0];
    const float* ef  = (const float*)d_in[1];
    const float* Ws1 = (const float*)d_in[2];
    const float* Wn1 = (const float*)d_in[3];
    const float* b1  = (const float*)d_in[4];
    const float* g1  = (const float*)d_in[5];
    const float* bt1 = (const float*)d_in[6];
    const float* Ws2 = (const float*)d_in[7];
    const float* Wn2 = (const float*)d_in[8];
    const float* b2  = (const float*)d_in[9];
    const float* g2  = (const float*)d_in[10];
    const float* bt2 = (const float*)d_in[11];
    const float* We1 = (const float*)d_in[12];
    const float* be1 = (const float*)d_in[13];
    const float* We2 = (const float*)d_in[14];
    const float* be2 = (const float*)d_in[15];
    const int* src = (const int*)d_in[16];
    const int* dst = (const int*)d_in[17];
    const int* u   = (const int*)d_in[18];
    const int* v   = (const int*)d_in[19];
    float* out = (float*)d_out;

    // Workspace (~85 MB). h1/h2 fp32 live in d_out (N*128 == out_size).
    // hb aliases xb+agg1b (dead after layer-1 GEMM; contiguous 25.6 MB).
    char* p = (char*)d_ws;
    auto take = [&](size_t bytes) {
        char* r = p;
        p += (bytes + 255) & ~(size_t)255;
        return r;
    };
    int* cnt     = (int*)take(NN * 4);       // adjacent to stats: one memset
    float* stats = (float*)take(512 * 4);    // [0:256)=layer1, [256:512)=layer2
    float* invd  = (float*)take(NN * 4);
    int* offs    = (int*)take((NN + 1) * 4);
    int* cursor  = (int*)take(NN * 4);
    int* bsum    = (int*)take(128 * 4);
    int* eidsrc  = (int*)take((size_t)EE * 4);
    short* Wp_e  = (short*)take(320 * 128 * 2);
    short* Wp1   = (short*)take(128 * 128 * 2);
    short* Wp2   = (short*)take(256 * 128 * 2);
    short* Wp2e  = (short*)take(256 * 8 * 2);
    short* xb    = (short*)take((size_t)NN * 64 * 2);
    short* agg1b = (short*)take((size_t)NN * 64 * 2);
    short* h1b   = (short*)take((size_t)NN * 128 * 2);
    short* agg2b = (short*)take((size_t)NN * 128 * 2);
    take(65536);  // pad: node GEMMs read up to ~25 KB past last row
    float* h1 = out;
    float* h2 = out;
    short* hb = xb;  // 25.6 MB union of xb+agg1b

    const int NB = (NN + 1023) / 1024;  // 98 scan blocks

    // ---- CSR build + weight pre-pack + x -> bf16 ----
    hipMemsetAsync(cnt, 0, ((char*)stats - (char*)cnt) + 512 * 4, stream);
    k_count<<<(EE + 255) / 256, 256, 0, stream>>>(dst, cnt);
    k_scan_part<<<NB, 1024, 0, stream>>>(cnt, bsum);
    k_scan_base<<<1, 64, 0, stream>>>(bsum, offs, NB);
    k_scan_final<<<NB, 1024, 0, stream>>>(cnt, bsum, offs, cursor, invd);
    k_fill<<<(EE + 255) / 256, 256, 0, stream>>>(src, dst, cursor, eidsrc);
    k_pack_all<<<360, 256, 0, stream>>>(We1, Ws1, Wn1, Ws2, Wn2, We2, Wp_e, Wp1, Wp2, Wp2e);
    k_f2bf<<<(NN * 8 + 255) / 256, 256, 0, stream>>>(x, xb, NN * 8);

    // ---- layer 1 (bf16 inputs, fp32 accum/stats; stats fused in GEMM) ----
    k_gather_bf<64><<<(NN * 8 + 255) / 256, 256, 0, stream>>>(xb, offs, eidsrc, invd, agg1b);
    k_node_mfma<2, 2><<<(NN + 127) / 128, 256, 0, stream>>>(xb, agg1b, Wp1, b1, h1, stats);
    k_bnrelu_bf16<<<(NN * 16 + 255) / 256, 256, 0, stream>>>(h1, stats, g1, bt1, h1b);

    // ---- layer 2 ----
    k_gather_bf<128><<<(NN * 16 + 255) / 256, 256, 0, stream>>>(h1b, offs, eidsrc, invd, agg2b);
    k_node_mfma<4, 4><<<(NN + 127) / 128, 256, 0, stream>>>(h1b, agg2b, Wp2, b2, h2, stats + 256);
    k_bnrelu_bf16<<<(NN * 16 + 255) / 256, 256, 0, stream>>>(h2, stats + 256, g2, bt2, hb);

    // ---- edge head (bf16 MFMA, counted-vmcnt 2-deep pipeline) ----
    k_edge_mfma<<<EE / 128, 256, 0, stream>>>(hb, ef, Wp_e, Wp2e, be1, be2, u, v, out);
}

// Round 10
// 640.403 us; speedup vs baseline: 10.8590x; 1.0108x over previous
//
#include <hip/hip_runtime.h>

// Problem constants (fixed by the reference).
#define NN 100000
#define EE 1600000
// D_IN=64, H=128, E_IN=64, C=8
constexpr float BN_EPS = 1e-5f;

typedef __attribute__((ext_vector_type(8))) short short8;
typedef __attribute__((ext_vector_type(4))) float f32x4;

__device__ __forceinline__ short f2bf(float f) {  // RNE f32 -> bf16
    unsigned u = __float_as_uint(f);
    u += 0x7fff + ((u >> 16) & 1);
    return (short)(u >> 16);
}
__device__ __forceinline__ float bf2f(short s) {
    return __uint_as_float(((unsigned)(unsigned short)s) << 16);
}

// async global->LDS DMA, 16 B per lane. LDS dest must be base + lane*16
// within each wave (guaranteed by construction at all call sites).
typedef __attribute__((address_space(1))) const unsigned int guint;
typedef __attribute__((address_space(3))) unsigned int luint;
__device__ __forceinline__ void gload_lds16(const void* g, void* l) {
    __builtin_amdgcn_global_load_lds((guint*)g, (luint*)l, 16, 0, 0);
}

// ---------------------------------------------------------------------------
// CSR build: count -> 3-stage parallel scan -> fill
// ---------------------------------------------------------------------------
__global__ void k_count(const int* __restrict__ dst, int* __restrict__ cnt) {
    int e = blockIdx.x * 256 + threadIdx.x;
    if (e < EE) atomicAdd(&cnt[dst[e]], 1);
}

// stage 1: per-1024-block sums
__global__ __launch_bounds__(1024) void k_scan_part(const int* __restrict__ cnt,
                                                    int* __restrict__ bsum) {
    const int t = threadIdx.x, lane = t & 63, w = t >> 6;
    int i = blockIdx.x * 1024 + t;
    int v = (i < NN) ? cnt[i] : 0;
#pragma unroll
    for (int d = 1; d < 64; d <<= 1) v += __shfl_xor(v, d, 64);
    __shared__ int ws[16];
    if (lane == 0) ws[w] = v;
    __syncthreads();
    if (t == 0) {
        int s = 0;
#pragma unroll
        for (int k = 0; k < 16; ++k) s += ws[k];
        bsum[blockIdx.x] = s;
    }
}

// stage 2: exclusive scan of the 98 block sums (single thread; tiny)
__global__ void k_scan_base(int* __restrict__ bsum, int* __restrict__ offs, int nb) {
    if (threadIdx.x == 0) {
        int run = 0;
        for (int k = 0; k < nb; ++k) {
            int v = bsum[k];
            bsum[k] = run;
            run += v;
        }
        offs[NN] = run;
    }
}

// stage 3: local exclusive scan + base; emits offs, cursor, invd
__global__ __launch_bounds__(1024) void k_scan_final(const int* __restrict__ cnt,
                                                     const int* __restrict__ bsum,
                                                     int* __restrict__ offs,
                                                     int* __restrict__ cursor,
                                                     float* __restrict__ invd) {
    const int t = threadIdx.x, lane = t & 63, w = t >> 6;
    __shared__ int wsum[16], wexcl[16];
    int i = blockIdx.x * 1024 + t;
    int v = (i < NN) ? cnt[i] : 0;
    int s = v;
#pragma unroll
    for (int d = 1; d < 64; d <<= 1) {
        int o = __shfl_up(s, d, 64);
        if (lane >= d) s += o;
    }
    if (lane == 63) wsum[w] = s;
    __syncthreads();
    if (t < 16) {
        int wv = wsum[t];
        int ss = wv;
#pragma unroll
        for (int d = 1; d < 16; d <<= 1) {
            int o = __shfl_up(ss, d, 16);
            if (t >= d) ss += o;
        }
        wexcl[t] = ss - wv;
    }
    __syncthreads();
    if (i < NN) {
        int o = bsum[blockIdx.x] + (s - v) + wexcl[w];
        offs[i] = o;
        cursor[i] = o;
        invd[i] = v > 0 ? 1.f / (float)v : 0.f;  // DGL mean: zero-degree -> 0
    }
}

__global__ void k_fill(const int* __restrict__ src, const int* __restrict__ dst,
                       int* __restrict__ cursor, int* __restrict__ eidsrc) {
    int e = blockIdx.x * 256 + threadIdx.x;
    if (e < EE) {
        int pos = atomicAdd(&cursor[dst[e]], 1);
        eidsrc[pos] = src[e];
    }
}

// ---------------------------------------------------------------------------
// fp32 -> bf16 bulk convert (8 elems/thread)
// ---------------------------------------------------------------------------
__global__ void k_f2bf(const float* __restrict__ in, short* __restrict__ out, int n8) {
    int i = blockIdx.x * 256 + threadIdx.x;
    if (i >= n8) return;
    float4 a = ((const float4*)in)[i * 2];
    float4 b = ((const float4*)in)[i * 2 + 1];
    short8 o;
    o[0] = f2bf(a.x); o[1] = f2bf(a.y); o[2] = f2bf(a.z); o[3] = f2bf(a.w);
    o[4] = f2bf(b.x); o[5] = f2bf(b.y); o[6] = f2bf(b.z); o[7] = f2bf(b.w);
    ((short8*)out)[i] = o;
}

// ---------------------------------------------------------------------------
// bf16 CSR mean-aggregation: F/8 lanes per node, 16 B (8 cols) per lane,
// fp32 accum, 8-deep unrolled.
// ---------------------------------------------------------------------------
template <int F>
__global__ __launch_bounds__(256) void k_gather_bf(
    const short* __restrict__ hbsrc, const int* __restrict__ offs,
    const int* __restrict__ eidsrc, const float* __restrict__ invd,
    short* __restrict__ aggb) {
    constexpr int G = F / 8;  // lanes per node
    int gid = blockIdx.x * 256 + threadIdx.x;
    int node = gid / G;
    int sub = gid % G;
    if (node >= NN) return;
    int beg = offs[node], end = offs[node + 1];
    float iv = invd[node];
    float s[8] = {0.f, 0.f, 0.f, 0.f, 0.f, 0.f, 0.f, 0.f};
    const size_t co = (size_t)sub * 8;
    int p = beg;
    for (; p + 8 <= end; p += 8) {
        int idx[8];
#pragma unroll
        for (int q = 0; q < 8; ++q) idx[q] = eidsrc[p + q];
        short8 r[8];
#pragma unroll
        for (int q = 0; q < 8; ++q)
            r[q] = *(const short8*)(hbsrc + (size_t)idx[q] * F + co);
#pragma unroll
        for (int q = 0; q < 8; ++q)
#pragma unroll
            for (int j = 0; j < 8; ++j) s[j] += bf2f(r[q][j]);
    }
    for (; p + 4 <= end; p += 4) {
        int i0 = eidsrc[p], i1 = eidsrc[p + 1], i2 = eidsrc[p + 2], i3 = eidsrc[p + 3];
        short8 r0 = *(const short8*)(hbsrc + (size_t)i0 * F + co);
        short8 r1 = *(const short8*)(hbsrc + (size_t)i1 * F + co);
        short8 r2 = *(const short8*)(hbsrc + (size_t)i2 * F + co);
        short8 r3 = *(const short8*)(hbsrc + (size_t)i3 * F + co);
#pragma unroll
        for (int j = 0; j < 8; ++j)
            s[j] += (bf2f(r0[j]) + bf2f(r1[j])) + (bf2f(r2[j]) + bf2f(r3[j]));
    }
    for (; p < end; ++p) {
        short8 r = *(const short8*)(hbsrc + (size_t)eidsrc[p] * F + co);
#pragma unroll
        for (int j = 0; j < 8; ++j) s[j] += bf2f(r[j]);
    }
    short8 o;
#pragma unroll
    for (int j = 0; j < 8; ++j) o[j] = f2bf(s[j] * iv);
    *(short8*)(aggb + (size_t)node * F + co) = o;
}

// ---------------------------------------------------------------------------
// Unified weight pre-pack into bf16 MFMA-B fragment order.
// ---------------------------------------------------------------------------
__device__ __forceinline__ void packW(const float* W, short* Wp, int local, int kbase) {
    int k = local >> 7, col = local & 127;
    int gk = k + kbase;
    int kc = gk >> 5, kw = gk & 31, bp = kw >> 3, j = kw & 7;
    int cb = col >> 4, n = col & 15;
    Wp[kc * 4096 + (cb * 64 + bp * 16 + n) * 8 + j] = f2bf(W[k * 128 + col]);
}

__global__ void k_pack_all(const float* __restrict__ We1, const float* __restrict__ Ws1,
                           const float* __restrict__ Wn1, const float* __restrict__ Ws2,
                           const float* __restrict__ Wn2, const float* __restrict__ We2,
                           short* __restrict__ Wp_e, short* __restrict__ Wp1,
                           short* __restrict__ Wp2, short* __restrict__ Wp2e) {
    int idx = blockIdx.x * 256 + threadIdx.x;
    if (idx < 40960) {
        packW(We1, Wp_e, idx, 0);
    } else if (idx < 49152) {
        packW(Ws1, Wp1, idx - 40960, 0);
    } else if (idx < 57344) {
        packW(Wn1, Wp1, idx - 49152, 64);
    } else if (idx < 73728) {
        packW(Ws2, Wp2, idx - 57344, 0);
    } else if (idx < 90112) {
        packW(Wn2, Wp2, idx - 73728, 128);
    } else if (idx < 92160) {
        int local = idx - 90112;  // over 128 k x 16 n
        int k = local >> 4, n = local & 15;
        float val = (n < 8) ? We2[k * 8 + n] : 0.f;
        int kc2 = k >> 5, kl = k & 31, bp = kl >> 3, j = kl & 7;
        Wp2e[(kc2 * 64 + bp * 16 + n) * 8 + j] = f2bf(val);
    }
}

// ---------------------------------------------------------------------------
// bf16 MFMA node GEMM: counted-vmcnt 3-buffer pipeline + fused col-stats.
// outz[N,128] (bf16) = [A1b | A2b] @ Wp + bias; stats from exact fp32 acc.
// ---------------------------------------------------------------------------
template <int KC1, int KC2>
__global__ __launch_bounds__(256) void k_node_mfma(
    const short* __restrict__ A1, const short* __restrict__ A2,
    const short* __restrict__ Wp, const float* __restrict__ bias,
    short* __restrict__ outz, float* __restrict__ stats) {
    __shared__ __align__(16) short sbuf[24576];  // 3 × (A 4096 | B 4096)
    __shared__ float bs[128];
    __shared__ float reds[4][128], redss[4][128];
    const int t = threadIdx.x;
    if (t < 128) bs[t] = bias[t];
    const int rowbase = blockIdx.x * 128;
    const int lane = t & 63, w = t >> 6;
    const int fo = (lane >> 4) * 16 + (lane & 15);
    __syncthreads();  // bs ready

    auto NSTAGE = [&](int kc, short* Ad, short* Bd) {
        const short* src;
        int kst, kloc;
        if (kc < KC1) { src = A1; kst = KC1 * 32; kloc = kc * 32; }
        else          { src = A2; kst = KC2 * 32; kloc = (kc - KC1) * 32; }
#pragma unroll
        for (int p = 0; p < 2; ++p) {
            int s = t + p * 256;
            int b = (s >> 4) & 3;
            int row = rowbase + ((s >> 6) << 4) + (s & 15);
            gload_lds16(src + (size_t)row * kst + kloc + b * 8, Ad + s * 8);
            gload_lds16(Wp + (size_t)kc * 4096 + s * 8, Bd + s * 8);
        }
    };

    f32x4 acc[2][8];
#pragma unroll
    for (int i = 0; i < 2; ++i)
#pragma unroll
        for (int j = 0; j < 8; ++j) acc[i][j] = (f32x4){0.f, 0.f, 0.f, 0.f};

    constexpr int KC = KC1 + KC2;
    NSTAGE(0, sbuf, sbuf + 4096);
    NSTAGE(1, sbuf + 8192, sbuf + 8192 + 4096);
    for (int kc = 0; kc < KC; ++kc) {
        // buffer kc complete; STAGE(kc+1)'s 4 loads/thread stay in flight.
        if (kc < KC - 1)
            asm volatile("s_waitcnt vmcnt(4) lgkmcnt(0)" ::: "memory");
        else
            asm volatile("s_waitcnt vmcnt(0) lgkmcnt(0)" ::: "memory");
        __builtin_amdgcn_s_barrier();
        __builtin_amdgcn_sched_barrier(0);
        if (kc + 2 < KC) {
            short* An = sbuf + ((kc + 2) % 3) * 8192;
            NSTAGE(kc + 2, An, An + 4096);
        }
        short* Ac = sbuf + (kc % 3) * 8192;
        short* Bc = Ac + 4096;
        short8 a0 = *(const short8*)(Ac + (2 * w * 64 + fo) * 8);
        short8 a1 = *(const short8*)(Ac + ((2 * w + 1) * 64 + fo) * 8);
#pragma unroll
        for (int cb = 0; cb < 8; ++cb) {
            short8 bfr = *(const short8*)(Bc + (cb * 64 + fo) * 8);
            acc[0][cb] = __builtin_amdgcn_mfma_f32_16x16x32_bf16(a0, bfr, acc[0][cb], 0, 0, 0);
            acc[1][cb] = __builtin_amdgcn_mfma_f32_16x16x32_bf16(a1, bfr, acc[1][cb], 0, 0, 0);
        }
    }
    __syncthreads();

    // epilogue: bias-add, bf16 store, per-column partial stats (fp32-exact)
    float cs[8], css[8];
#pragma unroll
    for (int cb = 0; cb < 8; ++cb) { cs[cb] = 0.f; css[cb] = 0.f; }
#pragma unroll
    for (int rb2 = 0; rb2 < 2; ++rb2) {
        int rloc = 32 * w + rb2 * 16 + ((lane >> 4) << 2);
#pragma unroll
        for (int cb = 0; cb < 8; ++cb) {
            int col = cb * 16 + (lane & 15);
            float bb = bs[col];
#pragma unroll
            for (int i = 0; i < 4; ++i) {
                int row = rowbase + rloc + i;
                if (row < NN) {
                    float v = acc[rb2][cb][i] + bb;
                    outz[(size_t)row * 128 + col] = f2bf(v);
                    cs[cb] += v;
                    css[cb] += v * v;
                }
            }
        }
    }
#pragma unroll
    for (int cb = 0; cb < 8; ++cb) {
        cs[cb] += __shfl_xor(cs[cb], 16);
        cs[cb] += __shfl_xor(cs[cb], 32);
        css[cb] += __shfl_xor(css[cb], 16);
        css[cb] += __shfl_xor(css[cb], 32);
    }
    if (lane < 16) {
#pragma unroll
        for (int cb = 0; cb < 8; ++cb) {
            reds[w][cb * 16 + lane] = cs[cb];
            redss[w][cb * 16 + lane] = css[cb];
        }
    }
    __syncthreads();
    if (t < 128) {
        atomicAdd(&stats[t], reds[0][t] + reds[1][t] + reds[2][t] + reds[3][t]);
    } else {
        int c = t - 128;
        atomicAdd(&stats[128 + c], redss[0][c] + redss[1][c] + redss[2][c] + redss[3][c]);
    }
}

// BN + ReLU over bf16 z -> bf16 out; scale/shift computed once per block.
__global__ void k_bnrelu_bf16(const short* __restrict__ z, const float* __restrict__ stats,
                              const float* __restrict__ g, const float* __restrict__ bt,
                              short* __restrict__ hb) {
    __shared__ float a_sh[128], b_sh[128];
    const int t = threadIdx.x;
    if (t < 128) {
        float mu = stats[t] * (1.f / NN);
        float var = stats[128 + t] * (1.f / NN) - mu * mu;  // biased (matches ref)
        float a = g[t] * rsqrtf(var + BN_EPS);
        a_sh[t] = a;
        b_sh[t] = bt[t] - mu * a;
    }
    __syncthreads();
    int gid = blockIdx.x * 256 + t;  // over NN*16 groups of 8
    if (gid >= NN * 16) return;
    int c0 = (gid & 15) * 8;
    short8 zv = reinterpret_cast<const short8*>(z)[gid];
    short8 o;
#pragma unroll
    for (int j = 0; j < 8; ++j)
        o[j] = f2bf(fmaxf(fmaf(a_sh[c0 + j], bf2f(zv[j]), b_sh[c0 + j]), 0.f));
    reinterpret_cast<short8*>(hb)[gid] = o;
}

// ---------------------------------------------------------------------------
// MFMA edge MLP: T4 counted-vmcnt pipeline, prefetch distance 2, 3 buffers.
// (unchanged from R9 — passed twice)
// ---------------------------------------------------------------------------
__global__ __launch_bounds__(256) void k_edge_mfma(
    const short* __restrict__ hb, const float* __restrict__ ef,
    const short* __restrict__ Wp, const short* __restrict__ Wp2e,
    const float* __restrict__ be1, const float* __restrict__ be2,
    const int* __restrict__ uu, const int* __restrict__ vv,
    float* __restrict__ out) {
    // 49152 B: staging buf[3] × (A 8KB|B 8KB)  ∪  Hid[128][136] (34816 B)
    __shared__ __align__(16) short smem[24576];
    __shared__ float be1s[128];
    __shared__ int suv[256];
    const int t = threadIdx.x;
    const int eb = blockIdx.x * 128;
    if (t < 128) {
        suv[t] = uu[eb + t];
        suv[128 + t] = vv[eb + t];
        be1s[t] = be1[t];
    }
    __syncthreads();

    const int lane = t & 63, w = t >> 6;
    const int fo = (lane >> 4) * 16 + (lane & 15);
    const int srow = t >> 1;      // ef-staging row
    const int sb0 = (t & 1) * 2;  // ef-staging k-subblock base
    const int sslotbase = (srow >> 4) * 64 + (srow & 15);

    // preload layer-2 B-frags (4 KB, L2-resident)
    short8 b2f[4];
#pragma unroll
    for (int kc2 = 0; kc2 < 4; ++kc2)
        b2f[kc2] = *(const short8*)(Wp2e + (kc2 * 64 + fo) * 8);

    auto STAGE = [&](int kc, short* Ad, short* Bd) {
        if (kc < 8) {
#pragma unroll
            for (int p = 0; p < 2; ++p) {
                int s = t + p * 256;
                int b = (s >> 4) & 3;
                int row = ((s >> 6) << 4) + (s & 15);
                const short* gsrc =
                    hb + (size_t)suv[(kc >= 4) * 128 + row] * 128 + (kc & 3) * 32 + b * 8;
                gload_lds16(gsrc, Ad + s * 8);
            }
        } else {
            const float* er = ef + (size_t)(eb + srow) * 64 + (kc - 8) * 32;
#pragma unroll
            for (int p = 0; p < 2; ++p) {
                int b = sb0 + p;
                float4 f0 = *(const float4*)(er + b * 8);
                float4 f1 = *(const float4*)(er + b * 8 + 4);
                short8 v8;
                v8[0] = f2bf(f0.x); v8[1] = f2bf(f0.y);
                v8[2] = f2bf(f0.z); v8[3] = f2bf(f0.w);
                v8[4] = f2bf(f1.x); v8[5] = f2bf(f1.y);
                v8[6] = f2bf(f1.z); v8[7] = f2bf(f1.w);
                *(short8*)(Ad + (sslotbase + b * 16) * 8) = v8;
            }
        }
#pragma unroll
        for (int p = 0; p < 2; ++p) {
            int s = t + p * 256;
            gload_lds16(Wp + (size_t)kc * 4096 + s * 8, Bd + s * 8);
        }
    };

    f32x4 acc[2][8];
#pragma unroll
    for (int i = 0; i < 2; ++i)
#pragma unroll
        for (int j = 0; j < 8; ++j) acc[i][j] = (f32x4){0.f, 0.f, 0.f, 0.f};

    // prologue: 2 stages in flight
    STAGE(0, smem, smem + 4096);
    STAGE(1, smem + 8192, smem + 8192 + 4096);
    for (int kc = 0; kc < 10; ++kc) {
        if (kc < 8)
            asm volatile("s_waitcnt vmcnt(4) lgkmcnt(0)" ::: "memory");
        else if (kc == 8)
            asm volatile("s_waitcnt vmcnt(2) lgkmcnt(0)" ::: "memory");
        else
            asm volatile("s_waitcnt vmcnt(0) lgkmcnt(0)" ::: "memory");
        __builtin_amdgcn_s_barrier();
        __builtin_amdgcn_sched_barrier(0);
        if (kc + 2 < 10) {
            short* An = smem + ((kc + 2) % 3) * 8192;
            STAGE(kc + 2, An, An + 4096);
        }
        short* Ac = smem + (kc % 3) * 8192;
        short* Bc = Ac + 4096;
        short8 afr0 = *(const short8*)(Ac + ((2 * w) * 64 + fo) * 8);
        short8 afr1 = *(const short8*)(Ac + ((2 * w + 1) * 64 + fo) * 8);
#pragma unroll
        for (int cb = 0; cb < 8; ++cb) {
            short8 bfr = *(const short8*)(Bc + (cb * 64 + fo) * 8);
            acc[0][cb] = __builtin_amdgcn_mfma_f32_16x16x32_bf16(afr0, bfr, acc[0][cb], 0, 0, 0);
            acc[1][cb] = __builtin_amdgcn_mfma_f32_16x16x32_bf16(afr1, bfr, acc[1][cb], 0, 0, 0);
        }
    }
    __syncthreads();  // all waves done with staging region before Hid overwrite

    // ---- epilogue 1: bias + relu -> Hid[128][136] bf16 (reuses stage region) ----
    short* Hid = smem;
#pragma unroll
    for (int rb2 = 0; rb2 < 2; ++rb2)
#pragma unroll
        for (int cb = 0; cb < 8; ++cb) {
            int col = cb * 16 + (lane & 15);
            int rbase = 32 * w + rb2 * 16 + ((lane >> 4) << 2);
            float bb = be1s[col];
#pragma unroll
            for (int i = 0; i < 4; ++i)
                Hid[(rbase + i) * 136 + col] = f2bf(fmaxf(acc[rb2][cb][i] + bb, 0.f));
        }
    __syncthreads();

    // ---- layer 2 via MFMA: out[e][0..7] = Hid @ We2p + be2 ----
#pragma unroll
    for (int rf = 0; rf < 2; ++rf) {
        f32x4 a2 = (f32x4){0.f, 0.f, 0.f, 0.f};
        const int rbl = 32 * w + 16 * rf + (lane & 15);
#pragma unroll
        for (int kc2 = 0; kc2 < 4; ++kc2) {
            short8 af = *(const short8*)(Hid + rbl * 136 + kc2 * 32 + 8 * (lane >> 4));
            a2 = __builtin_amdgcn_mfma_f32_16x16x32_bf16(af, b2f[kc2], a2, 0, 0, 0);
        }
        int col = lane & 15;
        if (col < 8) {
            int r0 = eb + 32 * w + 16 * rf + 4 * (lane >> 4);
            float bb = be2[col];
#pragma unroll
            for (int i = 0; i < 4; ++i)
                out[(size_t)(r0 + i) * 8 + col] = a2[i] + bb;
        }
    }
}

// ---------------------------------------------------------------------------
extern "C" void kernel_launch(void* const* d_in, const int* in_sizes, int n_in,
                              void* d_out, int out_size, void* d_ws, size_t ws_size,
                              hipStream_t stream) {
    const float* x   = (const float*)d_in[0];
    const float* ef  = (const float*)d_in[1];
    const float* Ws1 = (const float*)d_in[2];
    const float* Wn1 = (const float*)d_in[3];
    const float* b1  = (const float*)d_in[4];
    const float* g1  = (const float*)d_in[5];
    const float* bt1 = (const float*)d_in[6];
    const float* Ws2 = (const float*)d_in[7];
    const float* Wn2 = (const float*)d_in[8];
    const float* b2  = (const float*)d_in[9];
    const float* g2  = (const float*)d_in[10];
    const float* bt2 = (const float*)d_in[11];
    const float* We1 = (const float*)d_in[12];
    const float* be1 = (const float*)d_in[13];
    const float* We2 = (const float*)d_in[14];
    const float* be2 = (const float*)d_in[15];
    const int* src = (const int*)d_in[16];
    const int* dst = (const int*)d_in[17];
    const int* u   = (const int*)d_in[18];
    const int* v   = (const int*)d_in[19];
    float* out = (float*)d_out;

    // Workspace (~85 MB). z (pre-BN, bf16) lives in d_out's first half
    // (dead before the edge head overwrites d_out). hb aliases xb+agg1b.
    char* p = (char*)d_ws;
    auto take = [&](size_t bytes) {
        char* r = p;
        p += (bytes + 255) & ~(size_t)255;
        return r;
    };
    int* cnt     = (int*)take(NN * 4);       // adjacent to stats: one memset
    float* stats = (float*)take(512 * 4);    // [0:256)=layer1, [256:512)=layer2
    float* invd  = (float*)take(NN * 4);
    int* offs    = (int*)take((NN + 1) * 4);
    int* cursor  = (int*)take(NN * 4);
    int* bsum    = (int*)take(128 * 4);
    int* eidsrc  = (int*)take((size_t)EE * 4);
    short* Wp_e  = (short*)take(320 * 128 * 2);
    short* Wp1   = (short*)take(128 * 128 * 2);
    short* Wp2   = (short*)take(256 * 128 * 2);
    short* Wp2e  = (short*)take(256 * 8 * 2);
    short* xb    = (short*)take((size_t)NN * 64 * 2);
    short* agg1b = (short*)take((size_t)NN * 64 * 2);
    short* h1b   = (short*)take((size_t)NN * 128 * 2);
    short* agg2b = (short*)take((size_t)NN * 128 * 2);
    take(65536);  // pad: node GEMMs read up to ~25 KB past last row
    short* zb = (short*)out;  // bf16 pre-BN z, both layers (25.6 MB of d_out)
    short* hb = xb;           // 25.6 MB union of xb+agg1b

    const int NB = (NN + 1023) / 1024;  // 98 scan blocks

    // ---- CSR build + weight pre-pack + x -> bf16 ----
    hipMemsetAsync(cnt, 0, ((char*)stats - (char*)cnt) + 512 * 4, stream);
    k_count<<<(EE + 255) / 256, 256, 0, stream>>>(dst, cnt);
    k_scan_part<<<NB, 1024, 0, stream>>>(cnt, bsum);
    k_scan_base<<<1, 64, 0, stream>>>(bsum, offs, NB);
    k_scan_final<<<NB, 1024, 0, stream>>>(cnt, bsum, offs, cursor, invd);
    k_fill<<<(EE + 255) / 256, 256, 0, stream>>>(src, dst, cursor, eidsrc);
    k_pack_all<<<360, 256, 0, stream>>>(We1, Ws1, Wn1, Ws2, Wn2, We2, Wp_e, Wp1, Wp2, Wp2e);
    k_f2bf<<<(NN * 8 + 255) / 256, 256, 0, stream>>>(x, xb, NN * 8);

    // ---- layer 1 (bf16 inputs, fp32 accum/stats; stats fused in GEMM) ----
    k_gather_bf<64><<<(NN * 8 + 255) / 256, 256, 0, stream>>>(xb, offs, eidsrc, invd, agg1b);
    k_node_mfma<2, 2><<<(NN + 127) / 128, 256, 0, stream>>>(xb, agg1b, Wp1, b1, zb, stats);
    k_bnrelu_bf16<<<(NN * 16 + 255) / 256, 256, 0, stream>>>(zb, stats, g1, bt1, h1b);

    // ---- layer 2 ----
    k_gather_bf<128><<<(NN * 16 + 255) / 256, 256, 0, stream>>>(h1b, offs, eidsrc, invd, agg2b);
    k_node_mfma<4, 4><<<(NN + 127) / 128, 256, 0, stream>>>(h1b, agg2b, Wp2, b2, zb, stats + 256);
    k_bnrelu_bf16<<<(NN * 16 + 255) / 256, 256, 0, stream>>>(zb, stats + 256, g2, bt2, hb);

    // ---- edge head (bf16 MFMA, counted-vmcnt 2-deep pipeline) ----
    k_edge_mfma<<<EE / 128, 256, 0, stream>>>(hb, ef, Wp_e, Wp2e, be1, be2, u, v, out);
}